// Round 2
// baseline (2393.865 us; speedup 1.0000x reference)
//
#include <hip/hip_runtime.h>

// ---------------------------------------------------------------------------
// Per-pixel patch MLP, affine sub-chains collapsed offline (setup kernel).
// Round 2: weights read as WAVE-UNIFORM global loads (scalarize to s_load /
// SGPR operands of v_fmac) instead of LDS — removes the 110KB LDS block
// (occupancy 1 -> 2+ blocks/CU) and takes weight fetch off the LDS pipe.
// ---------------------------------------------------------------------------

#define IW 384
#define HW (384 * 384)          // 147456
#define NPIX (4 * HW)           // 589824
#define BLOCK 256
#define GRID (NPIX / BLOCK)     // 2304

// packed weight layout in d_ws (floats), row strides padded to multiples of 4
#define OFF_WtA   0             // [75][52]  W_input^T (k-major)
#define OFF_bA    3900          // [52]
#define OFF_Wh1   3952          // [75][52]  W_h1 rows (j-major, k<50)
#define OFF_bh1   7852          // [76]
#define OFF_Wth2  7928          // [75][76]  W_h2^T (j-major, m<75)
#define OFF_bh2   13628         // [76]
#define OFF_E     13704         // [3][76]
#define OFF_be    13932         // [4]
#define OFF_F     13936         // [3][52]
#define OFF_bf    14092         // [4]
#define OFF_D     14096         // [50][4]
#define OFF_bd    14296         // [52]
#define OFF_Wh4   14348         // [125][52]
#define OFF_bh4   20848         // [128]
#define OFF_Wth5  20976         // [125][52]  W_h5^T (j-major, m<50)
#define OFF_bh5   27476         // [52]
#define OFF_Wout  27528         // [3][52]
#define OFF_bout  27684         // [4]
#define TOTAL_W   27688         // floats = 110752 bytes

__device__ __forceinline__ float lrelu(float v) {
    return v >= 0.0f ? v : 0.01f * v;
}

__device__ __forceinline__ float tanh_fast(float v) {
    // tanh(v) = 1 - 2/(exp(2v)+1); saturates correctly for |v| large.
    float e = __expf(2.0f * v);
    return 1.0f - 2.0f * __builtin_amdgcn_rcpf(e + 1.0f);
}

// ---------------------------------------------------------------------------
// Setup: collapse affine chains, transpose, pad, pack into ws. (unchanged)
// ---------------------------------------------------------------------------
__global__ void setup_pack(
    const float* __restrict__ W_input, const float* __restrict__ b_input,
    const float* __restrict__ W_h1,  const float* __restrict__ b_h1,
    const float* __restrict__ W_h2,  const float* __restrict__ b_h2,
    const float* __restrict__ W_h3,  const float* __restrict__ b_h3,
    const float* __restrict__ W_h4,  const float* __restrict__ b_h4,
    const float* __restrict__ W_h5,  const float* __restrict__ b_h5,
    const float* __restrict__ W_out, const float* __restrict__ b_out,
    const float* __restrict__ W_e1,  const float* __restrict__ b_e1,
    const float* __restrict__ W_e2,  const float* __restrict__ b_e2,
    const float* __restrict__ W_e3,  const float* __restrict__ b_e3,
    const float* __restrict__ W_f1,  const float* __restrict__ b_f1,
    const float* __restrict__ W_f2,  const float* __restrict__ b_f2,
    const float* __restrict__ W_f3,  const float* __restrict__ b_f3,
    const float* __restrict__ W_d1,  const float* __restrict__ b_d1,
    const float* __restrict__ W_d2,  const float* __restrict__ b_d2,
    const float* __restrict__ W_d3,  const float* __restrict__ b_d3,
    float* __restrict__ ws)
{
    __shared__ float M1[675];   // W_e3 @ W_e2            (3 x 225)
    __shared__ float MF[450];   // W_f3 @ W_f2            (3 x 150)
    __shared__ float A1[450];   // W_d2 @ W_d1            (150 x 3)
    __shared__ float A2[150];   // W_d3 @ A1              (50 x 3)
    __shared__ float ue[75];    // W_e2 @ b_e1 + b_e2
    __shared__ float uf[50];    // W_f2 @ b_f1 + b_f2
    __shared__ float v1[150];   // W_d2 @ b_d1 + b_d2
    __shared__ float v2[50];    // W_d3 @ v1  + b_d3

    const int tid = threadIdx.x;
    const int NT  = 256;

    for (int o = tid; o < TOTAL_W; o += NT) ws[o] = 0.0f;
    __syncthreads();

    for (int o = tid; o < 3750; o += NT) { int k = o / 50, j = o % 50; ws[OFF_WtA + k * 52 + j] = W_input[j * 75 + k]; }
    for (int o = tid; o < 50;   o += NT) ws[OFF_bA + o] = b_input[o];
    for (int o = tid; o < 3750; o += NT) { int j = o / 50, k = o % 50; ws[OFF_Wh1 + j * 52 + k] = W_h1[j * 50 + k]; }
    for (int o = tid; o < 75;   o += NT) ws[OFF_bh1 + o] = b_h1[o];
    for (int o = tid; o < 5625; o += NT) { int j = o / 75, m = o % 75; ws[OFF_Wth2 + j * 76 + m] = W_h2[m * 75 + j]; }
    for (int o = tid; o < 75;   o += NT) ws[OFF_bh2 + o] = b_h2[o];
    for (int o = tid; o < 6250; o += NT) { int j = o / 50, k = o % 50; ws[OFF_Wh4 + j * 52 + k] = W_h4[j * 50 + k]; }
    for (int o = tid; o < 125;  o += NT) ws[OFF_bh4 + o] = b_h4[o];
    for (int o = tid; o < 6250; o += NT) { int j = o / 50, m = o % 50; ws[OFF_Wth5 + j * 52 + m] = W_h5[m * 125 + j]; }
    for (int o = tid; o < 50;   o += NT) ws[OFF_bh5 + o] = b_h5[o];
    for (int o = tid; o < 150;  o += NT) { int c = o / 50, k = o % 50; ws[OFF_Wout + c * 52 + k] = W_out[c * 50 + k]; }
    for (int o = tid; o < 3;    o += NT) ws[OFF_bout + o] = b_out[o];

    for (int o = tid; o < 675; o += NT) {
        int r = o / 225, c = o % 225; float s = 0.0f;
        for (int t = 0; t < 75; t++) s += W_e3[r * 75 + t] * W_e2[t * 225 + c];
        M1[o] = s;
    }
    for (int o = tid; o < 450; o += NT) {
        int r = o / 150, c = o % 150; float s = 0.0f;
        for (int t = 0; t < 50; t++) s += W_f3[r * 50 + t] * W_f2[t * 150 + c];
        MF[o] = s;
    }
    for (int o = tid; o < 450; o += NT) {
        int r = o / 3, c = o % 3; float s = 0.0f;
        for (int t = 0; t < 50; t++) s += W_d2[r * 50 + t] * W_d1[t * 3 + c];
        A1[o] = s;
    }
    for (int o = tid; o < 75; o += NT) {
        float s = b_e2[o];
        for (int t = 0; t < 225; t++) s += W_e2[o * 225 + t] * b_e1[t];
        ue[o] = s;
    }
    for (int o = tid; o < 50; o += NT) {
        float s = b_f2[o];
        for (int t = 0; t < 150; t++) s += W_f2[o * 150 + t] * b_f1[t];
        uf[o] = s;
    }
    for (int o = tid; o < 150; o += NT) {
        float s = b_d2[o];
        for (int t = 0; t < 50; t++) s += W_d2[o * 50 + t] * b_d1[t];
        v1[o] = s;
    }
    __syncthreads();

    for (int o = tid; o < 225; o += NT) {
        int r = o / 75, c = o % 75; float s = 0.0f;
        for (int t = 0; t < 225; t++) s += M1[r * 225 + t] * W_e1[t * 75 + c];
        ws[OFF_E + r * 76 + c] = s;
    }
    for (int o = tid; o < 3; o += NT) {
        float s = b_e3[o];
        for (int t = 0; t < 75; t++) s += W_e3[o * 75 + t] * ue[t];
        ws[OFF_be + o] = s;
    }
    for (int o = tid; o < 150; o += NT) {
        int r = o / 50, c = o % 50; float s = 0.0f;
        for (int t = 0; t < 150; t++) s += MF[r * 150 + t] * W_f1[t * 50 + c];
        ws[OFF_F + r * 52 + c] = s;
    }
    for (int o = tid; o < 3; o += NT) {
        float s = b_f3[o];
        for (int t = 0; t < 50; t++) s += W_f3[o * 50 + t] * uf[t];
        ws[OFF_bf + o] = s;
    }
    for (int o = tid; o < 150; o += NT) {
        int r = o / 3, c = o % 3; float s = 0.0f;
        for (int t = 0; t < 150; t++) s += W_d3[r * 150 + t] * A1[t * 3 + c];
        A2[o] = s;
    }
    for (int o = tid; o < 50; o += NT) {
        float s = b_d3[o];
        for (int t = 0; t < 150; t++) s += W_d3[o * 150 + t] * v1[t];
        v2[o] = s;
    }
    __syncthreads();

    for (int o = tid; o < 150; o += NT) {
        int r = o / 3, c = o % 3; float s = 0.0f;
        for (int t = 0; t < 50; t++) s += W_h3[r * 50 + t] * A2[t * 3 + c];
        ws[OFF_D + r * 4 + c] = s;
    }
    for (int o = tid; o < 50; o += NT) {
        float s = b_h3[o];
        for (int t = 0; t < 50; t++) s += W_h3[o * 50 + t] * v2[t];
        ws[OFF_bd + o] = s;
    }
}

// ---------------------------------------------------------------------------
// Main fused kernel: one thread per pixel, weights via wave-uniform loads.
// ---------------------------------------------------------------------------
__global__ __launch_bounds__(BLOCK, 4) void fused_mlp(
    const float* __restrict__ xin,   // (4,3,384,384)
    const float* __restrict__ w,     // packed weights (TOTAL_W floats)
    float* __restrict__ out)         // (4,3,384,384)
{
    const int idx = blockIdx.x * BLOCK + threadIdx.x;   // < NPIX (exact grid)
    const int bb = idx / HW;
    const int p  = idx - bb * HW;
    const int y  = p / IW;
    const int x0 = p - y * IW;
    const float* __restrict__ xb = xin + bb * 3 * HW;

    // ---------------- stage A: x1 = W_input @ sw + b ----------------
    float x1[50];
#pragma unroll
    for (int j = 0; j < 50; j++) x1[j] = w[OFF_bA + j];
    {
        int wo = OFF_WtA;
#pragma unroll 1
        for (int c = 0; c < 3; c++) {
            const float* xc = xb + c * HW;
#pragma unroll 1
            for (int kh = 0; kh < 5; kh++) {
                int yy = y - 2 + kh;
                yy = yy < 0 ? -yy : (yy > 383 ? 766 - yy : yy);
                const float* xr = xc + yy * IW;
#pragma unroll
                for (int kw = 0; kw < 5; kw++) {
                    int xx = x0 - 2 + kw;
                    xx = xx < 0 ? -xx : (xx > 383 ? 766 - xx : xx);
                    const float s = xr[xx];
#pragma unroll
                    for (int j = 0; j < 50; j++) x1[j] = fmaf(w[wo + j], s, x1[j]);
                    wo += 52;
                }
            }
        }
    }

    // ------- stage B: x3 = tanh(W_h2 @ lrelu(W_h1 @ x1 + b1) + b2) -------
    float x3[75];
#pragma unroll
    for (int m = 0; m < 75; m++) x3[m] = 0.0f;
#pragma unroll 1
    for (int j = 0; j < 75; j++) {
        const int r1 = OFF_Wh1 + j * 52;
        float d0 = 0.f, d1 = 0.f, d2 = 0.f, d3 = 0.f;
#pragma unroll
        for (int k = 0; k < 48; k += 4) {
            d0 = fmaf(w[r1 + k],     x1[k],     d0);
            d1 = fmaf(w[r1 + k + 1], x1[k + 1], d1);
            d2 = fmaf(w[r1 + k + 2], x1[k + 2], d2);
            d3 = fmaf(w[r1 + k + 3], x1[k + 3], d3);
        }
        d0 = fmaf(w[r1 + 48], x1[48], d0);
        d1 = fmaf(w[r1 + 49], x1[49], d1);
        float u = w[OFF_bh1 + j] + ((d0 + d1) + (d2 + d3));
        u = lrelu(u);
        const int r2 = OFF_Wth2 + j * 76;
#pragma unroll
        for (int m = 0; m < 75; m++) x3[m] = fmaf(w[r2 + m], u, x3[m]);
    }
#pragma unroll
    for (int m = 0; m < 75; m++) x3[m] = tanh_fast(x3[m] + w[OFF_bh2 + m]);

    // ------- stage C: x4 = lrelu(E@x3+be + F@x1+bf); xd = D@x4 + bd -------
    float x4[3];
#pragma unroll
    for (int c = 0; c < 3; c++) {
        const int re = OFF_E + c * 76;
        float a0 = 0.f, a1 = 0.f, a2 = 0.f;
#pragma unroll
        for (int k = 0; k < 75; k += 3) {
            a0 = fmaf(w[re + k],     x3[k],     a0);
            a1 = fmaf(w[re + k + 1], x3[k + 1], a1);
            a2 = fmaf(w[re + k + 2], x3[k + 2], a2);
        }
        float e = w[OFF_be + c] + (a0 + (a1 + a2));
        const int rf = OFF_F + c * 52;
        float b0 = 0.f, b1 = 0.f;
#pragma unroll
        for (int k = 0; k < 50; k += 2) {
            b0 = fmaf(w[rf + k],     x1[k],     b0);
            b1 = fmaf(w[rf + k + 1], x1[k + 1], b1);
        }
        float f = w[OFF_bf + c] + (b0 + b1);
        x4[c] = lrelu(e + f);
    }
    float xd[50];
#pragma unroll
    for (int m = 0; m < 50; m++) {
        const int rd = OFF_D + m * 4;
        xd[m] = fmaf(w[rd + 2], x4[2], fmaf(w[rd + 1], x4[1], fmaf(w[rd], x4[0], w[OFF_bd + m])));
    }

    // ------- stage D: x6 = W_h5 @ tanh(W_h4 @ xd + b4) + b5 - x1 -------
    float x6[50];
#pragma unroll
    for (int m = 0; m < 50; m++) x6[m] = w[OFF_bh5 + m] - x1[m];
#pragma unroll 1
    for (int j = 0; j < 125; j++) {
        const int r4 = OFF_Wh4 + j * 52;
        float d0 = 0.f, d1 = 0.f, d2 = 0.f, d3 = 0.f;
#pragma unroll
        for (int k = 0; k < 48; k += 4) {
            d0 = fmaf(w[r4 + k],     xd[k],     d0);
            d1 = fmaf(w[r4 + k + 1], xd[k + 1], d1);
            d2 = fmaf(w[r4 + k + 2], xd[k + 2], d2);
            d3 = fmaf(w[r4 + k + 3], xd[k + 3], d3);
        }
        d0 = fmaf(w[r4 + 48], xd[48], d0);
        d1 = fmaf(w[r4 + 49], xd[49], d1);
        float t = w[OFF_bh4 + j] + ((d0 + d1) + (d2 + d3));
        t = tanh_fast(t);
        const int r5 = OFF_Wth5 + j * 52;
#pragma unroll
        for (int m = 0; m < 50; m++) x6[m] = fmaf(w[r5 + m], t, x6[m]);
    }

    // ------- stage E: out = lrelu(W_out @ x6 + b), store transposed -------
#pragma unroll
    for (int c = 0; c < 3; c++) {
        const int ro = OFF_Wout + c * 52;
        float a0 = 0.f, a1 = 0.f;
#pragma unroll
        for (int k = 0; k < 50; k += 2) {
            a0 = fmaf(w[ro + k],     x6[k],     a0);
            a1 = fmaf(w[ro + k + 1], x6[k + 1], a1);
        }
        float v = w[OFF_bout + c] + (a0 + a1);
        out[(bb * 3 + c) * HW + p] = lrelu(v);
    }
}

extern "C" void kernel_launch(void* const* d_in, const int* in_sizes, int n_in,
                              void* d_out, int out_size, void* d_ws, size_t ws_size,
                              hipStream_t stream)
{
    const float* xin = (const float*)d_in[0];
    float* ws = (float*)d_ws;

    setup_pack<<<1, 256, 0, stream>>>(
        (const float*)d_in[1],  (const float*)d_in[2],   // input
        (const float*)d_in[3],  (const float*)d_in[4],   // h1
        (const float*)d_in[5],  (const float*)d_in[6],   // h2
        (const float*)d_in[7],  (const float*)d_in[8],   // h3
        (const float*)d_in[9],  (const float*)d_in[10],  // h4
        (const float*)d_in[11], (const float*)d_in[12],  // h5
        (const float*)d_in[13], (const float*)d_in[14],  // out
        (const float*)d_in[15], (const float*)d_in[16],  // e1
        (const float*)d_in[17], (const float*)d_in[18],  // e2
        (const float*)d_in[19], (const float*)d_in[20],  // e3
        (const float*)d_in[21], (const float*)d_in[22],  // f1
        (const float*)d_in[23], (const float*)d_in[24],  // f2
        (const float*)d_in[25], (const float*)d_in[26],  // f3
        (const float*)d_in[27], (const float*)d_in[28],  // d1
        (const float*)d_in[29], (const float*)d_in[30],  // d2
        (const float*)d_in[31], (const float*)d_in[32],  // d3
        ws);

    fused_mlp<<<GRID, BLOCK, 0, stream>>>(xin, ws, (float*)d_out);
}

// Round 3
// 550.754 us; speedup vs baseline: 4.3465x; 4.3465x over previous
//
#include <hip/hip_runtime.h>

// ---------------------------------------------------------------------------
// Round 3: MFMA rewrite.
//   - Affine sub-chains collapsed in setup kernel (E,F,D + biases), as before.
//   - setup_pack additionally emits bf16 hi/lo B-operand FRAGMENT images for
//     every layer (16x16x32 layout: n=lane&15, k=(lane>>4)*8+j), stage-major,
//     plus a 512-dword bias table, into d_ws.
//   - fused_mfma: 128 px/block (4 waves x 32 px = 2 m-tiles each).
//     Activations live in LDS as packed (lo16|hi16) bf16 pairs, rows are
//     wave-private -> no barriers for acts. Weights stream through a
//     ping-pong LDS buffer; one barrier per stage, prefetch issued after
//     each barrier. 3-term split GEMMs: Wh*xh + Wh*xl + Wl*xh (fp32 acc).
// ---------------------------------------------------------------------------

#define IW 384
#define HW (384 * 384)           // 147456
#define NPIX (4 * HW)            // 589824
#define MTILE 128                // pixels per block
#define NBLK (NPIX / MTILE)      // 4608
#define KST 108                  // act row stride (dwords), mult of 4, 2-way-free banks

typedef __attribute__((ext_vector_type(8))) short short8;
typedef __attribute__((ext_vector_type(4))) float f32x4;
typedef __attribute__((ext_vector_type(4))) unsigned int uint4_;

#define MFMA16(A, B, C) __builtin_amdgcn_mfma_f32_16x16x32_bf16((A), (B), (C), 0, 0, 0)

// bias table offsets (dwords in ws)
#define BA   0
#define B1   64
#define B2   144
#define BEF  224
#define BD   240
#define B4   304
#define B5   432
#define BOUT 496
#define BIAS_TOT 512

// weight image segment offsets (shorts, after the 512-dword bias table)
// A0 A1 A2 | h1a h1b | h2a h2b h2c | E F | D | h4c0 h5c0 ... h4c3 h5c3 | out
#define W_A0   0
#define W_A1   4096
#define W_A2   8192
#define W_H1A  12288
#define W_H1B  17408
#define W_H2A  22528
#define W_H2B  27648
#define W_H2C  32768
#define W_EF   37888     // E: 3072 shorts, then F: 2048 shorts
#define W_D    43008
#define W_H4C0 47104     // h4 chunk c at 47104 + c*8192
#define W_H5C0 51200     // h5 chunk c at 51200 + c*8192
#define W_OUT  79872
#define W_TOT  81920

__device__ __forceinline__ float lrelu(float v) { return v >= 0.0f ? v : 0.01f * v; }

__device__ __forceinline__ float tanh_fast(float v) {
    float e = __expf(2.0f * v);
    return 1.0f - 2.0f * __builtin_amdgcn_rcpf(e + 1.0f);
}

__device__ __forceinline__ unsigned short f2b(float f) {
    union { float f; unsigned u; } v; v.f = f;
    unsigned r = v.u + 0x7fffu + ((v.u >> 16) & 1u);
    return (unsigned short)(r >> 16);
}
__device__ __forceinline__ float b2f(unsigned short h) {
    union { unsigned u; float f; } v; v.u = ((unsigned)h) << 16;
    return v.f;
}
__device__ __forceinline__ unsigned packpair(float x) {
    unsigned short hi = f2b(x);
    unsigned short lo = f2b(x - b2f(hi));
    return ((unsigned)lo << 16) | (unsigned)hi;
}

// ---------------------------------------------------------------------------
// setup kernel: collapse affine chains + pack fragment images + bias table
// ---------------------------------------------------------------------------
__global__ void setup_pack(
    const float* __restrict__ W_input, const float* __restrict__ b_input,
    const float* __restrict__ W_h1,  const float* __restrict__ b_h1,
    const float* __restrict__ W_h2,  const float* __restrict__ b_h2,
    const float* __restrict__ W_h3,  const float* __restrict__ b_h3,
    const float* __restrict__ W_h4,  const float* __restrict__ b_h4,
    const float* __restrict__ W_h5,  const float* __restrict__ b_h5,
    const float* __restrict__ W_out, const float* __restrict__ b_out,
    const float* __restrict__ W_e1,  const float* __restrict__ b_e1,
    const float* __restrict__ W_e2,  const float* __restrict__ b_e2,
    const float* __restrict__ W_e3,  const float* __restrict__ b_e3,
    const float* __restrict__ W_f1,  const float* __restrict__ b_f1,
    const float* __restrict__ W_f2,  const float* __restrict__ b_f2,
    const float* __restrict__ W_f3,  const float* __restrict__ b_f3,
    const float* __restrict__ W_d1,  const float* __restrict__ b_d1,
    const float* __restrict__ W_d2,  const float* __restrict__ b_d2,
    const float* __restrict__ W_d3,  const float* __restrict__ b_d3,
    float* __restrict__ ws)
{
    __shared__ float M1[675];   // W_e3 @ W_e2   (3 x 225)
    __shared__ float MF[450];   // W_f3 @ W_f2   (3 x 150)
    __shared__ float A1[450];   // W_d2 @ W_d1   (150 x 3)
    __shared__ float A2[150];   // W_d3 @ A1     (50 x 3)
    __shared__ float ue[75], uf[50], v1[150], v2[50];
    __shared__ float sE[225];   // (3 x 75)
    __shared__ float sF[150];   // (3 x 50)
    __shared__ float sD[150];   // (50 x 3)
    __shared__ float sbd[50];
    __shared__ float sbef[3];

    const int tid = threadIdx.x;
    const int NT = 256;

    // ---- phase 1 ----
    for (int o = tid; o < 675; o += NT) {
        int r = o / 225, c = o % 225; float s = 0.0f;
        for (int t = 0; t < 75; t++) s += W_e3[r * 75 + t] * W_e2[t * 225 + c];
        M1[o] = s;
    }
    for (int o = tid; o < 450; o += NT) {
        int r = o / 150, c = o % 150; float s = 0.0f;
        for (int t = 0; t < 50; t++) s += W_f3[r * 50 + t] * W_f2[t * 150 + c];
        MF[o] = s;
    }
    for (int o = tid; o < 450; o += NT) {
        int r = o / 3, c = o % 3; float s = 0.0f;
        for (int t = 0; t < 50; t++) s += W_d2[r * 50 + t] * W_d1[t * 3 + c];
        A1[o] = s;
    }
    for (int o = tid; o < 75; o += NT) {
        float s = b_e2[o];
        for (int t = 0; t < 225; t++) s += W_e2[o * 225 + t] * b_e1[t];
        ue[o] = s;
    }
    for (int o = tid; o < 50; o += NT) {
        float s = b_f2[o];
        for (int t = 0; t < 150; t++) s += W_f2[o * 150 + t] * b_f1[t];
        uf[o] = s;
    }
    for (int o = tid; o < 150; o += NT) {
        float s = b_d2[o];
        for (int t = 0; t < 50; t++) s += W_d2[o * 50 + t] * b_d1[t];
        v1[o] = s;
    }
    __syncthreads();

    // ---- phase 2 ----
    for (int o = tid; o < 225; o += NT) {  // sE = M1 @ W_e1
        int r = o / 75, c = o % 75; float s = 0.0f;
        for (int t = 0; t < 225; t++) s += M1[r * 225 + t] * W_e1[t * 75 + c];
        sE[o] = s;
    }
    for (int o = tid; o < 150; o += NT) {  // sF = MF @ W_f1
        int r = o / 50, c = o % 50; float s = 0.0f;
        for (int t = 0; t < 150; t++) s += MF[r * 150 + t] * W_f1[t * 50 + c];
        sF[o] = s;
    }
    for (int o = tid; o < 150; o += NT) {  // A2 = W_d3 @ A1
        int r = o / 3, c = o % 3; float s = 0.0f;
        for (int t = 0; t < 150; t++) s += W_d3[r * 150 + t] * A1[t * 3 + c];
        A2[o] = s;
    }
    for (int o = tid; o < 50; o += NT) {   // v2 = W_d3 @ v1 + b_d3
        float s = b_d3[o];
        for (int t = 0; t < 150; t++) s += W_d3[o * 150 + t] * v1[t];
        v2[o] = s;
    }
    for (int o = tid; o < 3; o += NT) {    // bef = be + bf
        float se = b_e3[o];
        for (int t = 0; t < 75; t++) se += W_e3[o * 75 + t] * ue[t];
        float sf = b_f3[o];
        for (int t = 0; t < 50; t++) sf += W_f3[o * 50 + t] * uf[t];
        sbef[o] = se + sf;
    }
    __syncthreads();

    // ---- phase 3 ----
    for (int o = tid; o < 150; o += NT) {  // sD = W_h3 @ A2
        int r = o / 3, c = o % 3; float s = 0.0f;
        for (int t = 0; t < 50; t++) s += W_h3[r * 50 + t] * A2[t * 3 + c];
        sD[o] = s;
    }
    for (int o = tid; o < 50; o += NT) {   // sbd = W_h3 @ v2 + b_h3
        float s = b_h3[o];
        for (int t = 0; t < 50; t++) s += W_h3[o * 50 + t] * v2[t];
        sbd[o] = s;
    }
    __syncthreads();

    // ---- phase 4: bias table ----
    for (int i = tid; i < BIAS_TOT; i += NT) ws[i] = 0.0f;
    __syncthreads();
    for (int i = tid; i < 50;  i += NT) ws[BA  + i] = b_input[i];
    for (int i = tid; i < 75;  i += NT) ws[B1  + i] = b_h1[i];
    for (int i = tid; i < 75;  i += NT) ws[B2  + i] = b_h2[i];
    for (int i = tid; i < 3;   i += NT) ws[BEF + i] = sbef[i];
    for (int i = tid; i < 50;  i += NT) ws[BD  + i] = sbd[i];
    for (int i = tid; i < 125; i += NT) ws[B4  + i] = b_h4[i];
    for (int i = tid; i < 50;  i += NT) ws[B5  + i] = b_h5[i];
    for (int i = tid; i < 3;   i += NT) ws[BOUT + i] = b_out[i];

    // ---- phase 5: fragment packing ----
    // segment table: offset, layer, NT, KTS, nbase, kbase
    const int soff[20] = {W_A0,W_A1,W_A2,W_H1A,W_H1B,W_H2A,W_H2B,W_H2C,
                          W_EF,W_EF+3072,W_D,
                          W_H4C0,W_H5C0, W_H4C0+8192,W_H5C0+8192,
                          W_H4C0+16384,W_H5C0+16384, W_H4C0+24576,W_H5C0+24576,
                          W_OUT};
    const int slay[20] = {0,0,0, 1,1, 2,2,2, 3,4, 5, 6,7, 6,7, 6,7, 6,7, 8};
    const int sNT[20]  = {4,4,4, 5,5, 5,5,5, 1,1, 4, 2,4, 2,4, 2,4, 2,4, 1};
    const int sKTS[20] = {1,1,1, 1,1, 1,1,1, 3,2, 1, 2,1, 2,1, 2,1, 2,1, 2};
    const int snb[20]  = {0,0,0, 0,0, 0,0,0, 0,0, 0, 0,0, 32,0, 64,0, 96,0, 0};
    const int skb[20]  = {0,32,64, 0,32, 0,32,64, 0,0, 0, 0,0, 0,32, 0,64, 0,96, 0};

    short* wimg = (short*)(ws + BIAS_TOT);

    for (int s = 0; s < 20; s++) {
        int tot = sNT[s] * sKTS[s] * 1024;     // shorts
        short* dst = wimg + soff[s];
        int lay = slay[s], kts = sKTS[s], nb = snb[s], kb = skb[s];
        for (int i = tid; i < tot; i += NT) {
            int j = i & 7;
            int lane = (i >> 3) & 63;
            int frag = i >> 9;
            int pl = frag & 1;
            int ktnt = frag >> 1;
            int kt = ktnt % kts, nt = ktnt / kts;
            int n = nb + nt * 16 + (lane & 15);
            int k = kb + kt * 32 + (lane >> 4) * 8 + j;
            float v = 0.0f;
            switch (lay) {
                case 0: if (n < 50  && k < 75)  v = W_input[n * 75 + k]; break;
                case 1: if (n < 75  && k < 50)  v = W_h1[n * 50 + k]; break;
                case 2: if (n < 75  && k < 75)  v = W_h2[n * 75 + k]; break;
                case 3: if (n < 3   && k < 75)  v = sE[n * 75 + k]; break;
                case 4: if (n < 3   && k < 50)  v = sF[n * 50 + k]; break;
                case 5: if (n < 50  && k < 3)   v = sD[n * 3 + k]; break;
                case 6: if (n < 125 && k < 50)  v = W_h4[n * 50 + k]; break;
                case 7: if (n < 50  && k < 125) v = W_h5[n * 125 + k]; break;
                case 8: if (n < 3   && k < 50)  v = W_out[n * 50 + k]; break;
            }
            unsigned short hi = f2b(v);
            dst[i] = (short)(pl ? f2b(v - b2f(hi)) : hi);
        }
    }
}

// ---------------------------------------------------------------------------
// main kernel helpers
// ---------------------------------------------------------------------------
__device__ __forceinline__ void copyStage(short* dst, const short* src, int nsh, int tid) {
    uint4_* d = (uint4_*)dst;
    const uint4_* s = (const uint4_*)src;
    int n = nsh >> 3;
    for (int i = tid; i < n; i += 256) d[i] = s[i];
}

__device__ __forceinline__ short8 bfrag(const short* wb, int fragIdx, int lane) {
    return *(const short8*)(wb + fragIdx * 512 + lane * 8);
}

__device__ __forceinline__ void readA(const unsigned int* acts, int row0, int kbase,
                                      int lane, short8& ah, short8& al) {
    int m = lane & 15, qd = lane >> 4;
    const unsigned int* p = &acts[(row0 + m) * KST + kbase + qd * 8];
    uint4_ a = *(const uint4_*)p;
    uint4_ b = *(const uint4_*)(p + 4);
    union { unsigned u[4]; short8 s; } uh, ul;
    uh.u[0] = (a.x & 0xffffu) | (a.y << 16);
    uh.u[1] = (a.z & 0xffffu) | (a.w << 16);
    uh.u[2] = (b.x & 0xffffu) | (b.y << 16);
    uh.u[3] = (b.z & 0xffffu) | (b.w << 16);
    ul.u[0] = (a.x >> 16) | (a.y & 0xffff0000u);
    ul.u[1] = (a.z >> 16) | (a.w & 0xffff0000u);
    ul.u[2] = (b.x >> 16) | (b.y & 0xffff0000u);
    ul.u[3] = (b.z >> 16) | (b.w & 0xffff0000u);
    ah = uh.s; al = ul.s;
}

__device__ __forceinline__ void writeC(unsigned int* acts, int row0q, int col, f32x4 v) {
    acts[(row0q + 0) * KST + col] = packpair(v[0]);
    acts[(row0q + 1) * KST + col] = packpair(v[1]);
    acts[(row0q + 2) * KST + col] = packpair(v[2]);
    acts[(row0q + 3) * KST + col] = packpair(v[3]);
}

__device__ __forceinline__ void t3(f32x4& a0, f32x4& a1,
                                   short8 ah0, short8 al0, short8 ah1, short8 al1,
                                   short8 bh, short8 bl) {
    a0 = MFMA16(ah0, bh, a0);
    a1 = MFMA16(ah1, bh, a1);
    a0 = MFMA16(al0, bh, a0);
    a1 = MFMA16(al1, bh, a1);
    a0 = MFMA16(ah0, bl, a0);
    a1 = MFMA16(ah1, bl, a1);
}

// ---------------------------------------------------------------------------
// main fused kernel
// ---------------------------------------------------------------------------
__global__ __launch_bounds__(256, 2) void fused_mfma(
    const float* __restrict__ xin,
    const float* __restrict__ ws,
    float* __restrict__ out)
{
    __shared__ unsigned int acts[MTILE * KST];   // 55296 B
    __shared__ short wbuf[2][5120];              // 20480 B
    __shared__ float sbias[BIAS_TOT];            // 2048 B

    const int tid = threadIdx.x;
    const int wv = tid >> 6;
    const int lane = tid & 63;
    const int qd = lane >> 4;
    const int mcol = lane & 15;
    const int rw = wv * 32;                       // wave's row base in acts
    const int pxbase = blockIdx.x * MTILE + wv * 32;
    const short* wimg = (const short*)(ws + BIAS_TOT);
    const f32x4 zero4 = {0.f, 0.f, 0.f, 0.f};

    // ---- prologue ----
    for (int i = tid; i < BIAS_TOT; i += 256) sbias[i] = ws[i];
    for (int i = tid; i < MTILE * 16; i += 256) {          // zero k in [80,96)
        int r = i >> 4, k = 80 + (i & 15);
        acts[r * KST + k] = 0u;
    }
    copyStage(wbuf[0], wimg + W_A0, 4096, tid);

    // gather sw fragments (unfold, reflect pad) while stage 0 streams in
    short8 swh[3][2], swl[3][2];
    for (int mt = 0; mt < 2; mt++) {
        int g = pxbase + mt * 16 + mcol;
        int bb = g / HW; int p = g - bb * HW;
        int y = p / IW, x = p - y * IW;
        const float* xb = xin + bb * 3 * HW;
        for (int kt = 0; kt < 3; kt++) {
            union { unsigned u[4]; short8 s; } uh, ul;
#pragma unroll
            for (int jj = 0; jj < 8; jj += 2) {
                unsigned short hh[2], ll[2];
#pragma unroll
                for (int t = 0; t < 2; t++) {
                    int qq = kt * 32 + qd * 8 + jj + t;
                    float v = 0.0f;
                    if (qq < 75) {
                        int c = qq / 25, rem = qq - 25 * c;
                        int rr = rem / 5, ss = rem - 5 * rr;
                        int yy = y + rr - 2; yy = yy < 0 ? -yy : (yy > 383 ? 766 - yy : yy);
                        int xx = x + ss - 2; xx = xx < 0 ? -xx : (xx > 383 ? 766 - xx : xx);
                        v = xb[c * HW + yy * IW + xx];
                    }
                    hh[t] = f2b(v);
                    ll[t] = f2b(v - b2f(hh[t]));
                }
                uh.u[jj >> 1] = ((unsigned)hh[1] << 16) | hh[0];
                ul.u[jj >> 1] = ((unsigned)ll[1] << 16) | ll[0];
            }
            swh[kt][mt] = uh.s; swl[kt][mt] = ul.s;
        }
    }
    __syncthreads();                                       // stage 0 ready

    // ===== layer A: x1 = WA @ sw + bA  (N=64pad, K=96pad) =====
    f32x4 accA[4][2];
#pragma unroll
    for (int nt = 0; nt < 4; nt++) { accA[nt][0] = zero4; accA[nt][1] = zero4; }

    copyStage(wbuf[1], wimg + W_A1, 4096, tid);            // prefetch s1
#pragma unroll
    for (int nt = 0; nt < 4; nt++) {
        short8 bh = bfrag(wbuf[0], nt * 2, lane), bl = bfrag(wbuf[0], nt * 2 + 1, lane);
        t3(accA[nt][0], accA[nt][1], swh[0][0], swl[0][0], swh[0][1], swl[0][1], bh, bl);
    }
    __syncthreads();
    copyStage(wbuf[0], wimg + W_A2, 4096, tid);            // prefetch s2
#pragma unroll
    for (int nt = 0; nt < 4; nt++) {
        short8 bh = bfrag(wbuf[1], nt * 2, lane), bl = bfrag(wbuf[1], nt * 2 + 1, lane);
        t3(accA[nt][0], accA[nt][1], swh[1][0], swl[1][0], swh[1][1], swl[1][1], bh, bl);
    }
    __syncthreads();
    copyStage(wbuf[1], wimg + W_H1A, 5120, tid);           // prefetch s3
#pragma unroll
    for (int nt = 0; nt < 4; nt++) {
        short8 bh = bfrag(wbuf[0], nt * 2, lane), bl = bfrag(wbuf[0], nt * 2 + 1, lane);
        t3(accA[nt][0], accA[nt][1], swh[2][0], swl[2][0], swh[2][1], swl[2][1], bh, bl);
    }
    // epilogue A: add bias, keep C copy, write pairs, read x1 A-frags
    f32x4 x1C[4][2];
    short8 x1h[2][2], x1l[2][2];
#pragma unroll
    for (int nt = 0; nt < 4; nt++) {
        float bv = sbias[BA + nt * 16 + mcol];
#pragma unroll
        for (int mt = 0; mt < 2; mt++) {
            f32x4 v = accA[nt][mt];
            v[0] += bv; v[1] += bv; v[2] += bv; v[3] += bv;
            x1C[nt][mt] = v;
            writeC(acts, rw + mt * 16 + qd * 4, nt * 16 + mcol, v);
        }
    }
#pragma unroll
    for (int kt = 0; kt < 2; kt++)
#pragma unroll
        for (int mt = 0; mt < 2; mt++)
            readA(acts, rw + mt * 16, kt * 32, lane, x1h[kt][mt], x1l[kt][mt]);
    __syncthreads();

    // ===== layer h1: x2 = lrelu(h1 @ x1 + b1)  (N=80pad, K=64pad) =====
    f32x4 acc1[5][2];
#pragma unroll
    for (int nt = 0; nt < 5; nt++) { acc1[nt][0] = zero4; acc1[nt][1] = zero4; }

    copyStage(wbuf[0], wimg + W_H1B, 5120, tid);           // prefetch s4
#pragma unroll
    for (int nt = 0; nt < 5; nt++) {
        short8 bh = bfrag(wbuf[1], nt * 2, lane), bl = bfrag(wbuf[1], nt * 2 + 1, lane);
        t3(acc1[nt][0], acc1[nt][1], x1h[0][0], x1l[0][0], x1h[0][1], x1l[0][1], bh, bl);
    }
    __syncthreads();
    copyStage(wbuf[1], wimg + W_H2A, 5120, tid);           // prefetch s5
#pragma unroll
    for (int nt = 0; nt < 5; nt++) {
        short8 bh = bfrag(wbuf[0], nt * 2, lane), bl = bfrag(wbuf[0], nt * 2 + 1, lane);
        t3(acc1[nt][0], acc1[nt][1], x1h[1][0], x1l[1][0], x1h[1][1], x1l[1][1], bh, bl);
    }
    // epilogue h1: lrelu + write x2
#pragma unroll
    for (int nt = 0; nt < 5; nt++) {
        float bv = sbias[B1 + nt * 16 + mcol];
#pragma unroll
        for (int mt = 0; mt < 2; mt++) {
            f32x4 v = acc1[nt][mt];
            v[0] = lrelu(v[0] + bv); v[1] = lrelu(v[1] + bv);
            v[2] = lrelu(v[2] + bv); v[3] = lrelu(v[3] + bv);
            writeC(acts, rw + mt * 16 + qd * 4, nt * 16 + mcol, v);
        }
    }
    __syncthreads();

    // ===== layer h2: x3 = tanh(h2 @ x2 + b2)  (N=80pad, K=96pad) =====
    f32x4 acc2[5][2];
#pragma unroll
    for (int nt = 0; nt < 5; nt++) { acc2[nt][0] = zero4; acc2[nt][1] = zero4; }

    copyStage(wbuf[0], wimg + W_H2B, 5120, tid);           // prefetch s6
    {
        short8 ah0, al0, ah1, al1;
        readA(acts, rw, 0, lane, ah0, al0);
        readA(acts, rw + 16, 0, lane, ah1, al1);
#pragma unroll
        for (int nt = 0; nt < 5; nt++) {
            short8 bh = bfrag(wbuf[1], nt * 2, lane), bl = bfrag(wbuf[1], nt * 2 + 1, lane);
            t3(acc2[nt][0], acc2[nt][1], ah0, al0, ah1, al1, bh, bl);
        }
    }
    __syncthreads();
    copyStage(wbuf[1], wimg + W_H2C, 5120, tid);           // prefetch s7
    {
        short8 ah0, al0, ah1, al1;
        readA(acts, rw, 32, lane, ah0, al0);
        readA(acts, rw + 16, 32, lane, ah1, al1);
#pragma unroll
        for (int nt = 0; nt < 5; nt++) {
            short8 bh = bfrag(wbuf[0], nt * 2, lane), bl = bfrag(wbuf[0], nt * 2 + 1, lane);
            t3(acc2[nt][0], acc2[nt][1], ah0, al0, ah1, al1, bh, bl);
        }
    }
    __syncthreads();
    copyStage(wbuf[0], wimg + W_EF, 5120, tid);            // prefetch s8
    {
        short8 ah0, al0, ah1, al1;
        readA(acts, rw, 64, lane, ah0, al0);
        readA(acts, rw + 16, 64, lane, ah1, al1);
#pragma unroll
        for (int nt = 0; nt < 5; nt++) {
            short8 bh = bfrag(wbuf[1], nt * 2, lane), bl = bfrag(wbuf[1], nt * 2 + 1, lane);
            t3(acc2[nt][0], acc2[nt][1], ah0, al0, ah1, al1, bh, bl);
        }
    }
    // epilogue h2: tanh + write x3
#pragma unroll
    for (int nt = 0; nt < 5; nt++) {
        float bv = sbias[B2 + nt * 16 + mcol];
#pragma unroll
        for (int mt = 0; mt < 2; mt++) {
            f32x4 v = acc2[nt][mt];
            v[0] = tanh_fast(v[0] + bv); v[1] = tanh_fast(v[1] + bv);
            v[2] = tanh_fast(v[2] + bv); v[3] = tanh_fast(v[3] + bv);
            writeC(acts, rw + mt * 16 + qd * 4, nt * 16 + mcol, v);
        }
    }
    __syncthreads();

    // ===== EF: x4 = lrelu(E @ x3 + F @ x1 + bef)  (N=16pad) =====
    copyStage(wbuf[1], wimg + W_D, 4096, tid);             // prefetch s9
    f32x4 accEF[2];
    {
        float bv = sbias[BEF + mcol];
        accEF[0] = (f32x4){bv, bv, bv, bv};
        accEF[1] = accEF[0];
    }
#pragma unroll
    for (int kt = 0; kt < 3; kt++) {
        short8 ah0, al0, ah1, al1;
        readA(acts, rw, kt * 32, lane, ah0, al0);
        readA(acts, rw + 16, kt * 32, lane, ah1, al1);
        short8 bh = bfrag(wbuf[0], kt * 2, lane), bl = bfrag(wbuf[0], kt * 2 + 1, lane);
        t3(accEF[0], accEF[1], ah0, al0, ah1, al1, bh, bl);
    }
    {
        const short* Fp = wbuf[0] + 3072;
#pragma unroll
        for (int kt = 0; kt < 2; kt++) {
            short8 bh = bfrag(Fp, kt * 2, lane), bl = bfrag(Fp, kt * 2 + 1, lane);
            t3(accEF[0], accEF[1], x1h[kt][0], x1l[kt][0], x1h[kt][1], x1l[kt][1], bh, bl);
        }
    }
    short8 x4h[2], x4l[2];
#pragma unroll
    for (int mt = 0; mt < 2; mt++) {
        f32x4 v = accEF[mt];
        v[0] = lrelu(v[0]); v[1] = lrelu(v[1]); v[2] = lrelu(v[2]); v[3] = lrelu(v[3]);
        writeC(acts, rw + mt * 16 + qd * 4, 64 + mcol, v);
    }
    readA(acts, rw, 64, lane, x4h[0], x4l[0]);
    readA(acts, rw + 16, 64, lane, x4h[1], x4l[1]);
    __syncthreads();

    // ===== D: xd = D @ x4 + bd  (N=64pad, K=32pad) =====
    copyStage(wbuf[0], wimg + W_H4C0, 4096, tid);          // prefetch s10
    f32x4 accD[4][2];
#pragma unroll
    for (int nt = 0; nt < 4; nt++) {
        float bv = sbias[BD + nt * 16 + mcol];
        accD[nt][0] = (f32x4){bv, bv, bv, bv};
        accD[nt][1] = accD[nt][0];
    }
#pragma unroll
    for (int nt = 0; nt < 4; nt++) {
        short8 bh = bfrag(wbuf[1], nt * 2, lane), bl = bfrag(wbuf[1], nt * 2 + 1, lane);
        t3(accD[nt][0], accD[nt][1], x4h[0], x4l[0], x4h[1], x4l[1], bh, bl);
    }
    short8 xdh[2][2], xdl[2][2];
#pragma unroll
    for (int nt = 0; nt < 4; nt++)
#pragma unroll
        for (int mt = 0; mt < 2; mt++)
            writeC(acts, rw + mt * 16 + qd * 4, nt * 16 + mcol, accD[nt][mt]);
#pragma unroll
    for (int kt = 0; kt < 2; kt++)
#pragma unroll
        for (int mt = 0; mt < 2; mt++)
            readA(acts, rw + mt * 16, kt * 32, lane, xdh[kt][mt], xdl[kt][mt]);

    // x6 accumulator init: b5 - x1
    f32x4 x6a[4][2];
#pragma unroll
    for (int nt = 0; nt < 4; nt++) {
        float bv = sbias[B5 + nt * 16 + mcol];
#pragma unroll
        for (int mt = 0; mt < 2; mt++) {
            f32x4 v;
            v[0] = bv - x1C[nt][mt][0]; v[1] = bv - x1C[nt][mt][1];
            v[2] = bv - x1C[nt][mt][2]; v[3] = bv - x1C[nt][mt][3];
            x6a[nt][mt] = v;
        }
    }
    __syncthreads();

    // ===== h4/h5 chunked: x6 += h5[:,c] @ tanh(h4[c,:] @ xd + b4[c]) =====
    for (int c = 0; c < 4; c++) {
        // h4 chunk in wbuf[0]; prefetch h5 chunk into wbuf[1]
        copyStage(wbuf[1], wimg + W_H5C0 + c * 8192, 4096, tid);
        f32x4 acc5[2][2];
#pragma unroll
        for (int nt2 = 0; nt2 < 2; nt2++) {
            float bv = sbias[B4 + c * 32 + nt2 * 16 + mcol];
            acc5[nt2][0] = (f32x4){bv, bv, bv, bv};
            acc5[nt2][1] = acc5[nt2][0];
        }
#pragma unroll
        for (int nt2 = 0; nt2 < 2; nt2++)
#pragma unroll
            for (int kt = 0; kt < 2; kt++) {
                short8 bh = bfrag(wbuf[0], (nt2 * 2 + kt) * 2, lane);
                short8 bl = bfrag(wbuf[0], (nt2 * 2 + kt) * 2 + 1, lane);
                t3(acc5[nt2][0], acc5[nt2][1], xdh[kt][0], xdl[kt][0],
                   xdh[kt][1], xdl[kt][1], bh, bl);
            }
#pragma unroll
        for (int nt2 = 0; nt2 < 2; nt2++)
#pragma unroll
            for (int mt = 0; mt < 2; mt++) {
                f32x4 v = acc5[nt2][mt];
                v[0] = tanh_fast(v[0]); v[1] = tanh_fast(v[1]);
                v[2] = tanh_fast(v[2]); v[3] = tanh_fast(v[3]);
                writeC(acts, rw + mt * 16 + qd * 4, 64 + nt2 * 16 + mcol, v);
            }
        short8 chh[2], chl[2];
        readA(acts, rw, 64, lane, chh[0], chl[0]);
        readA(acts, rw + 16, 64, lane, chh[1], chl[1]);
        __syncthreads();

        // h5 chunk in wbuf[1]; prefetch next h4 chunk (or out) into wbuf[0]
        if (c < 3) copyStage(wbuf[0], wimg + W_H4C0 + (c + 1) * 8192, 4096, tid);
        else       copyStage(wbuf[0], wimg + W_OUT, 2048, tid);
#pragma unroll
        for (int nt = 0; nt < 4; nt++) {
            short8 bh = bfrag(wbuf[1], nt * 2, lane), bl = bfrag(wbuf[1], nt * 2 + 1, lane);
            t3(x6a[nt][0], x6a[nt][1], chh[0], chl[0], chh[1], chl[1], bh, bl);
        }
        __syncthreads();
    }

    // ===== out: x7 = lrelu(Wout @ x6 + bout)  (N=16pad, K=64pad) =====
    // write x6 pairs, read A-frags (wave-private, no barrier needed)
#pragma unroll
    for (int nt = 0; nt < 4; nt++)
#pragma unroll
        for (int mt = 0; mt < 2; mt++)
            writeC(acts, rw + mt * 16 + qd * 4, nt * 16 + mcol, x6a[nt][mt]);

    f32x4 accO[2];
    {
        float bv = sbias[BOUT + mcol];
        accO[0] = (f32x4){bv, bv, bv, bv};
        accO[1] = accO[0];
    }
#pragma unroll
    for (int kt = 0; kt < 2; kt++) {
        short8 ah0, al0, ah1, al1;
        readA(acts, rw, kt * 32, lane, ah0, al0);
        readA(acts, rw + 16, kt * 32, lane, ah1, al1);
        short8 bh = bfrag(wbuf[0], kt * 2, lane), bl = bfrag(wbuf[0], kt * 2 + 1, lane);
        t3(accO[0], accO[1], ah0, al0, ah1, al1, bh, bl);
    }
    if (mcol < 3) {
#pragma unroll
        for (int mt = 0; mt < 2; mt++) {
#pragma unroll
            for (int r = 0; r < 4; r++) {
                int g = pxbase + mt * 16 + qd * 4 + r;
                int bb = g / HW, p = g - bb * HW;
                out[(bb * 3 + mcol) * HW + p] = lrelu(accO[mt][r]);
            }
        }
    }
}

extern "C" void kernel_launch(void* const* d_in, const int* in_sizes, int n_in,
                              void* d_out, int out_size, void* d_ws, size_t ws_size,
                              hipStream_t stream)
{
    const float* xin = (const float*)d_in[0];
    float* ws = (float*)d_ws;

    setup_pack<<<1, 256, 0, stream>>>(
        (const float*)d_in[1],  (const float*)d_in[2],   // input
        (const float*)d_in[3],  (const float*)d_in[4],   // h1
        (const float*)d_in[5],  (const float*)d_in[6],   // h2
        (const float*)d_in[7],  (const float*)d_in[8],   // h3
        (const float*)d_in[9],  (const float*)d_in[10],  // h4
        (const float*)d_in[11], (const float*)d_in[12],  // h5
        (const float*)d_in[13], (const float*)d_in[14],  // out
        (const float*)d_in[15], (const float*)d_in[16],  // e1
        (const float*)d_in[17], (const float*)d_in[18],  // e2
        (const float*)d_in[19], (const float*)d_in[20],  // e3
        (const float*)d_in[21], (const float*)d_in[22],  // f1
        (const float*)d_in[23], (const float*)d_in[24],  // f2
        (const float*)d_in[25], (const float*)d_in[26],  // f3
        (const float*)d_in[27], (const float*)d_in[28],  // d1
        (const float*)d_in[29], (const float*)d_in[30],  // d2
        (const float*)d_in[31], (const float*)d_in[32],  // d3
        ws);

    fused_mfma<<<NBLK, 256, 0, stream>>>(xin, ws, (float*)d_out);
}

// Round 4
// 398.606 us; speedup vs baseline: 6.0056x; 1.3817x over previous
//
#include <hip/hip_runtime.h>

// ---------------------------------------------------------------------------
// Round 4: same MFMA structure as round 3, three changes:
//  1. setup split: setup_small (1 blk: affine collapse + bias + E/F/D images)
//     + setup_big (71 blks: all raw-weight fragment images in parallel).
//  2. Truncation-based hi/lo split for activations (lo catches the exact
//     residual, so hi may truncate): packpair = and+sub+v_perm (3 VALU);
//     readA unpack = 8 v_perm_b32.
//  3. Scalarized pixel coords (each block lives in ONE image row) + abs/min
//     reflect in the sw gather.
// ---------------------------------------------------------------------------

#define IW 384
#define HW (384 * 384)           // 147456
#define NPIX (4 * HW)            // 589824
#define MTILE 128                // pixels per block (divides IW: blocks never straddle rows)
#define NBLK (NPIX / MTILE)      // 4608
#define KST 108                  // act row stride (dwords): 108%32=12 -> 2-way-free banks

typedef __attribute__((ext_vector_type(8))) short short8;
typedef __attribute__((ext_vector_type(4))) float f32x4;
typedef __attribute__((ext_vector_type(4))) unsigned int uint4_;

#define MFMA16(A, B, C) __builtin_amdgcn_mfma_f32_16x16x32_bf16((A), (B), (C), 0, 0, 0)

// bias table offsets (dwords in ws)
#define BA   0
#define B1   64
#define B2   144
#define BEF  224
#define BD   240
#define B4   304
#define B5   432
#define BOUT 496
#define BIAS_TOT 512

// weight image segment offsets (shorts, after the 512-dword bias table)
#define W_A0   0
#define W_A1   4096
#define W_A2   8192
#define W_H1A  12288
#define W_H1B  17408
#define W_H2A  22528
#define W_H2B  27648
#define W_H2C  32768
#define W_EF   37888     // E: 3072 shorts, then F: 2048 shorts
#define W_D    43008
#define W_H4C0 47104     // h4 chunk c at 47104 + c*8192
#define W_H5C0 51200     // h5 chunk c at 51200 + c*8192
#define W_OUT  79872
#define W_TOT  81920

__device__ __forceinline__ float lrelu(float v) { return v >= 0.0f ? v : 0.01f * v; }

__device__ __forceinline__ float tanh_fast(float v) {
    float e = __expf(2.0f * v);
    return 1.0f - 2.0f * __builtin_amdgcn_rcpf(e + 1.0f);
}

// RNE bf16 (setup-side only; cost irrelevant there)
__device__ __forceinline__ unsigned short f2b(float f) {
    union { float f; unsigned u; } v; v.f = f;
    unsigned r = v.u + 0x7fffu + ((v.u >> 16) & 1u);
    return (unsigned short)(r >> 16);
}
__device__ __forceinline__ float b2f(unsigned short h) {
    union { unsigned u; float f; } v; v.u = ((unsigned)h) << 16;
    return v.f;
}

// main-kernel pair pack: (lo16<<16)|hi16, truncation split (3 VALU)
__device__ __forceinline__ unsigned packpair(float x) {
    unsigned u = __float_as_uint(x);
    unsigned l = __float_as_uint(x - __uint_as_float(u & 0xffff0000u));
    return __builtin_amdgcn_perm(l, u, 0x07060302u);   // [l.b3,l.b2,u.b3,u.b2]
}

// ---------------------------------------------------------------------------
// setup_small: collapse affine chains, bias table, E/F/D fragment images.
// ---------------------------------------------------------------------------
__global__ void setup_small(
    const float* __restrict__ W_input, const float* __restrict__ b_input,
    const float* __restrict__ W_h1,  const float* __restrict__ b_h1,
    const float* __restrict__ W_h2,  const float* __restrict__ b_h2,
    const float* __restrict__ W_h3,  const float* __restrict__ b_h3,
    const float* __restrict__ W_h4,  const float* __restrict__ b_h4,
    const float* __restrict__ W_h5,  const float* __restrict__ b_h5,
    const float* __restrict__ W_out, const float* __restrict__ b_out,
    const float* __restrict__ W_e1,  const float* __restrict__ b_e1,
    const float* __restrict__ W_e2,  const float* __restrict__ b_e2,
    const float* __restrict__ W_e3,  const float* __restrict__ b_e3,
    const float* __restrict__ W_f1,  const float* __restrict__ b_f1,
    const float* __restrict__ W_f2,  const float* __restrict__ b_f2,
    const float* __restrict__ W_f3,  const float* __restrict__ b_f3,
    const float* __restrict__ W_d1,  const float* __restrict__ b_d1,
    const float* __restrict__ W_d2,  const float* __restrict__ b_d2,
    const float* __restrict__ W_d3,  const float* __restrict__ b_d3,
    float* __restrict__ ws)
{
    __shared__ float M1[675];   // W_e3 @ W_e2   (3 x 225)
    __shared__ float MF[450];   // W_f3 @ W_f2   (3 x 150)
    __shared__ float A1[450];   // W_d2 @ W_d1   (150 x 3)
    __shared__ float A2[150];   // W_d3 @ A1     (50 x 3)
    __shared__ float ue[75], uf[50], v1[150], v2[50];
    __shared__ float sE[225];   // (3 x 75)
    __shared__ float sF[150];   // (3 x 50)
    __shared__ float sD[150];   // (50 x 3)
    __shared__ float sbd[50];
    __shared__ float sbef[3];

    const int tid = threadIdx.x;
    const int NT = 256;

    // ---- phase 1 ----
    for (int o = tid; o < 675; o += NT) {
        int r = o / 225, c = o % 225; float s = 0.0f;
        for (int t = 0; t < 75; t++) s += W_e3[r * 75 + t] * W_e2[t * 225 + c];
        M1[o] = s;
    }
    for (int o = tid; o < 450; o += NT) {
        int r = o / 150, c = o % 150; float s = 0.0f;
        for (int t = 0; t < 50; t++) s += W_f3[r * 50 + t] * W_f2[t * 150 + c];
        MF[o] = s;
    }
    for (int o = tid; o < 450; o += NT) {
        int r = o / 3, c = o % 3; float s = 0.0f;
        for (int t = 0; t < 50; t++) s += W_d2[r * 50 + t] * W_d1[t * 3 + c];
        A1[o] = s;
    }
    for (int o = tid; o < 75; o += NT) {
        float s = b_e2[o];
        for (int t = 0; t < 225; t++) s += W_e2[o * 225 + t] * b_e1[t];
        ue[o] = s;
    }
    for (int o = tid; o < 50; o += NT) {
        float s = b_f2[o];
        for (int t = 0; t < 150; t++) s += W_f2[o * 150 + t] * b_f1[t];
        uf[o] = s;
    }
    for (int o = tid; o < 150; o += NT) {
        float s = b_d2[o];
        for (int t = 0; t < 50; t++) s += W_d2[o * 50 + t] * b_d1[t];
        v1[o] = s;
    }
    __syncthreads();

    // ---- phase 2 ----
    for (int o = tid; o < 225; o += NT) {  // sE = M1 @ W_e1
        int r = o / 75, c = o % 75; float s = 0.0f;
        for (int t = 0; t < 225; t++) s += M1[r * 225 + t] * W_e1[t * 75 + c];
        sE[o] = s;
    }
    for (int o = tid; o < 150; o += NT) {  // sF = MF @ W_f1
        int r = o / 50, c = o % 50; float s = 0.0f;
        for (int t = 0; t < 150; t++) s += MF[r * 150 + t] * W_f1[t * 50 + c];
        sF[o] = s;
    }
    for (int o = tid; o < 150; o += NT) {  // A2 = W_d3 @ A1
        int r = o / 3, c = o % 3; float s = 0.0f;
        for (int t = 0; t < 150; t++) s += W_d3[r * 150 + t] * A1[t * 3 + c];
        A2[o] = s;
    }
    for (int o = tid; o < 50; o += NT) {   // v2 = W_d3 @ v1 + b_d3
        float s = b_d3[o];
        for (int t = 0; t < 150; t++) s += W_d3[o * 150 + t] * v1[t];
        v2[o] = s;
    }
    for (int o = tid; o < 3; o += NT) {    // bef = be + bf
        float se = b_e3[o];
        for (int t = 0; t < 75; t++) se += W_e3[o * 75 + t] * ue[t];
        float sf = b_f3[o];
        for (int t = 0; t < 50; t++) sf += W_f3[o * 50 + t] * uf[t];
        sbef[o] = se + sf;
    }
    __syncthreads();

    // ---- phase 3 ----
    for (int o = tid; o < 150; o += NT) {  // sD = W_h3 @ A2
        int r = o / 3, c = o % 3; float s = 0.0f;
        for (int t = 0; t < 50; t++) s += W_h3[r * 50 + t] * A2[t * 3 + c];
        sD[o] = s;
    }
    for (int o = tid; o < 50; o += NT) {   // sbd = W_h3 @ v2 + b_h3
        float s = b_h3[o];
        for (int t = 0; t < 50; t++) s += W_h3[o * 50 + t] * v2[t];
        sbd[o] = s;
    }
    __syncthreads();

    // ---- phase 4: bias table ----
    for (int i = tid; i < BIAS_TOT; i += NT) ws[i] = 0.0f;
    __syncthreads();
    for (int i = tid; i < 50;  i += NT) ws[BA  + i] = b_input[i];
    for (int i = tid; i < 75;  i += NT) ws[B1  + i] = b_h1[i];
    for (int i = tid; i < 75;  i += NT) ws[B2  + i] = b_h2[i];
    for (int i = tid; i < 3;   i += NT) ws[BEF + i] = sbef[i];
    for (int i = tid; i < 50;  i += NT) ws[BD  + i] = sbd[i];
    for (int i = tid; i < 125; i += NT) ws[B4  + i] = b_h4[i];
    for (int i = tid; i < 50;  i += NT) ws[B5  + i] = b_h5[i];
    for (int i = tid; i < 3;   i += NT) ws[BOUT + i] = b_out[i];

    // ---- phase 5: E/F/D fragment images (small, need sE/sF/sD) ----
    short* wimg = (short*)(ws + BIAS_TOT);
    const int soff2[3] = {W_EF, W_EF + 3072, W_D};
    const int sKT2[3]  = {3, 2, 1};
    for (int s = 0; s < 3; s++) {
        int tot = (s == 2 ? 4 : 1) * sKT2[s] * 1024;
        short* dst = wimg + soff2[s];
        int kts = sKT2[s];
        for (int i = tid; i < tot; i += NT) {
            int j = i & 7, lane = (i >> 3) & 63, frag = i >> 9, pl = frag & 1;
            int ktnt = frag >> 1, kt = ktnt % kts, nt = ktnt / kts;
            int n = nt * 16 + (lane & 15);
            int k = kt * 32 + (lane >> 4) * 8 + j;
            float v = 0.0f;
            if (s == 0)      { if (n < 3  && k < 75) v = sE[n * 75 + k]; }
            else if (s == 1) { if (n < 3  && k < 50) v = sF[n * 50 + k]; }
            else             { if (n < 50 && k < 3)  v = sD[n * 3 + k]; }
            unsigned short hi = f2b(v);
            dst[i] = (short)(pl ? f2b(v - b2f(hi)) : hi);
        }
    }
}

// ---------------------------------------------------------------------------
// setup_big: raw-weight fragment images, 71 blocks x 256 threads x 4 shorts.
// ---------------------------------------------------------------------------
__global__ void setup_big(
    const float* __restrict__ W_input, const float* __restrict__ W_h1,
    const float* __restrict__ W_h2,  const float* __restrict__ W_h4,
    const float* __restrict__ W_h5,  const float* __restrict__ W_out,
    float* __restrict__ ws)
{
    const int soff[17] = {W_A0,W_A1,W_A2,W_H1A,W_H1B,W_H2A,W_H2B,W_H2C,
                          W_H4C0,W_H5C0,W_H4C0+8192,W_H5C0+8192,
                          W_H4C0+16384,W_H5C0+16384,W_H4C0+24576,W_H5C0+24576,W_OUT};
    const int slay[17] = {0,0,0,1,1,2,2,2, 6,7,6,7,6,7,6,7, 8};
    const int sNT[17]  = {4,4,4,5,5,5,5,5, 2,4,2,4,2,4,2,4, 1};
    const int sKTS[17] = {1,1,1,1,1,1,1,1, 2,1,2,1,2,1,2,1, 2};
    const int snb[17]  = {0,0,0,0,0,0,0,0, 0,0,32,0,64,0,96,0, 0};
    const int skb[17]  = {0,32,64,0,32,0,32,64, 0,0,0,32,0,64,0,96, 0};

    int seg = 0, local = blockIdx.x;
    while (seg < 16 && local >= sNT[seg] * sKTS[seg]) { local -= sNT[seg] * sKTS[seg]; seg++; }
    const int kts = sKTS[seg];
    const int kt = local % kts, nt = local / kts;
    const int lay = slay[seg];
    const int nbase = snb[seg] + nt * 16;
    const int kbase = skb[seg] + kt * 32;
    short* dst = (short*)(ws + BIAS_TOT) + soff[seg] + local * 1024;

    for (int t = 0; t < 4; t++) {
        int i = threadIdx.x + t * 256;       // [0,1024)
        int pl = i >> 9;
        int w = i & 511;
        int lane = w >> 3, j = w & 7;
        int n = nbase + (lane & 15);
        int k = kbase + (lane >> 4) * 8 + j;
        float v = 0.0f;
        switch (lay) {
            case 0: if (n < 50  && k < 75)  v = W_input[n * 75 + k]; break;
            case 1: if (n < 75  && k < 50)  v = W_h1[n * 50 + k]; break;
            case 2: if (n < 75  && k < 75)  v = W_h2[n * 75 + k]; break;
            case 6: if (n < 125 && k < 50)  v = W_h4[n * 50 + k]; break;
            case 7: if (n < 50  && k < 125) v = W_h5[n * 125 + k]; break;
            case 8: if (n < 3   && k < 50)  v = W_out[n * 50 + k]; break;
        }
        unsigned short hi = f2b(v);
        dst[i] = (short)(pl ? f2b(v - b2f(hi)) : hi);
    }
}

// ---------------------------------------------------------------------------
// main kernel helpers
// ---------------------------------------------------------------------------
__device__ __forceinline__ void copyStage(short* dst, const short* src, int nsh, int tid) {
    uint4_* d = (uint4_*)dst;
    const uint4_* s = (const uint4_*)src;
    int n = nsh >> 3;
    for (int i = tid; i < n; i += 256) d[i] = s[i];
}

__device__ __forceinline__ short8 bfrag(const short* wb, int fragIdx, int lane) {
    return *(const short8*)(wb + fragIdx * 512 + lane * 8);
}

// pair dword = (lo16<<16)|hi16. hi plane: bytes [1:0]; lo plane: bytes [3:2].
__device__ __forceinline__ void readA(const unsigned int* acts, int row0, int kbase,
                                      int lane, short8& ah, short8& al) {
    int m = lane & 15, qd = lane >> 4;
    const unsigned int* p = &acts[(row0 + m) * KST + kbase + qd * 8];
    uint4_ a = *(const uint4_*)p;
    uint4_ b = *(const uint4_*)(p + 4);
    union { unsigned u[4]; short8 s; } uh, ul;
    uh.u[0] = __builtin_amdgcn_perm(a.y, a.x, 0x05040100u);
    uh.u[1] = __builtin_amdgcn_perm(a.w, a.z, 0x05040100u);
    uh.u[2] = __builtin_amdgcn_perm(b.y, b.x, 0x05040100u);
    uh.u[3] = __builtin_amdgcn_perm(b.w, b.z, 0x05040100u);
    ul.u[0] = __builtin_amdgcn_perm(a.y, a.x, 0x07060302u);
    ul.u[1] = __builtin_amdgcn_perm(a.w, a.z, 0x07060302u);
    ul.u[2] = __builtin_amdgcn_perm(b.y, b.x, 0x07060302u);
    ul.u[3] = __builtin_amdgcn_perm(b.w, b.z, 0x07060302u);
    ah = uh.s; al = ul.s;
}

__device__ __forceinline__ void writeC(unsigned int* acts, int row0q, int col, f32x4 v) {
    unsigned int* p = &acts[row0q * KST + col];
    p[0]       = packpair(v[0]);
    p[KST]     = packpair(v[1]);
    p[2 * KST] = packpair(v[2]);
    p[3 * KST] = packpair(v[3]);
}

__device__ __forceinline__ void t3(f32x4& a0, f32x4& a1,
                                   short8 ah0, short8 al0, short8 ah1, short8 al1,
                                   short8 bh, short8 bl) {
    a0 = MFMA16(ah0, bh, a0);
    a1 = MFMA16(ah1, bh, a1);
    a0 = MFMA16(al0, bh, a0);
    a1 = MFMA16(al1, bh, a1);
    a0 = MFMA16(ah0, bl, a0);
    a1 = MFMA16(ah1, bl, a1);
}

// ---------------------------------------------------------------------------
// main fused kernel
// ---------------------------------------------------------------------------
__global__ __launch_bounds__(256, 2) void fused_mfma(
    const float* __restrict__ xin,
    const float* __restrict__ ws,
    float* __restrict__ out)
{
    __shared__ unsigned int acts[MTILE * KST];   // 55296 B
    __shared__ short wbuf[2][5120];              // 20480 B
    __shared__ float sbias[BIAS_TOT];            // 2048 B

    const int tid = threadIdx.x;
    const int wv = tid >> 6;
    const int lane = tid & 63;
    const int qd = lane >> 4;
    const int mcol = lane & 15;
    const int rw = wv * 32;
    const short* wimg = (const short*)(ws + BIAS_TOT);
    const f32x4 zero4 = {0.f, 0.f, 0.f, 0.f};

    // scalar (wave-uniform) pixel coordinates: a block covers 128 consecutive
    // pixels of ONE image row (384 = 3*128, HW % 128 == 0).
    const int g0 = blockIdx.x * MTILE;
    const int bb = g0 / HW;
    const int p0 = g0 - bb * HW;
    const int yb = p0 / IW;
    const int xblk = p0 - yb * IW;
    const float* __restrict__ xb = xin + bb * 3 * HW;

    // ---- prologue ----
    for (int i = tid; i < BIAS_TOT; i += 256) sbias[i] = ws[i];
    for (int i = tid; i < MTILE * 16; i += 256) {          // zero k in [80,96)
        int r = i >> 4, k = 80 + (i & 15);
        acts[r * KST + k] = 0u;
    }
    copyStage(wbuf[0], wimg + W_A0, 4096, tid);

    // gather sw fragments (unfold, reflect pad): truncation hi/lo split
    short8 swh[3][2], swl[3][2];
#pragma unroll
    for (int mt = 0; mt < 2; mt++) {
        const int xpix = xblk + wv * 32 + mt * 16 + mcol;
#pragma unroll
        for (int kt = 0; kt < 3; kt++) {
            union { unsigned u[4]; short8 s; } uh, ul;
#pragma unroll
            for (int jj = 0; jj < 8; jj += 2) {
                unsigned v[2], l[2];
#pragma unroll
                for (int t = 0; t < 2; t++) {
                    int qq = kt * 32 + qd * 8 + jj + t;
                    float val = 0.0f;
                    if (qq < 75) {
                        int c = qq / 25, rem = qq - 25 * c;
                        int rr = rem / 5, ss = rem - 5 * rr;
                        int ty = yb + rr - 2; ty = ty < 0 ? -ty : ty;
                        ty = (766 - ty) < ty ? (766 - ty) : ty;
                        int tx = xpix + ss - 2; tx = tx < 0 ? -tx : tx;
                        tx = (766 - tx) < tx ? (766 - tx) : tx;
                        val = xb[c * HW + ty * IW + tx];
                    }
                    unsigned uv = __float_as_uint(val);
                    v[t] = uv;
                    l[t] = __float_as_uint(val - __uint_as_float(uv & 0xffff0000u));
                }
                uh.u[jj >> 1] = __builtin_amdgcn_perm(v[1], v[0], 0x07060302u);
                ul.u[jj >> 1] = __builtin_amdgcn_perm(l[1], l[0], 0x07060302u);
            }
            swh[kt][mt] = uh.s; swl[kt][mt] = ul.s;
        }
    }
    __syncthreads();                                       // stage 0 ready

    // ===== layer A: x1 = WA @ sw + bA =====
    f32x4 accA[4][2];
#pragma unroll
    for (int nt = 0; nt < 4; nt++) { accA[nt][0] = zero4; accA[nt][1] = zero4; }

    copyStage(wbuf[1], wimg + W_A1, 4096, tid);
#pragma unroll
    for (int nt = 0; nt < 4; nt++) {
        short8 bh = bfrag(wbuf[0], nt * 2, lane), bl = bfrag(wbuf[0], nt * 2 + 1, lane);
        t3(accA[nt][0], accA[nt][1], swh[0][0], swl[0][0], swh[0][1], swl[0][1], bh, bl);
    }
    __syncthreads();
    copyStage(wbuf[0], wimg + W_A2, 4096, tid);
#pragma unroll
    for (int nt = 0; nt < 4; nt++) {
        short8 bh = bfrag(wbuf[1], nt * 2, lane), bl = bfrag(wbuf[1], nt * 2 + 1, lane);
        t3(accA[nt][0], accA[nt][1], swh[1][0], swl[1][0], swh[1][1], swl[1][1], bh, bl);
    }
    __syncthreads();
    copyStage(wbuf[1], wimg + W_H1A, 5120, tid);
#pragma unroll
    for (int nt = 0; nt < 4; nt++) {
        short8 bh = bfrag(wbuf[0], nt * 2, lane), bl = bfrag(wbuf[0], nt * 2 + 1, lane);
        t3(accA[nt][0], accA[nt][1], swh[2][0], swl[2][0], swh[2][1], swl[2][1], bh, bl);
    }
    f32x4 x1C[4][2];
    short8 x1h[2][2], x1l[2][2];
#pragma unroll
    for (int nt = 0; nt < 4; nt++) {
        float bv = sbias[BA + nt * 16 + mcol];
#pragma unroll
        for (int mt = 0; mt < 2; mt++) {
            f32x4 v = accA[nt][mt];
            v[0] += bv; v[1] += bv; v[2] += bv; v[3] += bv;
            x1C[nt][mt] = v;
            writeC(acts, rw + mt * 16 + qd * 4, nt * 16 + mcol, v);
        }
    }
#pragma unroll
    for (int kt = 0; kt < 2; kt++)
#pragma unroll
        for (int mt = 0; mt < 2; mt++)
            readA(acts, rw + mt * 16, kt * 32, lane, x1h[kt][mt], x1l[kt][mt]);
    __syncthreads();

    // ===== layer h1: x2 = lrelu(h1 @ x1 + b1) =====
    f32x4 acc1[5][2];
#pragma unroll
    for (int nt = 0; nt < 5; nt++) { acc1[nt][0] = zero4; acc1[nt][1] = zero4; }

    copyStage(wbuf[0], wimg + W_H1B, 5120, tid);
#pragma unroll
    for (int nt = 0; nt < 5; nt++) {
        short8 bh = bfrag(wbuf[1], nt * 2, lane), bl = bfrag(wbuf[1], nt * 2 + 1, lane);
        t3(acc1[nt][0], acc1[nt][1], x1h[0][0], x1l[0][0], x1h[0][1], x1l[0][1], bh, bl);
    }
    __syncthreads();
    copyStage(wbuf[1], wimg + W_H2A, 5120, tid);
#pragma unroll
    for (int nt = 0; nt < 5; nt++) {
        short8 bh = bfrag(wbuf[0], nt * 2, lane), bl = bfrag(wbuf[0], nt * 2 + 1, lane);
        t3(acc1[nt][0], acc1[nt][1], x1h[1][0], x1l[1][0], x1h[1][1], x1l[1][1], bh, bl);
    }
#pragma unroll
    for (int nt = 0; nt < 5; nt++) {
        float bv = sbias[B1 + nt * 16 + mcol];
#pragma unroll
        for (int mt = 0; mt < 2; mt++) {
            f32x4 v = acc1[nt][mt];
            v[0] = lrelu(v[0] + bv); v[1] = lrelu(v[1] + bv);
            v[2] = lrelu(v[2] + bv); v[3] = lrelu(v[3] + bv);
            writeC(acts, rw + mt * 16 + qd * 4, nt * 16 + mcol, v);
        }
    }
    __syncthreads();

    // ===== layer h2: x3 = tanh(h2 @ x2 + b2) =====
    f32x4 acc2[5][2];
#pragma unroll
    for (int nt = 0; nt < 5; nt++) { acc2[nt][0] = zero4; acc2[nt][1] = zero4; }

    copyStage(wbuf[0], wimg + W_H2B, 5120, tid);
    {
        short8 ah0, al0, ah1, al1;
        readA(acts, rw, 0, lane, ah0, al0);
        readA(acts, rw + 16, 0, lane, ah1, al1);
#pragma unroll
        for (int nt = 0; nt < 5; nt++) {
            short8 bh = bfrag(wbuf[1], nt * 2, lane), bl = bfrag(wbuf[1], nt * 2 + 1, lane);
            t3(acc2[nt][0], acc2[nt][1], ah0, al0, ah1, al1, bh, bl);
        }
    }
    __syncthreads();
    copyStage(wbuf[1], wimg + W_H2C, 5120, tid);
    {
        short8 ah0, al0, ah1, al1;
        readA(acts, rw, 32, lane, ah0, al0);
        readA(acts, rw + 16, 32, lane, ah1, al1);
#pragma unroll
        for (int nt = 0; nt < 5; nt++) {
            short8 bh = bfrag(wbuf[0], nt * 2, lane), bl = bfrag(wbuf[0], nt * 2 + 1, lane);
            t3(acc2[nt][0], acc2[nt][1], ah0, al0, ah1, al1, bh, bl);
        }
    }
    __syncthreads();
    copyStage(wbuf[0], wimg + W_EF, 5120, tid);
    {
        short8 ah0, al0, ah1, al1;
        readA(acts, rw, 64, lane, ah0, al0);
        readA(acts, rw + 16, 64, lane, ah1, al1);
#pragma unroll
        for (int nt = 0; nt < 5; nt++) {
            short8 bh = bfrag(wbuf[1], nt * 2, lane), bl = bfrag(wbuf[1], nt * 2 + 1, lane);
            t3(acc2[nt][0], acc2[nt][1], ah0, al0, ah1, al1, bh, bl);
        }
    }
#pragma unroll
    for (int nt = 0; nt < 5; nt++) {
        float bv = sbias[B2 + nt * 16 + mcol];
#pragma unroll
        for (int mt = 0; mt < 2; mt++) {
            f32x4 v = acc2[nt][mt];
            v[0] = tanh_fast(v[0] + bv); v[1] = tanh_fast(v[1] + bv);
            v[2] = tanh_fast(v[2] + bv); v[3] = tanh_fast(v[3] + bv);
            writeC(acts, rw + mt * 16 + qd * 4, nt * 16 + mcol, v);
        }
    }
    __syncthreads();

    // ===== EF: x4 = lrelu(E @ x3 + F @ x1 + bef) =====
    copyStage(wbuf[1], wimg + W_D, 4096, tid);
    f32x4 accEF[2];
    {
        float bv = sbias[BEF + mcol];
        accEF[0] = (f32x4){bv, bv, bv, bv};
        accEF[1] = accEF[0];
    }
#pragma unroll
    for (int kt = 0; kt < 3; kt++) {
        short8 ah0, al0, ah1, al1;
        readA(acts, rw, kt * 32, lane, ah0, al0);
        readA(acts, rw + 16, kt * 32, lane, ah1, al1);
        short8 bh = bfrag(wbuf[0], kt * 2, lane), bl = bfrag(wbuf[0], kt * 2 + 1, lane);
        t3(accEF[0], accEF[1], ah0, al0, ah1, al1, bh, bl);
    }
    {
        const short* Fp = wbuf[0] + 3072;
#pragma unroll
        for (int kt = 0; kt < 2; kt++) {
            short8 bh = bfrag(Fp, kt * 2, lane), bl = bfrag(Fp, kt * 2 + 1, lane);
            t3(accEF[0], accEF[1], x1h[kt][0], x1l[kt][0], x1h[kt][1], x1l[kt][1], bh, bl);
        }
    }
    short8 x4h[2], x4l[2];
#pragma unroll
    for (int mt = 0; mt < 2; mt++) {
        f32x4 v = accEF[mt];
        v[0] = lrelu(v[0]); v[1] = lrelu(v[1]); v[2] = lrelu(v[2]); v[3] = lrelu(v[3]);
        writeC(acts, rw + mt * 16 + qd * 4, 64 + mcol, v);
    }
    readA(acts, rw, 64, lane, x4h[0], x4l[0]);
    readA(acts, rw + 16, 64, lane, x4h[1], x4l[1]);
    __syncthreads();

    // ===== D: xd = D @ x4 + bd =====
    copyStage(wbuf[0], wimg + W_H4C0, 4096, tid);
    f32x4 accD[4][2];
#pragma unroll
    for (int nt = 0; nt < 4; nt++) {
        float bv = sbias[BD + nt * 16 + mcol];
        accD[nt][0] = (f32x4){bv, bv, bv, bv};
        accD[nt][1] = accD[nt][0];
    }
#pragma unroll
    for (int nt = 0; nt < 4; nt++) {
        short8 bh = bfrag(wbuf[1], nt * 2, lane), bl = bfrag(wbuf[1], nt * 2 + 1, lane);
        t3(accD[nt][0], accD[nt][1], x4h[0], x4l[0], x4h[1], x4l[1], bh, bl);
    }
    short8 xdh[2][2], xdl[2][2];
#pragma unroll
    for (int nt = 0; nt < 4; nt++)
#pragma unroll
        for (int mt = 0; mt < 2; mt++)
            writeC(acts, rw + mt * 16 + qd * 4, nt * 16 + mcol, accD[nt][mt]);
#pragma unroll
    for (int kt = 0; kt < 2; kt++)
#pragma unroll
        for (int mt = 0; mt < 2; mt++)
            readA(acts, rw + mt * 16, kt * 32, lane, xdh[kt][mt], xdl[kt][mt]);

    f32x4 x6a[4][2];
#pragma unroll
    for (int nt = 0; nt < 4; nt++) {
        float bv = sbias[B5 + nt * 16 + mcol];
#pragma unroll
        for (int mt = 0; mt < 2; mt++) {
            f32x4 v;
            v[0] = bv - x1C[nt][mt][0]; v[1] = bv - x1C[nt][mt][1];
            v[2] = bv - x1C[nt][mt][2]; v[3] = bv - x1C[nt][mt][3];
            x6a[nt][mt] = v;
        }
    }
    __syncthreads();

    // ===== h4/h5 chunked: x6 += h5[:,c] @ tanh(h4[c,:] @ xd + b4[c]) =====
    for (int c = 0; c < 4; c++) {
        copyStage(wbuf[1], wimg + W_H5C0 + c * 8192, 4096, tid);
        f32x4 acc5[2][2];
#pragma unroll
        for (int nt2 = 0; nt2 < 2; nt2++) {
            float bv = sbias[B4 + c * 32 + nt2 * 16 + mcol];
            acc5[nt2][0] = (f32x4){bv, bv, bv, bv};
            acc5[nt2][1] = acc5[nt2][0];
        }
#pragma unroll
        for (int nt2 = 0; nt2 < 2; nt2++)
#pragma unroll
            for (int kt = 0; kt < 2; kt++) {
                short8 bh = bfrag(wbuf[0], (nt2 * 2 + kt) * 2, lane);
                short8 bl = bfrag(wbuf[0], (nt2 * 2 + kt) * 2 + 1, lane);
                t3(acc5[nt2][0], acc5[nt2][1], xdh[kt][0], xdl[kt][0],
                   xdh[kt][1], xdl[kt][1], bh, bl);
            }
#pragma unroll
        for (int nt2 = 0; nt2 < 2; nt2++)
#pragma unroll
            for (int mt = 0; mt < 2; mt++) {
                f32x4 v = acc5[nt2][mt];
                v[0] = tanh_fast(v[0]); v[1] = tanh_fast(v[1]);
                v[2] = tanh_fast(v[2]); v[3] = tanh_fast(v[3]);
                writeC(acts, rw + mt * 16 + qd * 4, 64 + nt2 * 16 + mcol, v);
            }
        short8 chh[2], chl[2];
        readA(acts, rw, 64, lane, chh[0], chl[0]);
        readA(acts, rw + 16, 64, lane, chh[1], chl[1]);
        __syncthreads();

        if (c < 3) copyStage(wbuf[0], wimg + W_H4C0 + (c + 1) * 8192, 4096, tid);
        else       copyStage(wbuf[0], wimg + W_OUT, 2048, tid);
#pragma unroll
        for (int nt = 0; nt < 4; nt++) {
            short8 bh = bfrag(wbuf[1], nt * 2, lane), bl = bfrag(wbuf[1], nt * 2 + 1, lane);
            t3(x6a[nt][0], x6a[nt][1], chh[0], chl[0], chh[1], chl[1], bh, bl);
        }
        __syncthreads();
    }

    // ===== out: x7 = lrelu(Wout @ x6 + bout) =====
#pragma unroll
    for (int nt = 0; nt < 4; nt++)
#pragma unroll
        for (int mt = 0; mt < 2; mt++)
            writeC(acts, rw + mt * 16 + qd * 4, nt * 16 + mcol, x6a[nt][mt]);

    f32x4 accO[2];
    {
        float bv = sbias[BOUT + mcol];
        accO[0] = (f32x4){bv, bv, bv, bv};
        accO[1] = accO[0];
    }
#pragma unroll
    for (int kt = 0; kt < 2; kt++) {
        short8 ah0, al0, ah1, al1;
        readA(acts, rw, kt * 32, lane, ah0, al0);
        readA(acts, rw + 16, kt * 32, lane, ah1, al1);
        short8 bh = bfrag(wbuf[0], kt * 2, lane), bl = bfrag(wbuf[0], kt * 2 + 1, lane);
        t3(accO[0], accO[1], ah0, al0, ah1, al1, bh, bl);
    }
    if (mcol < 3) {
#pragma unroll
        for (int mt = 0; mt < 2; mt++) {
#pragma unroll
            for (int r = 0; r < 4; r++) {
                int p = p0 + wv * 32 + mt * 16 + qd * 4 + r;
                out[(bb * 3 + mcol) * HW + p] = lrelu(accO[mt][r]);
            }
        }
    }
}

extern "C" void kernel_launch(void* const* d_in, const int* in_sizes, int n_in,
                              void* d_out, int out_size, void* d_ws, size_t ws_size,
                              hipStream_t stream)
{
    const float* xin = (const float*)d_in[0];
    float* ws = (float*)d_ws;

    setup_small<<<1, 256, 0, stream>>>(
        (const float*)d_in[1],  (const float*)d_in[2],   // input
        (const float*)d_in[3],  (const float*)d_in[4],   // h1
        (const float*)d_in[5],  (const float*)d_in[6],   // h2
        (const float*)d_in[7],  (const float*)d_in[8],   // h3
        (const float*)d_in[9],  (const float*)d_in[10],  // h4
        (const float*)d_in[11], (const float*)d_in[12],  // h5
        (const float*)d_in[13], (const float*)d_in[14],  // out
        (const float*)d_in[15], (const float*)d_in[16],  // e1
        (const float*)d_in[17], (const float*)d_in[18],  // e2
        (const float*)d_in[19], (const float*)d_in[20],  // e3
        (const float*)d_in[21], (const float*)d_in[22],  // f1
        (const float*)d_in[23], (const float*)d_in[24],  // f2
        (const float*)d_in[25], (const float*)d_in[26],  // f3
        (const float*)d_in[27], (const float*)d_in[28],  // d1
        (const float*)d_in[29], (const float*)d_in[30],  // d2
        (const float*)d_in[31], (const float*)d_in[32],  // d3
        ws);

    setup_big<<<71, 256, 0, stream>>>(
        (const float*)d_in[1],  (const float*)d_in[3],   // W_input, W_h1
        (const float*)d_in[5],  (const float*)d_in[9],   // W_h2, W_h4
        (const float*)d_in[11], (const float*)d_in[13],  // W_h5, W_out
        ws);

    fused_mfma<<<NBLK, 256, 0, stream>>>(xin, ws, (float*)d_out);
}

// Round 5
// 288.999 us; speedup vs baseline: 8.2833x; 1.3793x over previous
//
#include <hip/hip_runtime.h>

// ---------------------------------------------------------------------------
// Round 5: fp16 datapath.
//  - Single-fp16 activations (RNE, rel err 2^-11) packed as (f, f+16) feature
//    pairs per LDS dword; acts array 26.6 KB -> 48 KB/block -> 3 blocks/CU.
//  - Single-fp16 weights for raw layers (A,h1,h2,h4,h5,out); hi/lo fp16 pairs
//    only for collapsed E/F/D (large-magnitude entries).
//  - MFMA count 480 -> 178; B-frag LDS traffic 160 KB -> 89 KB per wave.
//  - Setup merged into one kernel: blocks 0..70 pack single-plane fragment
//    images; block 71 (1024 thr) does affine collapse + bias + E/F/D images.
// ---------------------------------------------------------------------------

#define IW 384
#define HW (384 * 384)           // 147456
#define NPIX (4 * HW)            // 589824
#define MTILE 128
#define NBLK (NPIX / MTILE)      // 4608
#define AST 52                   // acts row stride in dwords (48 data + 4 pad)

typedef _Float16 half8 __attribute__((ext_vector_type(8)));
typedef __attribute__((ext_vector_type(4))) float f32x4;
typedef __attribute__((ext_vector_type(4))) unsigned int uint4_;

#define MFMAH(A, B, C) __builtin_amdgcn_mfma_f32_16x16x32_f16((A), (B), (C), 0, 0, 0)

// bias table offsets (dwords in ws)
#define BA   0
#define B1   64
#define B2   144
#define BEF  224
#define BD   240
#define B4   304
#define B5   432
#define BOUT 496
#define BIAS_TOT 512

// weight image segment offsets (shorts, after bias table). frag = 512 shorts.
#define W_A0   0        // 4 frags single (nt0..3, k-tile 0)
#define W_A1   2048
#define W_A2   4096
#define W_H1A  6144     // 5 frags
#define W_H1B  8704
#define W_H2A  11264
#define W_H2B  13824
#define W_H2C  16384
#define W_EF   18944    // E: 6 frags hi/lo (kt-major), F: 4 frags at +3072
#define W_D    24064    // 8 frags hi/lo (nt-major)
#define W_H4C0 28160    // chunk c: h4 at 28160+c*4096 (4 frags, idx nt2*2+kt)
#define W_H5C0 30208    //          h5 at 30208+c*4096 (4 frags, idx nt)
#define W_OUT  44544    // 2 frags (idx kt)
#define W_TOT  45568

__device__ __forceinline__ float lrelu(float v) { return v >= 0.0f ? v : 0.01f * v; }

__device__ __forceinline__ float tanh_fast(float v) {
    float e = __expf(2.0f * v);
    return 1.0f - 2.0f * __builtin_amdgcn_rcpf(e + 1.0f);
}

__device__ __forceinline__ unsigned short f2h_bits(float v) {
    union { _Float16 h; unsigned short s; } u; u.h = (_Float16)v; return u.s;
}
__device__ __forceinline__ float h2f_bits(unsigned short s) {
    union { _Float16 h; unsigned short s; } u; u.s = s; return (float)u.h;
}

// ---------------------------------------------------------------------------
// setup_all: blocks 0..70 pack single-fp16 fragment images of raw weights;
// block 71 does affine collapse + bias table + E/F/D hi/lo images (1024 thr).
// ---------------------------------------------------------------------------
__global__ void setup_all(
    const float* __restrict__ W_input, const float* __restrict__ b_input,
    const float* __restrict__ W_h1,  const float* __restrict__ b_h1,
    const float* __restrict__ W_h2,  const float* __restrict__ b_h2,
    const float* __restrict__ W_h3,  const float* __restrict__ b_h3,
    const float* __restrict__ W_h4,  const float* __restrict__ b_h4,
    const float* __restrict__ W_h5,  const float* __restrict__ b_h5,
    const float* __restrict__ W_out, const float* __restrict__ b_out,
    const float* __restrict__ W_e1,  const float* __restrict__ b_e1,
    const float* __restrict__ W_e2,  const float* __restrict__ b_e2,
    const float* __restrict__ W_e3,  const float* __restrict__ b_e3,
    const float* __restrict__ W_f1,  const float* __restrict__ b_f1,
    const float* __restrict__ W_f2,  const float* __restrict__ b_f2,
    const float* __restrict__ W_f3,  const float* __restrict__ b_f3,
    const float* __restrict__ W_d1,  const float* __restrict__ b_d1,
    const float* __restrict__ W_d2,  const float* __restrict__ b_d2,
    const float* __restrict__ W_d3,  const float* __restrict__ b_d3,
    float* __restrict__ ws)
{
    const int tid = threadIdx.x;
    short* wimg = (short*)(ws + BIAS_TOT);

    if (blockIdx.x < 71) {
        // ---- single-plane fragment packing: one frag (512 shorts) per block
        const int soff[17] = {W_A0,W_A1,W_A2, W_H1A,W_H1B, W_H2A,W_H2B,W_H2C,
                              W_H4C0,W_H5C0, W_H4C0+4096,W_H5C0+4096,
                              W_H4C0+8192,W_H5C0+8192, W_H4C0+12288,W_H5C0+12288,
                              W_OUT};
        const int slay[17] = {0,0,0, 1,1, 2,2,2, 6,7, 6,7, 6,7, 6,7, 8};
        const int sNT[17]  = {4,4,4, 5,5, 5,5,5, 2,4, 2,4, 2,4, 2,4, 1};
        const int sKTS[17] = {1,1,1, 1,1, 1,1,1, 2,1, 2,1, 2,1, 2,1, 2};
        const int snb[17]  = {0,0,0, 0,0, 0,0,0, 0,0, 32,0, 64,0, 96,0, 0};
        const int skb[17]  = {0,32,64, 0,32, 0,32,64, 0,0, 0,32, 0,64, 0,96, 0};

        int seg = 0, local = blockIdx.x;
        while (seg < 16 && local >= sNT[seg] * sKTS[seg]) { local -= sNT[seg] * sKTS[seg]; seg++; }
        const int kts = sKTS[seg];
        const int kt = local % kts, nt = local / kts;
        const int lay = slay[seg];
        short* dst = wimg + soff[seg] + local * 512;

        if (tid < 512) {
            int j = tid & 7, lane = tid >> 3;
            int n = snb[seg] + nt * 16 + (lane & 15);
            int k = skb[seg] + kt * 32 + (lane >> 4) * 8 + j;
            float v = 0.0f;
            switch (lay) {
                case 0: if (n < 50  && k < 75)  v = W_input[n * 75 + k]; break;
                case 1: if (n < 75  && k < 50)  v = W_h1[n * 50 + k]; break;
                case 2: if (n < 75  && k < 75)  v = W_h2[n * 75 + k]; break;
                case 6: if (n < 125 && k < 50)  v = W_h4[n * 50 + k]; break;
                case 7: if (n < 50  && k < 125) v = W_h5[n * 125 + k]; break;
                case 8: if (n < 3   && k < 50)  v = W_out[n * 50 + k]; break;
            }
            dst[tid] = (short)f2h_bits(v);
        }
        return;
    }

    // ---- block 71: affine collapse (1024 threads) ----
    __shared__ float M1[675];   // W_e3 @ W_e2   (3 x 225)
    __shared__ float MF[450];   // W_f3 @ W_f2   (3 x 150)
    __shared__ float A1[450];   // W_d2 @ W_d1   (150 x 3)
    __shared__ float A2[150];   // W_d3 @ A1     (50 x 3)
    __shared__ float ue[75], uf[50], v1[150], v2[50];
    __shared__ float sE[225], sF[150], sD[150];
    __shared__ float sbd[50], sbef[3];
    const int NT = 1024;

    for (int o = tid; o < 675; o += NT) {
        int r = o / 225, c = o % 225; float s = 0.0f;
        for (int t = 0; t < 75; t++) s += W_e3[r * 75 + t] * W_e2[t * 225 + c];
        M1[o] = s;
    }
    for (int o = tid; o < 450; o += NT) {
        int r = o / 150, c = o % 150; float s = 0.0f;
        for (int t = 0; t < 50; t++) s += W_f3[r * 50 + t] * W_f2[t * 150 + c];
        MF[o] = s;
    }
    for (int o = tid; o < 450; o += NT) {
        int r = o / 3, c = o % 3; float s = 0.0f;
        for (int t = 0; t < 50; t++) s += W_d2[r * 50 + t] * W_d1[t * 3 + c];
        A1[o] = s;
    }
    for (int o = tid; o < 75; o += NT) {
        float s = b_e2[o];
        for (int t = 0; t < 225; t++) s += W_e2[o * 225 + t] * b_e1[t];
        ue[o] = s;
    }
    for (int o = tid; o < 50; o += NT) {
        float s = b_f2[o];
        for (int t = 0; t < 150; t++) s += W_f2[o * 150 + t] * b_f1[t];
        uf[o] = s;
    }
    for (int o = tid; o < 150; o += NT) {
        float s = b_d2[o];
        for (int t = 0; t < 50; t++) s += W_d2[o * 50 + t] * b_d1[t];
        v1[o] = s;
    }
    __syncthreads();

    for (int o = tid; o < 225; o += NT) {
        int r = o / 75, c = o % 75; float s = 0.0f;
        for (int t = 0; t < 225; t++) s += M1[r * 225 + t] * W_e1[t * 75 + c];
        sE[o] = s;
    }
    for (int o = tid; o < 150; o += NT) {
        int r = o / 50, c = o % 50; float s = 0.0f;
        for (int t = 0; t < 150; t++) s += MF[r * 150 + t] * W_f1[t * 50 + c];
        sF[o] = s;
    }
    for (int o = tid; o < 150; o += NT) {
        int r = o / 3, c = o % 3; float s = 0.0f;
        for (int t = 0; t < 150; t++) s += W_d3[r * 150 + t] * A1[t * 3 + c];
        A2[o] = s;
    }
    for (int o = tid; o < 50; o += NT) {
        float s = b_d3[o];
        for (int t = 0; t < 150; t++) s += W_d3[o * 150 + t] * v1[t];
        v2[o] = s;
    }
    for (int o = tid; o < 3; o += NT) {
        float se = b_e3[o];
        for (int t = 0; t < 75; t++) se += W_e3[o * 75 + t] * ue[t];
        float sf = b_f3[o];
        for (int t = 0; t < 50; t++) sf += W_f3[o * 50 + t] * uf[t];
        sbef[o] = se + sf;
    }
    __syncthreads();

    for (int o = tid; o < 150; o += NT) {
        int r = o / 3, c = o % 3; float s = 0.0f;
        for (int t = 0; t < 50; t++) s += W_h3[r * 50 + t] * A2[t * 3 + c];
        sD[o] = s;
    }
    for (int o = tid; o < 50; o += NT) {
        float s = b_h3[o];
        for (int t = 0; t < 50; t++) s += W_h3[o * 50 + t] * v2[t];
        sbd[o] = s;
    }
    __syncthreads();

    // bias table
    for (int i = tid; i < BIAS_TOT; i += NT) ws[i] = 0.0f;
    __syncthreads();
    for (int i = tid; i < 50;  i += NT) ws[BA  + i] = b_input[i];
    for (int i = tid; i < 75;  i += NT) ws[B1  + i] = b_h1[i];
    for (int i = tid; i < 75;  i += NT) ws[B2  + i] = b_h2[i];
    for (int i = tid; i < 3;   i += NT) ws[BEF + i] = sbef[i];
    for (int i = tid; i < 50;  i += NT) ws[BD  + i] = sbd[i];
    for (int i = tid; i < 125; i += NT) ws[B4  + i] = b_h4[i];
    for (int i = tid; i < 50;  i += NT) ws[B5  + i] = b_h5[i];
    for (int i = tid; i < 3;   i += NT) ws[BOUT + i] = b_out[i];

    // E/F/D fp16 hi/lo fragment images
    // E: 6 frags (kt-major hi/lo), F: 4 frags, D: 8 frags (nt-major hi/lo)
    for (int i = tid; i < 3072; i += NT) {
        int j = i & 7, lane = (i >> 3) & 63, frag = i >> 9, pl = frag & 1, kt = frag >> 1;
        int n = lane & 15, k = kt * 32 + (lane >> 4) * 8 + j;
        float v = (n < 3 && k < 75) ? sE[n * 75 + k] : 0.0f;
        float hi = h2f_bits(f2h_bits(v));
        wimg[W_EF + i] = (short)(pl ? f2h_bits(v - hi) : f2h_bits(v));
    }
    for (int i = tid; i < 2048; i += NT) {
        int j = i & 7, lane = (i >> 3) & 63, frag = i >> 9, pl = frag & 1, kt = frag >> 1;
        int n = lane & 15, k = kt * 32 + (lane >> 4) * 8 + j;
        float v = (n < 3 && k < 50) ? sF[n * 50 + k] : 0.0f;
        float hi = h2f_bits(f2h_bits(v));
        wimg[W_EF + 3072 + i] = (short)(pl ? f2h_bits(v - hi) : f2h_bits(v));
    }
    for (int i = tid; i < 4096; i += NT) {
        int j = i & 7, lane = (i >> 3) & 63, frag = i >> 9, pl = frag & 1, nt = frag >> 1;
        int n = nt * 16 + (lane & 15), k = (lane >> 4) * 8 + j;
        float v = (n < 50 && k < 3) ? sD[n * 3 + k] : 0.0f;
        float hi = h2f_bits(f2h_bits(v));
        wimg[W_D + i] = (short)(pl ? f2h_bits(v - hi) : f2h_bits(v));
    }
}

// ---------------------------------------------------------------------------
// main kernel helpers
// ---------------------------------------------------------------------------
__device__ __forceinline__ void copyStage(short* dst, const short* src, int nsh, int tid) {
    uint4_* d = (uint4_*)dst;
    const uint4_* s = (const uint4_*)src;
    int n = nsh >> 3;
    for (int i = tid; i < n; i += 256) d[i] = s[i];
}

__device__ __forceinline__ half8 bfragH(const short* wb, int fragIdx, int lane) {
    return *(const half8*)(wb + fragIdx * 512 + lane * 8);
}

// acts dword at [row][dcol]: low half = feature (pane base + dcol%16),
// high half = that + 16. A-frag read: lane (qd,m) k=qd*8+j.
__device__ __forceinline__ half8 readAf(const unsigned int* acts, int row0, int pane, int lane) {
    int m = lane & 15, qd = lane >> 4;
    const unsigned int* p = &acts[(row0 + m) * AST + pane + (qd & 1) * 8];
    uint4_ a = *(const uint4_*)p;
    uint4_ b = *(const uint4_*)(p + 4);
    unsigned sel = (qd >> 1) ? 0x07060302u : 0x05040100u;
    union { unsigned u[4]; half8 v; } r;
    r.u[0] = __builtin_amdgcn_perm(a.y, a.x, sel);
    r.u[1] = __builtin_amdgcn_perm(a.w, a.z, sel);
    r.u[2] = __builtin_amdgcn_perm(b.y, b.x, sel);
    r.u[3] = __builtin_amdgcn_perm(b.w, b.z, sel);
    return r.v;
}

// write feature pair (valA -> low/f, valB -> high/f+16) for 4 quad rows
__device__ __forceinline__ void writeCf(unsigned int* acts, int row0q, int dcol,
                                        f32x4 va, f32x4 vb) {
    unsigned int* p = &acts[row0q * AST + dcol];
#pragma unroll
    for (int r = 0; r < 4; r++) {
        union { _Float16 h[2]; unsigned u; } t;
        t.h[0] = (_Float16)va[r]; t.h[1] = (_Float16)vb[r];
        p[r * AST] = t.u;
    }
}

__device__ __forceinline__ void t2s(f32x4& a0, f32x4& a1, half8 x0, half8 x1, half8 b) {
    a0 = MFMAH(x0, b, a0);
    a1 = MFMAH(x1, b, a1);
}
__device__ __forceinline__ void t2p(f32x4& a0, f32x4& a1, half8 x0, half8 x1,
                                    half8 bh, half8 bl) {
    a0 = MFMAH(x0, bh, a0);
    a1 = MFMAH(x1, bh, a1);
    a0 = MFMAH(x0, bl, a0);
    a1 = MFMAH(x1, bl, a1);
}

// ---------------------------------------------------------------------------
// main fused kernel
// ---------------------------------------------------------------------------
__global__ __launch_bounds__(256, 3) void fused_mfma(
    const float* __restrict__ xin,
    const float* __restrict__ ws,
    float* __restrict__ out)
{
    __shared__ unsigned int acts[MTILE * AST];   // 26624 B
    __shared__ short wbuf[2][5120];              // 20480 B
    __shared__ float sbias[BIAS_TOT];            // 2048 B

    const int tid = threadIdx.x;
    const int wv = tid >> 6;
    const int lane = tid & 63;
    const int qd = lane >> 4;
    const int mcol = lane & 15;
    const int rw = wv * 32;
    const short* wimg = (const short*)(ws + BIAS_TOT);
    const f32x4 zero4 = {0.f, 0.f, 0.f, 0.f};

    const int g0 = blockIdx.x * MTILE;
    const int bb = g0 / HW;
    const int p0 = g0 - bb * HW;
    const int yb = p0 / IW;
    const int xblk = p0 - yb * IW;
    const float* __restrict__ xb = xin + bb * 3 * HW;

    for (int i = tid; i < BIAS_TOT; i += 256) sbias[i] = ws[i];
    copyStage(wbuf[0], wimg + W_A0, 2048, tid);

    // gather sw fragments (unfold, reflect pad), single fp16
    half8 swf[3][2];
#pragma unroll
    for (int mt = 0; mt < 2; mt++) {
        const int xpix = xblk + wv * 32 + mt * 16 + mcol;
#pragma unroll
        for (int kt = 0; kt < 3; kt++) {
            union { _Float16 h[8]; half8 v; } u;
#pragma unroll
            for (int j = 0; j < 8; j++) {
                int qq = kt * 32 + qd * 8 + j;
                float val = 0.0f;
                if (qq < 75) {
                    int c = qq / 25, rem = qq - 25 * c;
                    int rr = rem / 5, ss = rem - 5 * rr;
                    int ty = yb + rr - 2; ty = ty < 0 ? -ty : ty;
                    ty = (766 - ty) < ty ? (766 - ty) : ty;
                    int tx = xpix + ss - 2; tx = tx < 0 ? -tx : tx;
                    tx = (766 - tx) < tx ? (766 - tx) : tx;
                    val = xb[c * HW + ty * IW + tx];
                }
                u.h[j] = (_Float16)val;
            }
            swf[kt][mt] = u.v;
        }
    }
    __syncthreads();

    // ===== layer A: x1 = WA @ sw + bA =====
    f32x4 accA[4][2];
#pragma unroll
    for (int nt = 0; nt < 4; nt++) { accA[nt][0] = zero4; accA[nt][1] = zero4; }

    copyStage(wbuf[1], wimg + W_A1, 2048, tid);
#pragma unroll
    for (int nt = 0; nt < 4; nt++)
        t2s(accA[nt][0], accA[nt][1], swf[0][0], swf[0][1], bfragH(wbuf[0], nt, lane));
    __syncthreads();
    copyStage(wbuf[0], wimg + W_A2, 2048, tid);
#pragma unroll
    for (int nt = 0; nt < 4; nt++)
        t2s(accA[nt][0], accA[nt][1], swf[1][0], swf[1][1], bfragH(wbuf[1], nt, lane));
    __syncthreads();
    copyStage(wbuf[1], wimg + W_H1A, 2560, tid);
#pragma unroll
    for (int nt = 0; nt < 4; nt++)
        t2s(accA[nt][0], accA[nt][1], swf[2][0], swf[2][1], bfragH(wbuf[0], nt, lane));

    f32x4 x1C[4][2];
    half8 x1f[2][2];
#pragma unroll
    for (int nt = 0; nt < 4; nt++) {
        float bv = sbias[BA + nt * 16 + mcol];
#pragma unroll
        for (int mt = 0; mt < 2; mt++) {
            f32x4 v = accA[nt][mt];
            v[0] += bv; v[1] += bv; v[2] += bv; v[3] += bv;
            x1C[nt][mt] = v;
        }
    }
#pragma unroll
    for (int mt = 0; mt < 2; mt++) {
        writeCf(acts, rw + mt * 16 + qd * 4, mcol,      x1C[0][mt], x1C[1][mt]);
        writeCf(acts, rw + mt * 16 + qd * 4, 16 + mcol, x1C[2][mt], x1C[3][mt]);
    }
#pragma unroll
    for (int kt = 0; kt < 2; kt++)
#pragma unroll
        for (int mt = 0; mt < 2; mt++)
            x1f[kt][mt] = readAf(acts, rw + mt * 16, kt * 16, lane);
    __syncthreads();

    // ===== h1: x2 = lrelu(h1 @ x1 + b1) =====
    f32x4 acc1[5][2];
#pragma unroll
    for (int nt = 0; nt < 5; nt++) { acc1[nt][0] = zero4; acc1[nt][1] = zero4; }

    copyStage(wbuf[0], wimg + W_H1B, 2560, tid);
#pragma unroll
    for (int nt = 0; nt < 5; nt++)
        t2s(acc1[nt][0], acc1[nt][1], x1f[0][0], x1f[0][1], bfragH(wbuf[1], nt, lane));
    __syncthreads();
    copyStage(wbuf[1], wimg + W_H2A, 2560, tid);
#pragma unroll
    for (int nt = 0; nt < 5; nt++)
        t2s(acc1[nt][0], acc1[nt][1], x1f[1][0], x1f[1][1], bfragH(wbuf[0], nt, lane));
#pragma unroll
    for (int mt = 0; mt < 2; mt++) {
        f32x4 w5[5];
#pragma unroll
        for (int nt = 0; nt < 5; nt++) {
            float bv = sbias[B1 + nt * 16 + mcol];
            f32x4 v = acc1[nt][mt];
            v[0] = lrelu(v[0] + bv); v[1] = lrelu(v[1] + bv);
            v[2] = lrelu(v[2] + bv); v[3] = lrelu(v[3] + bv);
            w5[nt] = v;
        }
        writeCf(acts, rw + mt * 16 + qd * 4, mcol,      w5[0], w5[1]);
        writeCf(acts, rw + mt * 16 + qd * 4, 16 + mcol, w5[2], w5[3]);
        writeCf(acts, rw + mt * 16 + qd * 4, 32 + mcol, w5[4], zero4);
    }
    __syncthreads();

    // ===== h2: x3 = tanh(h2 @ x2 + b2) =====
    f32x4 acc2[5][2];
#pragma unroll
    for (int nt = 0; nt < 5; nt++) { acc2[nt][0] = zero4; acc2[nt][1] = zero4; }

    copyStage(wbuf[0], wimg + W_H2B, 2560, tid);
    {
        half8 a0 = readAf(acts, rw, 0, lane), a1 = readAf(acts, rw + 16, 0, lane);
#pragma unroll
        for (int nt = 0; nt < 5; nt++)
            t2s(acc2[nt][0], acc2[nt][1], a0, a1, bfragH(wbuf[1], nt, lane));
    }
    __syncthreads();
    copyStage(wbuf[1], wimg + W_H2C, 2560, tid);
    {
        half8 a0 = readAf(acts, rw, 16, lane), a1 = readAf(acts, rw + 16, 16, lane);
#pragma unroll
        for (int nt = 0; nt < 5; nt++)
            t2s(acc2[nt][0], acc2[nt][1], a0, a1, bfragH(wbuf[0], nt, lane));
    }
    __syncthreads();
    copyStage(wbuf[0], wimg + W_EF, 5120, tid);
    {
        half8 a0 = readAf(acts, rw, 32, lane), a1 = readAf(acts, rw + 16, 32, lane);
#pragma unroll
        for (int nt = 0; nt < 5; nt++)
            t2s(acc2[nt][0], acc2[nt][1], a0, a1, bfragH(wbuf[1], nt, lane));
    }
#pragma unroll
    for (int mt = 0; mt < 2; mt++) {
        f32x4 w5[5];
#pragma unroll
        for (int nt = 0; nt < 5; nt++) {
            float bv = sbias[B2 + nt * 16 + mcol];
            f32x4 v = acc2[nt][mt];
            v[0] = tanh_fast(v[0] + bv); v[1] = tanh_fast(v[1] + bv);
            v[2] = tanh_fast(v[2] + bv); v[3] = tanh_fast(v[3] + bv);
            w5[nt] = v;
        }
        writeCf(acts, rw + mt * 16 + qd * 4, mcol,      w5[0], w5[1]);
        writeCf(acts, rw + mt * 16 + qd * 4, 16 + mcol, w5[2], w5[3]);
        writeCf(acts, rw + mt * 16 + qd * 4, 32 + mcol, w5[4], zero4);
    }
    __syncthreads();

    // ===== EF: x4 = lrelu(E @ x3 + F @ x1 + bef) =====
    copyStage(wbuf[1], wimg + W_D, 4096, tid);
    f32x4 accEF[2];
    {
        float bv = sbias[BEF + mcol];
        accEF[0] = (f32x4){bv, bv, bv, bv};
        accEF[1] = accEF[0];
    }
#pragma unroll
    for (int kt = 0; kt < 3; kt++) {
        half8 a0 = readAf(acts, rw, kt * 16, lane), a1 = readAf(acts, rw + 16, kt * 16, lane);
        t2p(accEF[0], accEF[1], a0, a1,
            bfragH(wbuf[0], kt * 2, lane), bfragH(wbuf[0], kt * 2 + 1, lane));
    }
    {
        const short* Fp = wbuf[0] + 3072;
#pragma unroll
        for (int kt = 0; kt < 2; kt++)
            t2p(accEF[0], accEF[1], x1f[kt][0], x1f[kt][1],
                bfragH(Fp, kt * 2, lane), bfragH(Fp, kt * 2 + 1, lane));
    }
    half8 x4f[2];
#pragma unroll
    for (int mt = 0; mt < 2; mt++) {
        f32x4 v = accEF[mt];
        v[0] = lrelu(v[0]); v[1] = lrelu(v[1]); v[2] = lrelu(v[2]); v[3] = lrelu(v[3]);
        writeCf(acts, rw + mt * 16 + qd * 4, 32 + mcol, v, zero4);
    }
    x4f[0] = readAf(acts, rw, 32, lane);
    x4f[1] = readAf(acts, rw + 16, 32, lane);
    __syncthreads();

    // ===== D: xd = D @ x4 + bd =====
    copyStage(wbuf[0], wimg + W_H4C0, 2048, tid);
    f32x4 accD[4][2];
#pragma unroll
    for (int nt = 0; nt < 4; nt++) {
        float bv = sbias[BD + nt * 16 + mcol];
        accD[nt][0] = (f32x4){bv, bv, bv, bv};
        accD[nt][1] = accD[nt][0];
    }
#pragma unroll
    for (int nt = 0; nt < 4; nt++)
        t2p(accD[nt][0], accD[nt][1], x4f[0], x4f[1],
            bfragH(wbuf[1], nt * 2, lane), bfragH(wbuf[1], nt * 2 + 1, lane));
#pragma unroll
    for (int mt = 0; mt < 2; mt++) {
        writeCf(acts, rw + mt * 16 + qd * 4, mcol,      accD[0][mt], accD[1][mt]);
        writeCf(acts, rw + mt * 16 + qd * 4, 16 + mcol, accD[2][mt], accD[3][mt]);
    }
    half8 xdf[2][2];
#pragma unroll
    for (int kt = 0; kt < 2; kt++)
#pragma unroll
        for (int mt = 0; mt < 2; mt++)
            xdf[kt][mt] = readAf(acts, rw + mt * 16, kt * 16, lane);

    f32x4 x6a[4][2];
#pragma unroll
    for (int nt = 0; nt < 4; nt++) {
        float bv = sbias[B5 + nt * 16 + mcol];
#pragma unroll
        for (int mt = 0; mt < 2; mt++) {
            f32x4 v;
            v[0] = bv - x1C[nt][mt][0]; v[1] = bv - x1C[nt][mt][1];
            v[2] = bv - x1C[nt][mt][2]; v[3] = bv - x1C[nt][mt][3];
            x6a[nt][mt] = v;
        }
    }
    __syncthreads();

    // ===== h4/h5 chunks: x6 += h5[:,c] @ tanh(h4[c,:] @ xd + b4[c]) =====
    for (int c = 0; c < 4; c++) {
        copyStage(wbuf[1], wimg + W_H5C0 + c * 4096, 2048, tid);
        f32x4 acc5[2][2];
#pragma unroll
        for (int nt2 = 0; nt2 < 2; nt2++) {
            float bv = sbias[B4 + c * 32 + nt2 * 16 + mcol];
            acc5[nt2][0] = (f32x4){bv, bv, bv, bv};
            acc5[nt2][1] = acc5[nt2][0];
        }
#pragma unroll
        for (int nt2 = 0; nt2 < 2; nt2++)
#pragma unroll
            for (int kt = 0; kt < 2; kt++)
                t2s(acc5[nt2][0], acc5[nt2][1], xdf[kt][0], xdf[kt][1],
                    bfragH(wbuf[0], nt2 * 2 + kt, lane));
#pragma unroll
        for (int mt = 0; mt < 2; mt++) {
            f32x4 v0 = acc5[0][mt], v1 = acc5[1][mt];
            v0[0] = tanh_fast(v0[0]); v0[1] = tanh_fast(v0[1]);
            v0[2] = tanh_fast(v0[2]); v0[3] = tanh_fast(v0[3]);
            v1[0] = tanh_fast(v1[0]); v1[1] = tanh_fast(v1[1]);
            v1[2] = tanh_fast(v1[2]); v1[3] = tanh_fast(v1[3]);
            writeCf(acts, rw + mt * 16 + qd * 4, 32 + mcol, v0, v1);
        }
        half8 chf[2];
        chf[0] = readAf(acts, rw, 32, lane);
        chf[1] = readAf(acts, rw + 16, 32, lane);
        __syncthreads();

        if (c < 3) copyStage(wbuf[0], wimg + W_H4C0 + (c + 1) * 4096, 2048, tid);
        else       copyStage(wbuf[0], wimg + W_OUT, 1024, tid);
#pragma unroll
        for (int nt = 0; nt < 4; nt++)
            t2s(x6a[nt][0], x6a[nt][1], chf[0], chf[1], bfragH(wbuf[1], nt, lane));
        __syncthreads();
    }

    // ===== out: x7 = lrelu(Wout @ x6 + bout) =====
#pragma unroll
    for (int mt = 0; mt < 2; mt++) {
        writeCf(acts, rw + mt * 16 + qd * 4, mcol,      x6a[0][mt], x6a[1][mt]);
        writeCf(acts, rw + mt * 16 + qd * 4, 16 + mcol, x6a[2][mt], x6a[3][mt]);
    }
    f32x4 accO[2];
    {
        float bv = sbias[BOUT + mcol];
        accO[0] = (f32x4){bv, bv, bv, bv};
        accO[1] = accO[0];
    }
#pragma unroll
    for (int kt = 0; kt < 2; kt++) {
        half8 a0 = readAf(acts, rw, kt * 16, lane), a1 = readAf(acts, rw + 16, kt * 16, lane);
        t2s(accO[0], accO[1], a0, a1, bfragH(wbuf[0], kt, lane));
    }
    if (mcol < 3) {
#pragma unroll
        for (int mt = 0; mt < 2; mt++) {
#pragma unroll
            for (int r = 0; r < 4; r++) {
                int p = p0 + wv * 32 + mt * 16 + qd * 4 + r;
                out[(bb * 3 + mcol) * HW + p] = lrelu(accO[mt][r]);
            }
        }
    }
}

extern "C" void kernel_launch(void* const* d_in, const int* in_sizes, int n_in,
                              void* d_out, int out_size, void* d_ws, size_t ws_size,
                              hipStream_t stream)
{
    const float* xin = (const float*)d_in[0];
    float* ws = (float*)d_ws;

    setup_all<<<72, 1024, 0, stream>>>(
        (const float*)d_in[1],  (const float*)d_in[2],   // input
        (const float*)d_in[3],  (const float*)d_in[4],   // h1
        (const float*)d_in[5],  (const float*)d_in[6],   // h2
        (const float*)d_in[7],  (const float*)d_in[8],   // h3
        (const float*)d_in[9],  (const float*)d_in[10],  // h4
        (const float*)d_in[11], (const float*)d_in[12],  // h5
        (const float*)d_in[13], (const float*)d_in[14],  // out
        (const float*)d_in[15], (const float*)d_in[16],  // e1
        (const float*)d_in[17], (const float*)d_in[18],  // e2
        (const float*)d_in[19], (const float*)d_in[20],  // e3
        (const float*)d_in[21], (const float*)d_in[22],  // f1
        (const float*)d_in[23], (const float*)d_in[24],  // f2
        (const float*)d_in[25], (const float*)d_in[26],  // f3
        (const float*)d_in[27], (const float*)d_in[28],  // d1
        (const float*)d_in[29], (const float*)d_in[30],  // d2
        (const float*)d_in[31], (const float*)d_in[32],  // d3
        ws);

    fused_mfma<<<NBLK, 256, 0, stream>>>(xin, ws, (float*)d_out);
}

// Round 7
// 270.003 us; speedup vs baseline: 8.8661x; 1.0704x over previous
//
#include <hip/hip_runtime.h>

// ---------------------------------------------------------------------------
// Round 7: round 6 with the setup_collapse D-chain bug fixed (b_d1 is length
// 50, not 3 — only 3 elements were staged into LDS, corrupting v1/bd).
// fused_mfma identical to round 5/6.
// ---------------------------------------------------------------------------

#define IW 384
#define HW (384 * 384)           // 147456
#define NPIX (4 * HW)            // 589824
#define MTILE 128
#define NBLK (NPIX / MTILE)      // 4608
#define AST 52                   // acts row stride in dwords (48 data + 4 pad)

typedef _Float16 half8 __attribute__((ext_vector_type(8)));
typedef __attribute__((ext_vector_type(4))) float f32x4;
typedef __attribute__((ext_vector_type(4))) unsigned int uint4_;

#define MFMAH(A, B, C) __builtin_amdgcn_mfma_f32_16x16x32_f16((A), (B), (C), 0, 0, 0)

// bias table offsets (dwords in ws)
#define BA   0
#define B1   64
#define B2   144
#define BEF  224
#define BD   240
#define B4   304
#define B5   432
#define BOUT 496
#define BIAS_TOT 512

// weight image segment offsets (shorts, after bias table). frag = 512 shorts.
#define W_A0   0
#define W_A1   2048
#define W_A2   4096
#define W_H1A  6144
#define W_H1B  8704
#define W_H2A  11264
#define W_H2B  13824
#define W_H2C  16384
#define W_EF   18944    // E: 6 frags hi/lo (kt-major), F: 4 frags at +3072
#define W_D    24064    // 8 frags hi/lo (nt-major)
#define W_H4C0 28160    // chunk c: h4 at 28160+c*4096
#define W_H5C0 30208    //          h5 at 30208+c*4096
#define W_OUT  44544
#define W_TOT  45568

// fp32 staging (dword offsets in ws) for collapse results
#define STG_E   23296   // 225  (3 x 75)
#define STG_F   23521   // 150  (3 x 50)
#define STG_D   23671   // 150  (50 x 3)
#define STG_BE  23821   // 3
#define STG_BF  23824   // 3
#define STG_BD  23827   // 50

__device__ __forceinline__ float lrelu(float v) { return v >= 0.0f ? v : 0.01f * v; }

__device__ __forceinline__ float tanh_fast(float v) {
    float e = __expf(2.0f * v);
    return 1.0f - 2.0f * __builtin_amdgcn_rcpf(e + 1.0f);
}

__device__ __forceinline__ unsigned short f2h_bits(float v) {
    union { _Float16 h; unsigned short s; } u; u.h = (_Float16)v; return u.s;
}
__device__ __forceinline__ float h2f_bits(unsigned short s) {
    union { _Float16 h; unsigned short s; } u; u.s = s; return (float)u.h;
}

// ---------------------------------------------------------------------------
// setup_collapse: 3 blocks, one affine chain each, operands staged in LDS.
// ---------------------------------------------------------------------------
__global__ __launch_bounds__(256) void setup_collapse(
    const float* __restrict__ W_e1, const float* __restrict__ b_e1,
    const float* __restrict__ W_e2, const float* __restrict__ b_e2,
    const float* __restrict__ W_e3, const float* __restrict__ b_e3,
    const float* __restrict__ W_f1, const float* __restrict__ b_f1,
    const float* __restrict__ W_f2, const float* __restrict__ b_f2,
    const float* __restrict__ W_f3, const float* __restrict__ b_f3,
    const float* __restrict__ W_d1, const float* __restrict__ b_d1,
    const float* __restrict__ W_d2, const float* __restrict__ b_d2,
    const float* __restrict__ W_d3, const float* __restrict__ b_d3,
    const float* __restrict__ W_h3, const float* __restrict__ b_h3,
    float* __restrict__ ws)
{
    __shared__ float A[17500];
    __shared__ float B[675];
    __shared__ float C[256];
    __shared__ float Dd[256];
    __shared__ float Es[256];

    const int tid = threadIdx.x;
    const int NT = 256;

    if (blockIdx.x == 0) {
        // ================= E chain =================
        // phase A: A=W_e2 (75x225), Es=W_e3 (3x75), C=b_e1 (225)
        for (int i = tid; i < 16875; i += NT) A[i] = W_e2[i];
        for (int i = tid; i < 225;   i += NT) { Es[i] = W_e3[i]; C[i] = b_e1[i]; }
        __syncthreads();
        // M1 = W_e3 @ W_e2  (3 x 225) -> B
        for (int o = tid; o < 675; o += NT) {
            int r = o / 225, c = o % 225;
            float s0 = 0.f, s1 = 0.f, s2 = 0.f;
#pragma unroll
            for (int t = 0; t < 75; t += 3) {
                s0 += Es[r * 75 + t]     * A[t * 225 + c];
                s1 += Es[r * 75 + t + 1] * A[(t + 1) * 225 + c];
                s2 += Es[r * 75 + t + 2] * A[(t + 2) * 225 + c];
            }
            B[o] = s0 + s1 + s2;
        }
        // ue = W_e2 @ b_e1 + b_e2  (75) -> Dd
        for (int o = tid; o < 75; o += NT) {
            float s0 = 0.f, s1 = 0.f, s2 = 0.f;
#pragma unroll
            for (int t = 0; t < 225; t += 3) {
                s0 += A[o * 225 + t]     * C[t];
                s1 += A[o * 225 + t + 1] * C[t + 1];
                s2 += A[o * 225 + t + 2] * C[t + 2];
            }
            Dd[o] = b_e2[o] + s0 + s1 + s2;
        }
        __syncthreads();
        // phase B: A=W_e1 (225x75)
        for (int i = tid; i < 16875; i += NT) A[i] = W_e1[i];
        __syncthreads();
        // sE = M1 @ W_e1 (3 x 75) -> staging
        for (int o = tid; o < 225; o += NT) {
            int r = o / 75, c = o % 75;
            float s0 = 0.f, s1 = 0.f, s2 = 0.f;
#pragma unroll
            for (int t = 0; t < 225; t += 3) {
                s0 += B[r * 225 + t]     * A[t * 75 + c];
                s1 += B[r * 225 + t + 1] * A[(t + 1) * 75 + c];
                s2 += B[r * 225 + t + 2] * A[(t + 2) * 75 + c];
            }
            ws[STG_E + o] = s0 + s1 + s2;
        }
        // be = W_e3 @ ue + b_e3 (3)
        for (int o = tid; o < 3; o += NT) {
            float s = b_e3[o];
            for (int t = 0; t < 75; t++) s += Es[o * 75 + t] * Dd[t];
            ws[STG_BE + o] = s;
        }
    } else if (blockIdx.x == 1) {
        // ================= F chain =================
        // A[0..7500)=W_f2 (50x150), A[7500..15000)=W_f1 (150x50),
        // Es=W_f3 (3x50), C=b_f1 (150)
        for (int i = tid; i < 7500; i += NT) { A[i] = W_f2[i]; A[7500 + i] = W_f1[i]; }
        for (int i = tid; i < 150;  i += NT) { Es[i] = W_f3[i]; C[i] = b_f1[i]; }
        __syncthreads();
        // MF = W_f3 @ W_f2 (3 x 150) -> B
        for (int o = tid; o < 450; o += NT) {
            int r = o / 150, c = o % 150;
            float s0 = 0.f, s1 = 0.f;
#pragma unroll
            for (int t = 0; t < 50; t += 2) {
                s0 += Es[r * 50 + t]     * A[t * 150 + c];
                s1 += Es[r * 50 + t + 1] * A[(t + 1) * 150 + c];
            }
            B[o] = s0 + s1;
        }
        // uf = W_f2 @ b_f1 + b_f2 (50) -> Dd
        for (int o = tid; o < 50; o += NT) {
            float s0 = 0.f, s1 = 0.f;
#pragma unroll
            for (int t = 0; t < 150; t += 2) {
                s0 += A[o * 150 + t]     * C[t];
                s1 += A[o * 150 + t + 1] * C[t + 1];
            }
            Dd[o] = b_f2[o] + s0 + s1;
        }
        __syncthreads();
        // sF = MF @ W_f1 (3 x 50) -> staging
        for (int o = tid; o < 150; o += NT) {
            int r = o / 50, c = o % 50;
            float s0 = 0.f, s1 = 0.f;
#pragma unroll
            for (int t = 0; t < 150; t += 2) {
                s0 += B[r * 150 + t]     * A[7500 + t * 50 + c];
                s1 += B[r * 150 + t + 1] * A[7500 + (t + 1) * 50 + c];
            }
            ws[STG_F + o] = s0 + s1;
        }
        // bf = W_f3 @ uf + b_f3 (3)
        for (int o = tid; o < 3; o += NT) {
            float s = b_f3[o];
            for (int t = 0; t < 50; t++) s += Es[o * 50 + t] * Dd[t];
            ws[STG_BF + o] = s;
        }
    } else {
        // ================= D chain =================
        // A[0..7500)=W_d2 (150x50), A[7500..15000)=W_d3 (50x150),
        // A[15000..17500)=W_h3 (50x50), Es=W_d1 (50x3=150), C=b_d1 (50)
        for (int i = tid; i < 7500; i += NT) { A[i] = W_d2[i]; A[7500 + i] = W_d3[i]; }
        for (int i = tid; i < 2500; i += NT) A[15000 + i] = W_h3[i];
        for (int i = tid; i < 150;  i += NT) Es[i] = W_d1[i];
        for (int i = tid; i < 50;   i += NT) C[i] = b_d1[i];   // FIX: b_d1 has 50 elems
        __syncthreads();
        // A1 = W_d2 @ W_d1 (150 x 3) -> B
        for (int o = tid; o < 450; o += NT) {
            int r = o / 3, c = o % 3;
            float s0 = 0.f, s1 = 0.f;
#pragma unroll
            for (int t = 0; t < 50; t += 2) {
                s0 += A[r * 50 + t]     * Es[t * 3 + c];
                s1 += A[r * 50 + t + 1] * Es[(t + 1) * 3 + c];
            }
            B[o] = s0 + s1;
        }
        // v1 = W_d2 @ b_d1 + b_d2 (150) -> Dd   (inner dim 50)
        for (int o = tid; o < 150; o += NT) {
            float s0 = 0.f, s1 = 0.f;
#pragma unroll
            for (int t = 0; t < 50; t += 2) {
                s0 += A[o * 50 + t]     * C[t];
                s1 += A[o * 50 + t + 1] * C[t + 1];
            }
            Dd[o] = b_d2[o] + s0 + s1;
        }
        __syncthreads();
        // A2 = W_d3 @ A1 (50 x 3) -> Es (reuse), v2 = W_d3 @ v1 + b_d3 (50) -> C
        for (int o = tid; o < 150; o += NT) {
            int r = o / 3, c = o % 3;
            float s0 = 0.f, s1 = 0.f;
#pragma unroll
            for (int t = 0; t < 150; t += 2) {
                s0 += A[7500 + r * 150 + t]     * B[t * 3 + c];
                s1 += A[7500 + r * 150 + t + 1] * B[(t + 1) * 3 + c];
            }
            Es[o] = s0 + s1;
        }
        for (int o = tid; o < 50; o += NT) {
            float s0 = 0.f, s1 = 0.f;
#pragma unroll
            for (int t = 0; t < 150; t += 2) {
                s0 += A[7500 + o * 150 + t]     * Dd[t];
                s1 += A[7500 + o * 150 + t + 1] * Dd[t + 1];
            }
            C[o] = b_d3[o] + s0 + s1;     // v2
        }
        __syncthreads();
        // sD = W_h3 @ A2 (50 x 3) -> staging ; sbd = W_h3 @ v2 + b_h3 (50)
        for (int o = tid; o < 150; o += NT) {
            int r = o / 3, c = o % 3;
            float s0 = 0.f, s1 = 0.f;
#pragma unroll
            for (int t = 0; t < 50; t += 2) {
                s0 += A[15000 + r * 50 + t]     * Es[t * 3 + c];
                s1 += A[15000 + r * 50 + t + 1] * Es[(t + 1) * 3 + c];
            }
            ws[STG_D + o] = s0 + s1;
        }
        for (int o = tid; o < 50; o += NT) {
            float s0 = 0.f, s1 = 0.f;
#pragma unroll
            for (int t = 0; t < 50; t += 2) {
                s0 += A[15000 + o * 50 + t]     * C[t];
                s1 += A[15000 + o * 50 + t + 1] * C[t + 1];
            }
            ws[STG_BD + o] = b_h3[o] + s0 + s1;
        }
    }
}

// ---------------------------------------------------------------------------
// setup_pack: blocks 0..70 raw-weight fp16 frag images; block 71 bias table
// + E/F/D hi/lo images from fp32 staging.
// ---------------------------------------------------------------------------
__global__ __launch_bounds__(512) void setup_pack(
    const float* __restrict__ W_input, const float* __restrict__ b_input,
    const float* __restrict__ W_h1,  const float* __restrict__ b_h1,
    const float* __restrict__ W_h2,  const float* __restrict__ b_h2,
    const float* __restrict__ W_h4,  const float* __restrict__ b_h4,
    const float* __restrict__ W_h5,  const float* __restrict__ b_h5,
    const float* __restrict__ W_out, const float* __restrict__ b_out,
    float* __restrict__ ws)
{
    const int tid = threadIdx.x;
    short* wimg = (short*)(ws + BIAS_TOT);

    if (blockIdx.x < 71) {
        const int soff[17] = {W_A0,W_A1,W_A2, W_H1A,W_H1B, W_H2A,W_H2B,W_H2C,
                              W_H4C0,W_H5C0, W_H4C0+4096,W_H5C0+4096,
                              W_H4C0+8192,W_H5C0+8192, W_H4C0+12288,W_H5C0+12288,
                              W_OUT};
        const int slay[17] = {0,0,0, 1,1, 2,2,2, 6,7, 6,7, 6,7, 6,7, 8};
        const int sNT[17]  = {4,4,4, 5,5, 5,5,5, 2,4, 2,4, 2,4, 2,4, 1};
        const int sKTS[17] = {1,1,1, 1,1, 1,1,1, 2,1, 2,1, 2,1, 2,1, 2};
        const int snb[17]  = {0,0,0, 0,0, 0,0,0, 0,0, 32,0, 64,0, 96,0, 0};
        const int skb[17]  = {0,32,64, 0,32, 0,32,64, 0,0, 0,32, 0,64, 0,96, 0};

        int seg = 0, local = blockIdx.x;
        while (seg < 16 && local >= sNT[seg] * sKTS[seg]) { local -= sNT[seg] * sKTS[seg]; seg++; }
        const int kts = sKTS[seg];
        const int kt = local % kts, nt = local / kts;
        const int lay = slay[seg];
        short* dst = wimg + soff[seg] + local * 512;

        int j = tid & 7, lane = tid >> 3;
        int n = snb[seg] + nt * 16 + (lane & 15);
        int k = skb[seg] + kt * 32 + (lane >> 4) * 8 + j;
        float v = 0.0f;
        switch (lay) {
            case 0: if (n < 50  && k < 75)  v = W_input[n * 75 + k]; break;
            case 1: if (n < 75  && k < 50)  v = W_h1[n * 50 + k]; break;
            case 2: if (n < 75  && k < 75)  v = W_h2[n * 75 + k]; break;
            case 6: if (n < 125 && k < 50)  v = W_h4[n * 50 + k]; break;
            case 7: if (n < 50  && k < 125) v = W_h5[n * 125 + k]; break;
            case 8: if (n < 3   && k < 50)  v = W_out[n * 50 + k]; break;
        }
        dst[tid] = (short)f2h_bits(v);
        return;
    }

    // ---- block 71: bias table + E/F/D hi/lo images ----
    const int NT = 512;
    for (int i = tid; i < BIAS_TOT; i += NT) ws[i] = 0.0f;
    __syncthreads();
    for (int i = tid; i < 50;  i += NT) ws[BA  + i] = b_input[i];
    for (int i = tid; i < 75;  i += NT) ws[B1  + i] = b_h1[i];
    for (int i = tid; i < 75;  i += NT) ws[B2  + i] = b_h2[i];
    for (int i = tid; i < 3;   i += NT) ws[BEF + i] = ws[STG_BE + i] + ws[STG_BF + i];
    for (int i = tid; i < 50;  i += NT) ws[BD  + i] = ws[STG_BD + i];
    for (int i = tid; i < 125; i += NT) ws[B4  + i] = b_h4[i];
    for (int i = tid; i < 50;  i += NT) ws[B5  + i] = b_h5[i];
    for (int i = tid; i < 3;   i += NT) ws[BOUT + i] = b_out[i];

    for (int i = tid; i < 3072; i += NT) {   // E: 6 frags kt-major hi/lo
        int j = i & 7, lane = (i >> 3) & 63, frag = i >> 9, pl = frag & 1, kt = frag >> 1;
        int n = lane & 15, k = kt * 32 + (lane >> 4) * 8 + j;
        float v = (n < 3 && k < 75) ? ws[STG_E + n * 75 + k] : 0.0f;
        float hi = h2f_bits(f2h_bits(v));
        wimg[W_EF + i] = (short)(pl ? f2h_bits(v - hi) : f2h_bits(v));
    }
    for (int i = tid; i < 2048; i += NT) {   // F: 4 frags
        int j = i & 7, lane = (i >> 3) & 63, frag = i >> 9, pl = frag & 1, kt = frag >> 1;
        int n = lane & 15, k = kt * 32 + (lane >> 4) * 8 + j;
        float v = (n < 3 && k < 50) ? ws[STG_F + n * 50 + k] : 0.0f;
        float hi = h2f_bits(f2h_bits(v));
        wimg[W_EF + 3072 + i] = (short)(pl ? f2h_bits(v - hi) : f2h_bits(v));
    }
    for (int i = tid; i < 4096; i += NT) {   // D: 8 frags nt-major hi/lo
        int j = i & 7, lane = (i >> 3) & 63, frag = i >> 9, pl = frag & 1, nt = frag >> 1;
        int n = nt * 16 + (lane & 15), k = (lane >> 4) * 8 + j;
        float v = (n < 50 && k < 3) ? ws[STG_D + n * 3 + k] : 0.0f;
        float hi = h2f_bits(f2h_bits(v));
        wimg[W_D + i] = (short)(pl ? f2h_bits(v - hi) : f2h_bits(v));
    }
}

// ---------------------------------------------------------------------------
// main kernel helpers (identical to round 5)
// ---------------------------------------------------------------------------
__device__ __forceinline__ void copyStage(short* dst, const short* src, int nsh, int tid) {
    uint4_* d = (uint4_*)dst;
    const uint4_* s = (const uint4_*)src;
    int n = nsh >> 3;
    for (int i = tid; i < n; i += 256) d[i] = s[i];
}

__device__ __forceinline__ half8 bfragH(const short* wb, int fragIdx, int lane) {
    return *(const half8*)(wb + fragIdx * 512 + lane * 8);
}

__device__ __forceinline__ half8 readAf(const unsigned int* acts, int row0, int pane, int lane) {
    int m = lane & 15, qd = lane >> 4;
    const unsigned int* p = &acts[(row0 + m) * AST + pane + (qd & 1) * 8];
    uint4_ a = *(const uint4_*)p;
    uint4_ b = *(const uint4_*)(p + 4);
    unsigned sel = (qd >> 1) ? 0x07060302u : 0x05040100u;
    union { unsigned u[4]; half8 v; } r;
    r.u[0] = __builtin_amdgcn_perm(a.y, a.x, sel);
    r.u[1] = __builtin_amdgcn_perm(a.w, a.z, sel);
    r.u[2] = __builtin_amdgcn_perm(b.y, b.x, sel);
    r.u[3] = __builtin_amdgcn_perm(b.w, b.z, sel);
    return r.v;
}

__device__ __forceinline__ void writeCf(unsigned int* acts, int row0q, int dcol,
                                        f32x4 va, f32x4 vb) {
    unsigned int* p = &acts[row0q * AST + dcol];
#pragma unroll
    for (int r = 0; r < 4; r++) {
        union { _Float16 h[2]; unsigned u; } t;
        t.h[0] = (_Float16)va[r]; t.h[1] = (_Float16)vb[r];
        p[r * AST] = t.u;
    }
}

__device__ __forceinline__ void t2s(f32x4& a0, f32x4& a1, half8 x0, half8 x1, half8 b) {
    a0 = MFMAH(x0, b, a0);
    a1 = MFMAH(x1, b, a1);
}
__device__ __forceinline__ void t2p(f32x4& a0, f32x4& a1, half8 x0, half8 x1,
                                    half8 bh, half8 bl) {
    a0 = MFMAH(x0, bh, a0);
    a1 = MFMAH(x1, bh, a1);
    a0 = MFMAH(x0, bl, a0);
    a1 = MFMAH(x1, bl, a1);
}

// ---------------------------------------------------------------------------
// main fused kernel (identical to round 5)
// ---------------------------------------------------------------------------
__global__ __launch_bounds__(256, 3) void fused_mfma(
    const float* __restrict__ xin,
    const float* __restrict__ ws,
    float* __restrict__ out)
{
    __shared__ unsigned int acts[MTILE * AST];
    __shared__ short wbuf[2][5120];
    __shared__ float sbias[BIAS_TOT];

    const int tid = threadIdx.x;
    const int wv = tid >> 6;
    const int lane = tid & 63;
    const int qd = lane >> 4;
    const int mcol = lane & 15;
    const int rw = wv * 32;
    const short* wimg = (const short*)(ws + BIAS_TOT);
    const f32x4 zero4 = {0.f, 0.f, 0.f, 0.f};

    const int g0 = blockIdx.x * MTILE;
    const int bb = g0 / HW;
    const int p0 = g0 - bb * HW;
    const int yb = p0 / IW;
    const int xblk = p0 - yb * IW;
    const float* __restrict__ xb = xin + bb * 3 * HW;

    for (int i = tid; i < BIAS_TOT; i += 256) sbias[i] = ws[i];
    copyStage(wbuf[0], wimg + W_A0, 2048, tid);

    half8 swf[3][2];
#pragma unroll
    for (int mt = 0; mt < 2; mt++) {
        const int xpix = xblk + wv * 32 + mt * 16 + mcol;
#pragma unroll
        for (int kt = 0; kt < 3; kt++) {
            union { _Float16 h[8]; half8 v; } u;
#pragma unroll
            for (int j = 0; j < 8; j++) {
                int qq = kt * 32 + qd * 8 + j;
                float val = 0.0f;
                if (qq < 75) {
                    int c = qq / 25, rem = qq - 25 * c;
                    int rr = rem / 5, ss = rem - 5 * rr;
                    int ty = yb + rr - 2; ty = ty < 0 ? -ty : ty;
                    ty = (766 - ty) < ty ? (766 - ty) : ty;
                    int tx = xpix + ss - 2; tx = tx < 0 ? -tx : tx;
                    tx = (766 - tx) < tx ? (766 - tx) : tx;
                    val = xb[c * HW + ty * IW + tx];
                }
                u.h[j] = (_Float16)val;
            }
            swf[kt][mt] = u.v;
        }
    }
    __syncthreads();

    // ===== layer A =====
    f32x4 accA[4][2];
#pragma unroll
    for (int nt = 0; nt < 4; nt++) { accA[nt][0] = zero4; accA[nt][1] = zero4; }

    copyStage(wbuf[1], wimg + W_A1, 2048, tid);
#pragma unroll
    for (int nt = 0; nt < 4; nt++)
        t2s(accA[nt][0], accA[nt][1], swf[0][0], swf[0][1], bfragH(wbuf[0], nt, lane));
    __syncthreads();
    copyStage(wbuf[0], wimg + W_A2, 2048, tid);
#pragma unroll
    for (int nt = 0; nt < 4; nt++)
        t2s(accA[nt][0], accA[nt][1], swf[1][0], swf[1][1], bfragH(wbuf[1], nt, lane));
    __syncthreads();
    copyStage(wbuf[1], wimg + W_H1A, 2560, tid);
#pragma unroll
    for (int nt = 0; nt < 4; nt++)
        t2s(accA[nt][0], accA[nt][1], swf[2][0], swf[2][1], bfragH(wbuf[0], nt, lane));

    f32x4 x1C[4][2];
    half8 x1f[2][2];
#pragma unroll
    for (int nt = 0; nt < 4; nt++) {
        float bv = sbias[BA + nt * 16 + mcol];
#pragma unroll
        for (int mt = 0; mt < 2; mt++) {
            f32x4 v = accA[nt][mt];
            v[0] += bv; v[1] += bv; v[2] += bv; v[3] += bv;
            x1C[nt][mt] = v;
        }
    }
#pragma unroll
    for (int mt = 0; mt < 2; mt++) {
        writeCf(acts, rw + mt * 16 + qd * 4, mcol,      x1C[0][mt], x1C[1][mt]);
        writeCf(acts, rw + mt * 16 + qd * 4, 16 + mcol, x1C[2][mt], x1C[3][mt]);
    }
#pragma unroll
    for (int kt = 0; kt < 2; kt++)
#pragma unroll
        for (int mt = 0; mt < 2; mt++)
            x1f[kt][mt] = readAf(acts, rw + mt * 16, kt * 16, lane);
    __syncthreads();

    // ===== h1 =====
    f32x4 acc1[5][2];
#pragma unroll
    for (int nt = 0; nt < 5; nt++) { acc1[nt][0] = zero4; acc1[nt][1] = zero4; }

    copyStage(wbuf[0], wimg + W_H1B, 2560, tid);
#pragma unroll
    for (int nt = 0; nt < 5; nt++)
        t2s(acc1[nt][0], acc1[nt][1], x1f[0][0], x1f[0][1], bfragH(wbuf[1], nt, lane));
    __syncthreads();
    copyStage(wbuf[1], wimg + W_H2A, 2560, tid);
#pragma unroll
    for (int nt = 0; nt < 5; nt++)
        t2s(acc1[nt][0], acc1[nt][1], x1f[1][0], x1f[1][1], bfragH(wbuf[0], nt, lane));
#pragma unroll
    for (int mt = 0; mt < 2; mt++) {
        f32x4 w5[5];
#pragma unroll
        for (int nt = 0; nt < 5; nt++) {
            float bv = sbias[B1 + nt * 16 + mcol];
            f32x4 v = acc1[nt][mt];
            v[0] = lrelu(v[0] + bv); v[1] = lrelu(v[1] + bv);
            v[2] = lrelu(v[2] + bv); v[3] = lrelu(v[3] + bv);
            w5[nt] = v;
        }
        writeCf(acts, rw + mt * 16 + qd * 4, mcol,      w5[0], w5[1]);
        writeCf(acts, rw + mt * 16 + qd * 4, 16 + mcol, w5[2], w5[3]);
        writeCf(acts, rw + mt * 16 + qd * 4, 32 + mcol, w5[4], zero4);
    }
    __syncthreads();

    // ===== h2 =====
    f32x4 acc2[5][2];
#pragma unroll
    for (int nt = 0; nt < 5; nt++) { acc2[nt][0] = zero4; acc2[nt][1] = zero4; }

    copyStage(wbuf[0], wimg + W_H2B, 2560, tid);
    {
        half8 a0 = readAf(acts, rw, 0, lane), a1 = readAf(acts, rw + 16, 0, lane);
#pragma unroll
        for (int nt = 0; nt < 5; nt++)
            t2s(acc2[nt][0], acc2[nt][1], a0, a1, bfragH(wbuf[1], nt, lane));
    }
    __syncthreads();
    copyStage(wbuf[1], wimg + W_H2C, 2560, tid);
    {
        half8 a0 = readAf(acts, rw, 16, lane), a1 = readAf(acts, rw + 16, 16, lane);
#pragma unroll
        for (int nt = 0; nt < 5; nt++)
            t2s(acc2[nt][0], acc2[nt][1], a0, a1, bfragH(wbuf[0], nt, lane));
    }
    __syncthreads();
    copyStage(wbuf[0], wimg + W_EF, 5120, tid);
    {
        half8 a0 = readAf(acts, rw, 32, lane), a1 = readAf(acts, rw + 16, 32, lane);
#pragma unroll
        for (int nt = 0; nt < 5; nt++)
            t2s(acc2[nt][0], acc2[nt][1], a0, a1, bfragH(wbuf[1], nt, lane));
    }
#pragma unroll
    for (int mt = 0; mt < 2; mt++) {
        f32x4 w5[5];
#pragma unroll
        for (int nt = 0; nt < 5; nt++) {
            float bv = sbias[B2 + nt * 16 + mcol];
            f32x4 v = acc2[nt][mt];
            v[0] = tanh_fast(v[0] + bv); v[1] = tanh_fast(v[1] + bv);
            v[2] = tanh_fast(v[2] + bv); v[3] = tanh_fast(v[3] + bv);
            w5[nt] = v;
        }
        writeCf(acts, rw + mt * 16 + qd * 4, mcol,      w5[0], w5[1]);
        writeCf(acts, rw + mt * 16 + qd * 4, 16 + mcol, w5[2], w5[3]);
        writeCf(acts, rw + mt * 16 + qd * 4, 32 + mcol, w5[4], zero4);
    }
    __syncthreads();

    // ===== EF =====
    copyStage(wbuf[1], wimg + W_D, 4096, tid);
    f32x4 accEF[2];
    {
        float bv = sbias[BEF + mcol];
        accEF[0] = (f32x4){bv, bv, bv, bv};
        accEF[1] = accEF[0];
    }
#pragma unroll
    for (int kt = 0; kt < 3; kt++) {
        half8 a0 = readAf(acts, rw, kt * 16, lane), a1 = readAf(acts, rw + 16, kt * 16, lane);
        t2p(accEF[0], accEF[1], a0, a1,
            bfragH(wbuf[0], kt * 2, lane), bfragH(wbuf[0], kt * 2 + 1, lane));
    }
    {
        const short* Fp = wbuf[0] + 3072;
#pragma unroll
        for (int kt = 0; kt < 2; kt++)
            t2p(accEF[0], accEF[1], x1f[kt][0], x1f[kt][1],
                bfragH(Fp, kt * 2, lane), bfragH(Fp, kt * 2 + 1, lane));
    }
    half8 x4f[2];
#pragma unroll
    for (int mt = 0; mt < 2; mt++) {
        f32x4 v = accEF[mt];
        v[0] = lrelu(v[0]); v[1] = lrelu(v[1]); v[2] = lrelu(v[2]); v[3] = lrelu(v[3]);
        writeCf(acts, rw + mt * 16 + qd * 4, 32 + mcol, v, zero4);
    }
    x4f[0] = readAf(acts, rw, 32, lane);
    x4f[1] = readAf(acts, rw + 16, 32, lane);
    __syncthreads();

    // ===== D =====
    copyStage(wbuf[0], wimg + W_H4C0, 2048, tid);
    f32x4 accD[4][2];
#pragma unroll
    for (int nt = 0; nt < 4; nt++) {
        float bv = sbias[BD + nt * 16 + mcol];
        accD[nt][0] = (f32x4){bv, bv, bv, bv};
        accD[nt][1] = accD[nt][0];
    }
#pragma unroll
    for (int nt = 0; nt < 4; nt++)
        t2p(accD[nt][0], accD[nt][1], x4f[0], x4f[1],
            bfragH(wbuf[1], nt * 2, lane), bfragH(wbuf[1], nt * 2 + 1, lane));
#pragma unroll
    for (int mt = 0; mt < 2; mt++) {
        writeCf(acts, rw + mt * 16 + qd * 4, mcol,      accD[0][mt], accD[1][mt]);
        writeCf(acts, rw + mt * 16 + qd * 4, 16 + mcol, accD[2][mt], accD[3][mt]);
    }
    half8 xdf[2][2];
#pragma unroll
    for (int kt = 0; kt < 2; kt++)
#pragma unroll
        for (int mt = 0; mt < 2; mt++)
            xdf[kt][mt] = readAf(acts, rw + mt * 16, kt * 16, lane);

    f32x4 x6a[4][2];
#pragma unroll
    for (int nt = 0; nt < 4; nt++) {
        float bv = sbias[B5 + nt * 16 + mcol];
#pragma unroll
        for (int mt = 0; mt < 2; mt++) {
            f32x4 v;
            v[0] = bv - x1C[nt][mt][0]; v[1] = bv - x1C[nt][mt][1];
            v[2] = bv - x1C[nt][mt][2]; v[3] = bv - x1C[nt][mt][3];
            x6a[nt][mt] = v;
        }
    }
    __syncthreads();

    // ===== h4/h5 chunks =====
    for (int c = 0; c < 4; c++) {
        copyStage(wbuf[1], wimg + W_H5C0 + c * 4096, 2048, tid);
        f32x4 acc5[2][2];
#pragma unroll
        for (int nt2 = 0; nt2 < 2; nt2++) {
            float bv = sbias[B4 + c * 32 + nt2 * 16 + mcol];
            acc5[nt2][0] = (f32x4){bv, bv, bv, bv};
            acc5[nt2][1] = acc5[nt2][0];
        }
#pragma unroll
        for (int nt2 = 0; nt2 < 2; nt2++)
#pragma unroll
            for (int kt = 0; kt < 2; kt++)
                t2s(acc5[nt2][0], acc5[nt2][1], xdf[kt][0], xdf[kt][1],
                    bfragH(wbuf[0], nt2 * 2 + kt, lane));
#pragma unroll
        for (int mt = 0; mt < 2; mt++) {
            f32x4 v0 = acc5[0][mt], v1 = acc5[1][mt];
            v0[0] = tanh_fast(v0[0]); v0[1] = tanh_fast(v0[1]);
            v0[2] = tanh_fast(v0[2]); v0[3] = tanh_fast(v0[3]);
            v1[0] = tanh_fast(v1[0]); v1[1] = tanh_fast(v1[1]);
            v1[2] = tanh_fast(v1[2]); v1[3] = tanh_fast(v1[3]);
            writeCf(acts, rw + mt * 16 + qd * 4, 32 + mcol, v0, v1);
        }
        half8 chf[2];
        chf[0] = readAf(acts, rw, 32, lane);
        chf[1] = readAf(acts, rw + 16, 32, lane);
        __syncthreads();

        if (c < 3) copyStage(wbuf[0], wimg + W_H4C0 + (c + 1) * 4096, 2048, tid);
        else       copyStage(wbuf[0], wimg + W_OUT, 1024, tid);
#pragma unroll
        for (int nt = 0; nt < 4; nt++)
            t2s(x6a[nt][0], x6a[nt][1], chf[0], chf[1], bfragH(wbuf[1], nt, lane));
        __syncthreads();
    }

    // ===== out =====
#pragma unroll
    for (int mt = 0; mt < 2; mt++) {
        writeCf(acts, rw + mt * 16 + qd * 4, mcol,      x6a[0][mt], x6a[1][mt]);
        writeCf(acts, rw + mt * 16 + qd * 4, 16 + mcol, x6a[2][mt], x6a[3][mt]);
    }
    f32x4 accO[2];
    {
        float bv = sbias[BOUT + mcol];
        accO[0] = (f32x4){bv, bv, bv, bv};
        accO[1] = accO[0];
    }
#pragma unroll
    for (int kt = 0; kt < 2; kt++) {
        half8 a0 = readAf(acts, rw, kt * 16, lane), a1 = readAf(acts, rw + 16, kt * 16, lane);
        t2s(accO[0], accO[1], a0, a1, bfragH(wbuf[0], kt, lane));
    }
    if (mcol < 3) {
#pragma unroll
        for (int mt = 0; mt < 2; mt++) {
#pragma unroll
            for (int r = 0; r < 4; r++) {
                int p = p0 + wv * 32 + mt * 16 + qd * 4 + r;
                out[(bb * 3 + mcol) * HW + p] = lrelu(accO[mt][r]);
            }
        }
    }
}

extern "C" void kernel_launch(void* const* d_in, const int* in_sizes, int n_in,
                              void* d_out, int out_size, void* d_ws, size_t ws_size,
                              hipStream_t stream)
{
    const float* xin = (const float*)d_in[0];
    float* ws = (float*)d_ws;

    setup_collapse<<<3, 256, 0, stream>>>(
        (const float*)d_in[15], (const float*)d_in[16],  // e1
        (const float*)d_in[17], (const float*)d_in[18],  // e2
        (const float*)d_in[19], (const float*)d_in[20],  // e3
        (const float*)d_in[21], (const float*)d_in[22],  // f1
        (const float*)d_in[23], (const float*)d_in[24],  // f2
        (const float*)d_in[25], (const float*)d_in[26],  // f3
        (const float*)d_in[27], (const float*)d_in[28],  // d1
        (const float*)d_in[29], (const float*)d_in[30],  // d2
        (const float*)d_in[31], (const float*)d_in[32],  // d3
        (const float*)d_in[7],  (const float*)d_in[8],   // h3
        ws);

    setup_pack<<<72, 512, 0, stream>>>(
        (const float*)d_in[1],  (const float*)d_in[2],   // input
        (const float*)d_in[3],  (const float*)d_in[4],   // h1
        (const float*)d_in[5],  (const float*)d_in[6],   // h2
        (const float*)d_in[9],  (const float*)d_in[10],  // h4
        (const float*)d_in[11], (const float*)d_in[12],  // h5
        (const float*)d_in[13], (const float*)d_in[14],  // out
        ws);

    fused_mfma<<<NBLK, 256, 0, stream>>>(xin, ws, (float*)d_out);
}

// Round 9
// 257.729 us; speedup vs baseline: 9.2883x; 1.0476x over previous
//
#include <hip/hip_runtime.h>

// ---------------------------------------------------------------------------
// Round 9 = Round 8 with the cvt_pkrtz union type fixed (__fp16 vector, the
// builtin's native return type).
//  - setup_collapse: float4 + unroll-4 global->LDS staging.
//  - fused_mfma: f32->f16 pair conversions via v_cvt_pkrtz_f16_f32.
// ---------------------------------------------------------------------------

#define IW 384
#define HW (384 * 384)           // 147456
#define NPIX (4 * HW)            // 589824
#define MTILE 128
#define NBLK (NPIX / MTILE)      // 4608
#define AST 52                   // acts row stride in dwords (48 data + 4 pad)

typedef _Float16 half8 __attribute__((ext_vector_type(8)));
typedef __fp16 fp16x2 __attribute__((ext_vector_type(2)));
typedef __attribute__((ext_vector_type(4))) float f32x4;
typedef __attribute__((ext_vector_type(4))) unsigned int uint4_;

#define MFMAH(A, B, C) __builtin_amdgcn_mfma_f32_16x16x32_f16((A), (B), (C), 0, 0, 0)

// bias table offsets (dwords in ws)
#define BA   0
#define B1   64
#define B2   144
#define BEF  224
#define BD   240
#define B4   304
#define B5   432
#define BOUT 496
#define BIAS_TOT 512

// weight image segment offsets (shorts, after bias table). frag = 512 shorts.
#define W_A0   0
#define W_A1   2048
#define W_A2   4096
#define W_H1A  6144
#define W_H1B  8704
#define W_H2A  11264
#define W_H2B  13824
#define W_H2C  16384
#define W_EF   18944    // E: 6 frags hi/lo (kt-major), F: 4 frags at +3072
#define W_D    24064    // 8 frags hi/lo (nt-major)
#define W_H4C0 28160    // chunk c: h4 at 28160+c*4096
#define W_H5C0 30208    //          h5 at 30208+c*4096
#define W_OUT  44544
#define W_TOT  45568

// fp32 staging (dword offsets in ws) for collapse results
#define STG_E   23296   // 225  (3 x 75)
#define STG_F   23521   // 150  (3 x 50)
#define STG_D   23671   // 150  (50 x 3)
#define STG_BE  23821   // 3
#define STG_BF  23824   // 3
#define STG_BD  23827   // 50

__device__ __forceinline__ float lrelu(float v) { return v >= 0.0f ? v : 0.01f * v; }

__device__ __forceinline__ float tanh_fast(float v) {
    float e = __expf(2.0f * v);
    return 1.0f - 2.0f * __builtin_amdgcn_rcpf(e + 1.0f);
}

__device__ __forceinline__ unsigned short f2h_bits(float v) {
    union { _Float16 h; unsigned short s; } u; u.h = (_Float16)v; return u.s;
}
__device__ __forceinline__ float h2f_bits(unsigned short s) {
    union { _Float16 h; unsigned short s; } u; u.s = s; return (float)u.h;
}
// pack two f32 -> f16 pair in ONE v_cvt_pkrtz_f16_f32 (a in low 16, b in high)
__device__ __forceinline__ unsigned packh2(float a, float b) {
    union { fp16x2 h; unsigned u; } u;
    u.h = __builtin_amdgcn_cvt_pkrtz(a, b);
    return u.u;
}

// deep-pipelined global->LDS staging: float4 x unroll-4 (~16 loads in flight)
__device__ __forceinline__ void stage(float* dst, const float* __restrict__ src,
                                      int n, int tid) {
    int n4 = n >> 2;
    float4* d = (float4*)dst;
    const float4* s = (const float4*)src;
#pragma unroll 4
    for (int i = tid; i < n4; i += 256) d[i] = s[i];
    for (int i = (n4 << 2) + tid; i < n; i += 256) dst[i] = src[i];
}

// ---------------------------------------------------------------------------
// setup_collapse: 3 blocks, one affine chain each, operands staged in LDS.
// ---------------------------------------------------------------------------
__global__ __launch_bounds__(256) void setup_collapse(
    const float* __restrict__ W_e1, const float* __restrict__ b_e1,
    const float* __restrict__ W_e2, const float* __restrict__ b_e2,
    const float* __restrict__ W_e3, const float* __restrict__ b_e3,
    const float* __restrict__ W_f1, const float* __restrict__ b_f1,
    const float* __restrict__ W_f2, const float* __restrict__ b_f2,
    const float* __restrict__ W_f3, const float* __restrict__ b_f3,
    const float* __restrict__ W_d1, const float* __restrict__ b_d1,
    const float* __restrict__ W_d2, const float* __restrict__ b_d2,
    const float* __restrict__ W_d3, const float* __restrict__ b_d3,
    const float* __restrict__ W_h3, const float* __restrict__ b_h3,
    float* __restrict__ ws)
{
    __shared__ __align__(16) float A[17500];
    __shared__ float B[675];
    __shared__ float C[256];
    __shared__ float Dd[256];
    __shared__ float Es[256];

    const int tid = threadIdx.x;
    const int NT = 256;

    if (blockIdx.x == 0) {
        // ================= E chain =================
        stage(A, W_e2, 16875, tid);                       // W_e2 (75x225)
        for (int i = tid; i < 225; i += NT) { Es[i] = W_e3[i]; C[i] = b_e1[i]; }
        __syncthreads();
        // M1 = W_e3 @ W_e2  (3 x 225) -> B
        for (int o = tid; o < 675; o += NT) {
            int r = o / 225, c = o % 225;
            float s0 = 0.f, s1 = 0.f, s2 = 0.f;
#pragma unroll
            for (int t = 0; t < 75; t += 3) {
                s0 += Es[r * 75 + t]     * A[t * 225 + c];
                s1 += Es[r * 75 + t + 1] * A[(t + 1) * 225 + c];
                s2 += Es[r * 75 + t + 2] * A[(t + 2) * 225 + c];
            }
            B[o] = s0 + s1 + s2;
        }
        // ue = W_e2 @ b_e1 + b_e2  (75) -> Dd
        for (int o = tid; o < 75; o += NT) {
            float s0 = 0.f, s1 = 0.f, s2 = 0.f;
#pragma unroll
            for (int t = 0; t < 225; t += 3) {
                s0 += A[o * 225 + t]     * C[t];
                s1 += A[o * 225 + t + 1] * C[t + 1];
                s2 += A[o * 225 + t + 2] * C[t + 2];
            }
            Dd[o] = b_e2[o] + s0 + s1 + s2;
        }
        __syncthreads();
        stage(A, W_e1, 16875, tid);                       // W_e1 (225x75)
        __syncthreads();
        // sE = M1 @ W_e1 (3 x 75) -> staging
        for (int o = tid; o < 225; o += NT) {
            int r = o / 75, c = o % 75;
            float s0 = 0.f, s1 = 0.f, s2 = 0.f;
#pragma unroll
            for (int t = 0; t < 225; t += 3) {
                s0 += B[r * 225 + t]     * A[t * 75 + c];
                s1 += B[r * 225 + t + 1] * A[(t + 1) * 75 + c];
                s2 += B[r * 225 + t + 2] * A[(t + 2) * 75 + c];
            }
            ws[STG_E + o] = s0 + s1 + s2;
        }
        // be = W_e3 @ ue + b_e3 (3)
        for (int o = tid; o < 3; o += NT) {
            float s = b_e3[o];
            for (int t = 0; t < 75; t++) s += Es[o * 75 + t] * Dd[t];
            ws[STG_BE + o] = s;
        }
    } else if (blockIdx.x == 1) {
        // ================= F chain =================
        stage(A,        W_f2, 7500, tid);                 // W_f2 (50x150)
        stage(A + 7500, W_f1, 7500, tid);                 // W_f1 (150x50)
        for (int i = tid; i < 150; i += NT) { Es[i] = W_f3[i]; C[i] = b_f1[i]; }
        __syncthreads();
        // MF = W_f3 @ W_f2 (3 x 150) -> B
        for (int o = tid; o < 450; o += NT) {
            int r = o / 150, c = o % 150;
            float s0 = 0.f, s1 = 0.f;
#pragma unroll
            for (int t = 0; t < 50; t += 2) {
                s0 += Es[r * 50 + t]     * A[t * 150 + c];
                s1 += Es[r * 50 + t + 1] * A[(t + 1) * 150 + c];
            }
            B[o] = s0 + s1;
        }
        // uf = W_f2 @ b_f1 + b_f2 (50) -> Dd
        for (int o = tid; o < 50; o += NT) {
            float s0 = 0.f, s1 = 0.f;
#pragma unroll
            for (int t = 0; t < 150; t += 2) {
                s0 += A[o * 150 + t]     * C[t];
                s1 += A[o * 150 + t + 1] * C[t + 1];
            }
            Dd[o] = b_f2[o] + s0 + s1;
        }
        __syncthreads();
        // sF = MF @ W_f1 (3 x 50) -> staging
        for (int o = tid; o < 150; o += NT) {
            int r = o / 50, c = o % 50;
            float s0 = 0.f, s1 = 0.f;
#pragma unroll
            for (int t = 0; t < 150; t += 2) {
                s0 += B[r * 150 + t]     * A[7500 + t * 50 + c];
                s1 += B[r * 150 + t + 1] * A[7500 + (t + 1) * 50 + c];
            }
            ws[STG_F + o] = s0 + s1;
        }
        // bf = W_f3 @ uf + b_f3 (3)
        for (int o = tid; o < 3; o += NT) {
            float s = b_f3[o];
            for (int t = 0; t < 50; t++) s += Es[o * 50 + t] * Dd[t];
            ws[STG_BF + o] = s;
        }
    } else {
        // ================= D chain =================
        stage(A,         W_d2, 7500, tid);                // W_d2 (150x50)
        stage(A + 7500,  W_d3, 7500, tid);                // W_d3 (50x150)
        stage(A + 15000, W_h3, 2500, tid);                // W_h3 (50x50)
        for (int i = tid; i < 150; i += NT) Es[i] = W_d1[i];
        for (int i = tid; i < 50;  i += NT) C[i] = b_d1[i];
        __syncthreads();
        // A1 = W_d2 @ W_d1 (150 x 3) -> B
        for (int o = tid; o < 450; o += NT) {
            int r = o / 3, c = o % 3;
            float s0 = 0.f, s1 = 0.f;
#pragma unroll
            for (int t = 0; t < 50; t += 2) {
                s0 += A[r * 50 + t]     * Es[t * 3 + c];
                s1 += A[r * 50 + t + 1] * Es[(t + 1) * 3 + c];
            }
            B[o] = s0 + s1;
        }
        // v1 = W_d2 @ b_d1 + b_d2 (150) -> Dd   (inner dim 50)
        for (int o = tid; o < 150; o += NT) {
            float s0 = 0.f, s1 = 0.f;
#pragma unroll
            for (int t = 0; t < 50; t += 2) {
                s0 += A[o * 50 + t]     * C[t];
                s1 += A[o * 50 + t + 1] * C[t + 1];
            }
            Dd[o] = b_d2[o] + s0 + s1;
        }
        __syncthreads();
        // A2 = W_d3 @ A1 (50 x 3) -> Es (reuse), v2 = W_d3 @ v1 + b_d3 (50) -> C
        for (int o = tid; o < 150; o += NT) {
            int r = o / 3, c = o % 3;
            float s0 = 0.f, s1 = 0.f;
#pragma unroll
            for (int t = 0; t < 150; t += 2) {
                s0 += A[7500 + r * 150 + t]     * B[t * 3 + c];
                s1 += A[7500 + r * 150 + t + 1] * B[(t + 1) * 3 + c];
            }
            Es[o] = s0 + s1;
        }
        for (int o = tid; o < 50; o += NT) {
            float s0 = 0.f, s1 = 0.f;
#pragma unroll
            for (int t = 0; t < 150; t += 2) {
                s0 += A[7500 + o * 150 + t]     * Dd[t];
                s1 += A[7500 + o * 150 + t + 1] * Dd[t + 1];
            }
            C[o] = b_d3[o] + s0 + s1;     // v2
        }
        __syncthreads();
        // sD = W_h3 @ A2 (50 x 3) -> staging ; sbd = W_h3 @ v2 + b_h3 (50)
        for (int o = tid; o < 150; o += NT) {
            int r = o / 3, c = o % 3;
            float s0 = 0.f, s1 = 0.f;
#pragma unroll
            for (int t = 0; t < 50; t += 2) {
                s0 += A[15000 + r * 50 + t]     * Es[t * 3 + c];
                s1 += A[15000 + r * 50 + t + 1] * Es[(t + 1) * 3 + c];
            }
            ws[STG_D + o] = s0 + s1;
        }
        for (int o = tid; o < 50; o += NT) {
            float s0 = 0.f, s1 = 0.f;
#pragma unroll
            for (int t = 0; t < 50; t += 2) {
                s0 += A[15000 + o * 50 + t]     * C[t];
                s1 += A[15000 + o * 50 + t + 1] * C[t + 1];
            }
            ws[STG_BD + o] = b_h3[o] + s0 + s1;
        }
    }
}

// ---------------------------------------------------------------------------
// setup_pack: blocks 0..70 raw-weight fp16 frag images; block 71 bias table
// + E/F/D hi/lo images from fp32 staging.
// ---------------------------------------------------------------------------
__global__ __launch_bounds__(512) void setup_pack(
    const float* __restrict__ W_input, const float* __restrict__ b_input,
    const float* __restrict__ W_h1,  const float* __restrict__ b_h1,
    const float* __restrict__ W_h2,  const float* __restrict__ b_h2,
    const float* __restrict__ W_h4,  const float* __restrict__ b_h4,
    const float* __restrict__ W_h5,  const float* __restrict__ b_h5,
    const float* __restrict__ W_out, const float* __restrict__ b_out,
    float* __restrict__ ws)
{
    const int tid = threadIdx.x;
    short* wimg = (short*)(ws + BIAS_TOT);

    if (blockIdx.x < 71) {
        const int soff[17] = {W_A0,W_A1,W_A2, W_H1A,W_H1B, W_H2A,W_H2B,W_H2C,
                              W_H4C0,W_H5C0, W_H4C0+4096,W_H5C0+4096,
                              W_H4C0+8192,W_H5C0+8192, W_H4C0+12288,W_H5C0+12288,
                              W_OUT};
        const int slay[17] = {0,0,0, 1,1, 2,2,2, 6,7, 6,7, 6,7, 6,7, 8};
        const int sNT[17]  = {4,4,4, 5,5, 5,5,5, 2,4, 2,4, 2,4, 2,4, 1};
        const int sKTS[17] = {1,1,1, 1,1, 1,1,1, 2,1, 2,1, 2,1, 2,1, 2};
        const int snb[17]  = {0,0,0, 0,0, 0,0,0, 0,0, 32,0, 64,0, 96,0, 0};
        const int skb[17]  = {0,32,64, 0,32, 0,32,64, 0,0, 0,32, 0,64, 0,96, 0};

        int seg = 0, local = blockIdx.x;
        while (seg < 16 && local >= sNT[seg] * sKTS[seg]) { local -= sNT[seg] * sKTS[seg]; seg++; }
        const int kts = sKTS[seg];
        const int kt = local % kts, nt = local / kts;
        const int lay = slay[seg];
        short* dst = wimg + soff[seg] + local * 512;

        int j = tid & 7, lane = tid >> 3;
        int n = snb[seg] + nt * 16 + (lane & 15);
        int k = skb[seg] + kt * 32 + (lane >> 4) * 8 + j;
        float v = 0.0f;
        switch (lay) {
            case 0: if (n < 50  && k < 75)  v = W_input[n * 75 + k]; break;
            case 1: if (n < 75  && k < 50)  v = W_h1[n * 50 + k]; break;
            case 2: if (n < 75  && k < 75)  v = W_h2[n * 75 + k]; break;
            case 6: if (n < 125 && k < 50)  v = W_h4[n * 50 + k]; break;
            case 7: if (n < 50  && k < 125) v = W_h5[n * 125 + k]; break;
            case 8: if (n < 3   && k < 50)  v = W_out[n * 50 + k]; break;
        }
        dst[tid] = (short)f2h_bits(v);
        return;
    }

    // ---- block 71: bias table + E/F/D hi/lo images ----
    const int NT = 512;
    for (int i = tid; i < BIAS_TOT; i += NT) ws[i] = 0.0f;
    __syncthreads();
    for (int i = tid; i < 50;  i += NT) ws[BA  + i] = b_input[i];
    for (int i = tid; i < 75;  i += NT) ws[B1  + i] = b_h1[i];
    for (int i = tid; i < 75;  i += NT) ws[B2  + i] = b_h2[i];
    for (int i = tid; i < 3;   i += NT) ws[BEF + i] = ws[STG_BE + i] + ws[STG_BF + i];
    for (int i = tid; i < 50;  i += NT) ws[BD  + i] = ws[STG_BD + i];
    for (int i = tid; i < 125; i += NT) ws[B4  + i] = b_h4[i];
    for (int i = tid; i < 50;  i += NT) ws[B5  + i] = b_h5[i];
    for (int i = tid; i < 3;   i += NT) ws[BOUT + i] = b_out[i];

    for (int i = tid; i < 3072; i += NT) {   // E: 6 frags kt-major hi/lo
        int j = i & 7, lane = (i >> 3) & 63, frag = i >> 9, pl = frag & 1, kt = frag >> 1;
        int n = lane & 15, k = kt * 32 + (lane >> 4) * 8 + j;
        float v = (n < 3 && k < 75) ? ws[STG_E + n * 75 + k] : 0.0f;
        float hi = h2f_bits(f2h_bits(v));
        wimg[W_EF + i] = (short)(pl ? f2h_bits(v - hi) : f2h_bits(v));
    }
    for (int i = tid; i < 2048; i += NT) {   // F: 4 frags
        int j = i & 7, lane = (i >> 3) & 63, frag = i >> 9, pl = frag & 1, kt = frag >> 1;
        int n = lane & 15, k = kt * 32 + (lane >> 4) * 8 + j;
        float v = (n < 3 && k < 50) ? ws[STG_F + n * 50 + k] : 0.0f;
        float hi = h2f_bits(f2h_bits(v));
        wimg[W_EF + 3072 + i] = (short)(pl ? f2h_bits(v - hi) : f2h_bits(v));
    }
    for (int i = tid; i < 4096; i += NT) {   // D: 8 frags nt-major hi/lo
        int j = i & 7, lane = (i >> 3) & 63, frag = i >> 9, pl = frag & 1, nt = frag >> 1;
        int n = nt * 16 + (lane & 15), k = (lane >> 4) * 8 + j;
        float v = (n < 50 && k < 3) ? ws[STG_D + n * 3 + k] : 0.0f;
        float hi = h2f_bits(f2h_bits(v));
        wimg[W_D + i] = (short)(pl ? f2h_bits(v - hi) : f2h_bits(v));
    }
}

// ---------------------------------------------------------------------------
// main kernel helpers
// ---------------------------------------------------------------------------
__device__ __forceinline__ void copyStage(short* dst, const short* src, int nsh, int tid) {
    uint4_* d = (uint4_*)dst;
    const uint4_* s = (const uint4_*)src;
    int n = nsh >> 3;
    for (int i = tid; i < n; i += 256) d[i] = s[i];
}

__device__ __forceinline__ half8 bfragH(const short* wb, int fragIdx, int lane) {
    return *(const half8*)(wb + fragIdx * 512 + lane * 8);
}

__device__ __forceinline__ half8 readAf(const unsigned int* acts, int row0, int pane, int lane) {
    int m = lane & 15, qd = lane >> 4;
    const unsigned int* p = &acts[(row0 + m) * AST + pane + (qd & 1) * 8];
    uint4_ a = *(const uint4_*)p;
    uint4_ b = *(const uint4_*)(p + 4);
    unsigned sel = (qd >> 1) ? 0x07060302u : 0x05040100u;
    union { unsigned u[4]; half8 v; } r;
    r.u[0] = __builtin_amdgcn_perm(a.y, a.x, sel);
    r.u[1] = __builtin_amdgcn_perm(a.w, a.z, sel);
    r.u[2] = __builtin_amdgcn_perm(b.y, b.x, sel);
    r.u[3] = __builtin_amdgcn_perm(b.w, b.z, sel);
    return r.v;
}

__device__ __forceinline__ void writeCf(unsigned int* acts, int row0q, int dcol,
                                        f32x4 va, f32x4 vb) {
    unsigned int* p = &acts[row0q * AST + dcol];
#pragma unroll
    for (int r = 0; r < 4; r++) p[r * AST] = packh2(va[r], vb[r]);
}

__device__ __forceinline__ void t2s(f32x4& a0, f32x4& a1, half8 x0, half8 x1, half8 b) {
    a0 = MFMAH(x0, b, a0);
    a1 = MFMAH(x1, b, a1);
}
__device__ __forceinline__ void t2p(f32x4& a0, f32x4& a1, half8 x0, half8 x1,
                                    half8 bh, half8 bl) {
    a0 = MFMAH(x0, bh, a0);
    a1 = MFMAH(x1, bh, a1);
    a0 = MFMAH(x0, bl, a0);
    a1 = MFMAH(x1, bl, a1);
}

// ---------------------------------------------------------------------------
// main fused kernel
// ---------------------------------------------------------------------------
__global__ __launch_bounds__(256, 3) void fused_mfma(
    const float* __restrict__ xin,
    const float* __restrict__ ws,
    float* __restrict__ out)
{
    __shared__ unsigned int acts[MTILE * AST];
    __shared__ short wbuf[2][5120];
    __shared__ float sbias[BIAS_TOT];

    const int tid = threadIdx.x;
    const int wv = tid >> 6;
    const int lane = tid & 63;
    const int qd = lane >> 4;
    const int mcol = lane & 15;
    const int rw = wv * 32;
    const short* wimg = (const short*)(ws + BIAS_TOT);
    const f32x4 zero4 = {0.f, 0.f, 0.f, 0.f};

    const int g0 = blockIdx.x * MTILE;
    const int bb = g0 / HW;
    const int p0 = g0 - bb * HW;
    const int yb = p0 / IW;
    const int xblk = p0 - yb * IW;
    const float* __restrict__ xb = xin + bb * 3 * HW;

    for (int i = tid; i < BIAS_TOT; i += 256) sbias[i] = ws[i];
    copyStage(wbuf[0], wimg + W_A0, 2048, tid);

    half8 swf[3][2];
#pragma unroll
    for (int mt = 0; mt < 2; mt++) {
        const int xpix = xblk + wv * 32 + mt * 16 + mcol;
#pragma unroll
        for (int kt = 0; kt < 3; kt++) {
            union { unsigned u32[4]; half8 v; } u;
#pragma unroll
            for (int jj = 0; jj < 8; jj += 2) {
                float vv[2];
#pragma unroll
                for (int t = 0; t < 2; t++) {
                    int qq = kt * 32 + qd * 8 + jj + t;
                    float val = 0.0f;
                    if (qq < 75) {
                        int c = qq / 25, rem = qq - 25 * c;
                        int rr = rem / 5, ss = rem - 5 * rr;
                        int ty = yb + rr - 2; ty = ty < 0 ? -ty : ty;
                        ty = (766 - ty) < ty ? (766 - ty) : ty;
                        int tx = xpix + ss - 2; tx = tx < 0 ? -tx : tx;
                        tx = (766 - tx) < tx ? (766 - tx) : tx;
                        val = xb[c * HW + ty * IW + tx];
                    }
                    vv[t] = val;
                }
                u.u32[jj >> 1] = packh2(vv[0], vv[1]);
            }
            swf[kt][mt] = u.v;
        }
    }
    __syncthreads();

    // ===== layer A =====
    f32x4 accA[4][2];
#pragma unroll
    for (int nt = 0; nt < 4; nt++) { accA[nt][0] = zero4; accA[nt][1] = zero4; }

    copyStage(wbuf[1], wimg + W_A1, 2048, tid);
#pragma unroll
    for (int nt = 0; nt < 4; nt++)
        t2s(accA[nt][0], accA[nt][1], swf[0][0], swf[0][1], bfragH(wbuf[0], nt, lane));
    __syncthreads();
    copyStage(wbuf[0], wimg + W_A2, 2048, tid);
#pragma unroll
    for (int nt = 0; nt < 4; nt++)
        t2s(accA[nt][0], accA[nt][1], swf[1][0], swf[1][1], bfragH(wbuf[1], nt, lane));
    __syncthreads();
    copyStage(wbuf[1], wimg + W_H1A, 2560, tid);
#pragma unroll
    for (int nt = 0; nt < 4; nt++)
        t2s(accA[nt][0], accA[nt][1], swf[2][0], swf[2][1], bfragH(wbuf[0], nt, lane));

    f32x4 x1C[4][2];
    half8 x1f[2][2];
#pragma unroll
    for (int nt = 0; nt < 4; nt++) {
        float bv = sbias[BA + nt * 16 + mcol];
#pragma unroll
        for (int mt = 0; mt < 2; mt++) {
            f32x4 v = accA[nt][mt];
            v[0] += bv; v[1] += bv; v[2] += bv; v[3] += bv;
            x1C[nt][mt] = v;
        }
    }
#pragma unroll
    for (int mt = 0; mt < 2; mt++) {
        writeCf(acts, rw + mt * 16 + qd * 4, mcol,      x1C[0][mt], x1C[1][mt]);
        writeCf(acts, rw + mt * 16 + qd * 4, 16 + mcol, x1C[2][mt], x1C[3][mt]);
    }
#pragma unroll
    for (int kt = 0; kt < 2; kt++)
#pragma unroll
        for (int mt = 0; mt < 2; mt++)
            x1f[kt][mt] = readAf(acts, rw + mt * 16, kt * 16, lane);
    __syncthreads();

    // ===== h1 =====
    f32x4 acc1[5][2];
#pragma unroll
    for (int nt = 0; nt < 5; nt++) { acc1[nt][0] = zero4; acc1[nt][1] = zero4; }

    copyStage(wbuf[0], wimg + W_H1B, 2560, tid);
#pragma unroll
    for (int nt = 0; nt < 5; nt++)
        t2s(acc1[nt][0], acc1[nt][1], x1f[0][0], x1f[0][1], bfragH(wbuf[1], nt, lane));
    __syncthreads();
    copyStage(wbuf[1], wimg + W_H2A, 2560, tid);
#pragma unroll
    for (int nt = 0; nt < 5; nt++)
        t2s(acc1[nt][0], acc1[nt][1], x1f[1][0], x1f[1][1], bfragH(wbuf[0], nt, lane));
#pragma unroll
    for (int mt = 0; mt < 2; mt++) {
        f32x4 w5[5];
#pragma unroll
        for (int nt = 0; nt < 5; nt++) {
            float bv = sbias[B1 + nt * 16 + mcol];
            f32x4 v = acc1[nt][mt];
            v[0] = lrelu(v[0] + bv); v[1] = lrelu(v[1] + bv);
            v[2] = lrelu(v[2] + bv); v[3] = lrelu(v[3] + bv);
            w5[nt] = v;
        }
        writeCf(acts, rw + mt * 16 + qd * 4, mcol,      w5[0], w5[1]);
        writeCf(acts, rw + mt * 16 + qd * 4, 16 + mcol, w5[2], w5[3]);
        writeCf(acts, rw + mt * 16 + qd * 4, 32 + mcol, w5[4], zero4);
    }
    __syncthreads();

    // ===== h2 =====
    f32x4 acc2[5][2];
#pragma unroll
    for (int nt = 0; nt < 5; nt++) { acc2[nt][0] = zero4; acc2[nt][1] = zero4; }

    copyStage(wbuf[0], wimg + W_H2B, 2560, tid);
    {
        half8 a0 = readAf(acts, rw, 0, lane), a1 = readAf(acts, rw + 16, 0, lane);
#pragma unroll
        for (int nt = 0; nt < 5; nt++)
            t2s(acc2[nt][0], acc2[nt][1], a0, a1, bfragH(wbuf[1], nt, lane));
    }
    __syncthreads();
    copyStage(wbuf[1], wimg + W_H2C, 2560, tid);
    {
        half8 a0 = readAf(acts, rw, 16, lane), a1 = readAf(acts, rw + 16, 16, lane);
#pragma unroll
        for (int nt = 0; nt < 5; nt++)
            t2s(acc2[nt][0], acc2[nt][1], a0, a1, bfragH(wbuf[0], nt, lane));
    }
    __syncthreads();
    copyStage(wbuf[0], wimg + W_EF, 5120, tid);
    {
        half8 a0 = readAf(acts, rw, 32, lane), a1 = readAf(acts, rw + 16, 32, lane);
#pragma unroll
        for (int nt = 0; nt < 5; nt++)
            t2s(acc2[nt][0], acc2[nt][1], a0, a1, bfragH(wbuf[1], nt, lane));
    }
#pragma unroll
    for (int mt = 0; mt < 2; mt++) {
        f32x4 w5[5];
#pragma unroll
        for (int nt = 0; nt < 5; nt++) {
            float bv = sbias[B2 + nt * 16 + mcol];
            f32x4 v = acc2[nt][mt];
            v[0] = tanh_fast(v[0] + bv); v[1] = tanh_fast(v[1] + bv);
            v[2] = tanh_fast(v[2] + bv); v[3] = tanh_fast(v[3] + bv);
            w5[nt] = v;
        }
        writeCf(acts, rw + mt * 16 + qd * 4, mcol,      w5[0], w5[1]);
        writeCf(acts, rw + mt * 16 + qd * 4, 16 + mcol, w5[2], w5[3]);
        writeCf(acts, rw + mt * 16 + qd * 4, 32 + mcol, w5[4], zero4);
    }
    __syncthreads();

    // ===== EF =====
    copyStage(wbuf[1], wimg + W_D, 4096, tid);
    f32x4 accEF[2];
    {
        float bv = sbias[BEF + mcol];
        accEF[0] = (f32x4){bv, bv, bv, bv};
        accEF[1] = accEF[0];
    }
#pragma unroll
    for (int kt = 0; kt < 3; kt++) {
        half8 a0 = readAf(acts, rw, kt * 16, lane), a1 = readAf(acts, rw + 16, kt * 16, lane);
        t2p(accEF[0], accEF[1], a0, a1,
            bfragH(wbuf[0], kt * 2, lane), bfragH(wbuf[0], kt * 2 + 1, lane));
    }
    {
        const short* Fp = wbuf[0] + 3072;
#pragma unroll
        for (int kt = 0; kt < 2; kt++)
            t2p(accEF[0], accEF[1], x1f[kt][0], x1f[kt][1],
                bfragH(Fp, kt * 2, lane), bfragH(Fp, kt * 2 + 1, lane));
    }
    half8 x4f[2];
#pragma unroll
    for (int mt = 0; mt < 2; mt++) {
        f32x4 v = accEF[mt];
        v[0] = lrelu(v[0]); v[1] = lrelu(v[1]); v[2] = lrelu(v[2]); v[3] = lrelu(v[3]);
        writeCf(acts, rw + mt * 16 + qd * 4, 32 + mcol, v, zero4);
    }
    x4f[0] = readAf(acts, rw, 32, lane);
    x4f[1] = readAf(acts, rw + 16, 32, lane);
    __syncthreads();

    // ===== D =====
    copyStage(wbuf[0], wimg + W_H4C0, 2048, tid);
    f32x4 accD[4][2];
#pragma unroll
    for (int nt = 0; nt < 4; nt++) {
        float bv = sbias[BD + nt * 16 + mcol];
        accD[nt][0] = (f32x4){bv, bv, bv, bv};
        accD[nt][1] = accD[nt][0];
    }
#pragma unroll
    for (int nt = 0; nt < 4; nt++)
        t2p(accD[nt][0], accD[nt][1], x4f[0], x4f[1],
            bfragH(wbuf[1], nt * 2, lane), bfragH(wbuf[1], nt * 2 + 1, lane));
#pragma unroll
    for (int mt = 0; mt < 2; mt++) {
        writeCf(acts, rw + mt * 16 + qd * 4, mcol,      accD[0][mt], accD[1][mt]);
        writeCf(acts, rw + mt * 16 + qd * 4, 16 + mcol, accD[2][mt], accD[3][mt]);
    }
    half8 xdf[2][2];
#pragma unroll
    for (int kt = 0; kt < 2; kt++)
#pragma unroll
        for (int mt = 0; mt < 2; mt++)
            xdf[kt][mt] = readAf(acts, rw + mt * 16, kt * 16, lane);

    f32x4 x6a[4][2];
#pragma unroll
    for (int nt = 0; nt < 4; nt++) {
        float bv = sbias[B5 + nt * 16 + mcol];
#pragma unroll
        for (int mt = 0; mt < 2; mt++) {
            f32x4 v;
            v[0] = bv - x1C[nt][mt][0]; v[1] = bv - x1C[nt][mt][1];
            v[2] = bv - x1C[nt][mt][2]; v[3] = bv - x1C[nt][mt][3];
            x6a[nt][mt] = v;
        }
    }
    __syncthreads();

    // ===== h4/h5 chunks =====
    for (int c = 0; c < 4; c++) {
        copyStage(wbuf[1], wimg + W_H5C0 + c * 4096, 2048, tid);
        f32x4 acc5[2][2];
#pragma unroll
        for (int nt2 = 0; nt2 < 2; nt2++) {
            float bv = sbias[B4 + c * 32 + nt2 * 16 + mcol];
            acc5[nt2][0] = (f32x4){bv, bv, bv, bv};
            acc5[nt2][1] = acc5[nt2][0];
        }
#pragma unroll
        for (int nt2 = 0; nt2 < 2; nt2++)
#pragma unroll
            for (int kt = 0; kt < 2; kt++)
                t2s(acc5[nt2][0], acc5[nt2][1], xdf[kt][0], xdf[kt][1],
                    bfragH(wbuf[0], nt2 * 2 + kt, lane));
#pragma unroll
        for (int mt = 0; mt < 2; mt++) {
            f32x4 v0 = acc5[0][mt], v1 = acc5[1][mt];
            v0[0] = tanh_fast(v0[0]); v0[1] = tanh_fast(v0[1]);
            v0[2] = tanh_fast(v0[2]); v0[3] = tanh_fast(v0[3]);
            v1[0] = tanh_fast(v1[0]); v1[1] = tanh_fast(v1[1]);
            v1[2] = tanh_fast(v1[2]); v1[3] = tanh_fast(v1[3]);
            writeCf(acts, rw + mt * 16 + qd * 4, 32 + mcol, v0, v1);
        }
        half8 chf[2];
        chf[0] = readAf(acts, rw, 32, lane);
        chf[1] = readAf(acts, rw + 16, 32, lane);
        __syncthreads();

        if (c < 3) copyStage(wbuf[0], wimg + W_H4C0 + (c + 1) * 4096, 2048, tid);
        else       copyStage(wbuf[0], wimg + W_OUT, 1024, tid);
#pragma unroll
        for (int nt = 0; nt < 4; nt++)
            t2s(x6a[nt][0], x6a[nt][1], chf[0], chf[1], bfragH(wbuf[1], nt, lane));
        __syncthreads();
    }

    // ===== out =====
#pragma unroll
    for (int mt = 0; mt < 2; mt++) {
        writeCf(acts, rw + mt * 16 + qd * 4, mcol,      x6a[0][mt], x6a[1][mt]);
        writeCf(acts, rw + mt * 16 + qd * 4, 16 + mcol, x6a[2][mt], x6a[3][mt]);
    }
    f32x4 accO[2];
    {
        float bv = sbias[BOUT + mcol];
        accO[0] = (f32x4){bv, bv, bv, bv};
        accO[1] = accO[0];
    }
#pragma unroll
    for (int kt = 0; kt < 2; kt++) {
        half8 a0 = readAf(acts, rw, kt * 16, lane), a1 = readAf(acts, rw + 16, kt * 16, lane);
        t2s(accO[0], accO[1], a0, a1, bfragH(wbuf[0], kt, lane));
    }
    if (mcol < 3) {
#pragma unroll
        for (int mt = 0; mt < 2; mt++) {
#pragma unroll
            for (int r = 0; r < 4; r++) {
                int p = p0 + wv * 32 + mt * 16 + qd * 4 + r;
                out[(bb * 3 + mcol) * HW + p] = lrelu(accO[mt][r]);
            }
        }
    }
}

extern "C" void kernel_launch(void* const* d_in, const int* in_sizes, int n_in,
                              void* d_out, int out_size, void* d_ws, size_t ws_size,
                              hipStream_t stream)
{
    const float* xin = (const float*)d_in[0];
    float* ws = (float*)d_ws;

    setup_collapse<<<3, 256, 0, stream>>>(
        (const float*)d_in[15], (const float*)d_in[16],  // e1
        (const float*)d_in[17], (const float*)d_in[18],  // e2
        (const float*)d_in[19], (const float*)d_in[20],  // e3
        (const float*)d_in[21], (const float*)d_in[22],  // f1
        (const float*)d_in[23], (const float*)d_in[24],  // f2
        (const float*)d_in[25], (const float*)d_in[26],  // f3
        (const float*)d_in[27], (const float*)d_in[28],  // d1
        (const float*)d_in[29], (const float*)d_in[30],  // d2
        (const float*)d_in[31], (const float*)d_in[32],  // d3
        (const float*)d_in[7],  (const float*)d_in[8],   // h3
        ws);

    setup_pack<<<72, 512, 0, stream>>>(
        (const float*)d_in[1],  (const float*)d_in[2],   // input
        (const float*)d_in[3],  (const float*)d_in[4],   // h1
        (const float*)d_in[5],  (const float*)d_in[6],   // h2
        (const float*)d_in[9],  (const float*)d_in[10],  // h4
        (const float*)d_in[11], (const float*)d_in[12],  // h5
        (const float*)d_in[13], (const float*)d_in[14],  // out
        ws);

    fused_mfma<<<NBLK, 256, 0, stream>>>(xin, ws, (float*)d_out);
}

// Round 10
// 255.648 us; speedup vs baseline: 9.3639x; 1.0081x over previous
//
#include <hip/hip_runtime.h>

// ---------------------------------------------------------------------------
// Round 10:
//  - setup_all: ONE kernel, 75 independent blocks (0-70 raw frag pack,
//    71/72/73 = E/F/D collapse chains packing their own images, 74 = biases).
//    be/bf stored separately; fused sums them into BEF at sbias load.
//  - fused_mfma: cooperative sw-patch staging into LDS (aliases acts) + tap
//    offset table; frag build = ds_read + add instead of per-element
//    division/reflect math. Everything else identical to R9.
// ---------------------------------------------------------------------------

#define IW 384
#define HW (384 * 384)           // 147456
#define NPIX (4 * HW)            // 589824
#define MTILE 128
#define NBLK (NPIX / MTILE)      // 4608
#define AST 52                   // acts row stride in dwords (48 data + 4 pad)

typedef _Float16 half8 __attribute__((ext_vector_type(8)));
typedef __fp16 fp16x2 __attribute__((ext_vector_type(2)));
typedef __attribute__((ext_vector_type(4))) float f32x4;
typedef __attribute__((ext_vector_type(4))) unsigned int uint4_;

#define MFMAH(A, B, C) __builtin_amdgcn_mfma_f32_16x16x32_f16((A), (B), (C), 0, 0, 0)

// bias table offsets (dwords in ws)
#define BA   0
#define B1   64
#define B2   144
#define BEF  224
#define BD   240
#define B4   304
#define B5   432
#define BOUT 496
#define BIAS_TOT 512

// weight image segment offsets (shorts, after bias table). frag = 512 shorts.
#define W_A0   0
#define W_A1   2048
#define W_A2   4096
#define W_H1A  6144
#define W_H1B  8704
#define W_H2A  11264
#define W_H2B  13824
#define W_H2C  16384
#define W_EF   18944    // E: 6 frags hi/lo (kt-major), F: 4 frags at +3072
#define W_D    24064    // 8 frags hi/lo (nt-major)
#define W_H4C0 28160    // chunk c: h4 at 28160+c*4096
#define W_H5C0 30208    //          h5 at 30208+c*4096
#define W_OUT  44544
#define W_TOT  45568

// be / bf slots (dword offsets, after images: 512 + 45568/2 = 23296)
#define STG_BE  23296   // 3
#define STG_BF  23300   // 3

__device__ __forceinline__ float lrelu(float v) { return v >= 0.0f ? v : 0.01f * v; }

__device__ __forceinline__ float tanh_fast(float v) {
    float e = __expf(2.0f * v);
    return 1.0f - 2.0f * __builtin_amdgcn_rcpf(e + 1.0f);
}

__device__ __forceinline__ unsigned short f2h_bits(float v) {
    union { _Float16 h; unsigned short s; } u; u.h = (_Float16)v; return u.s;
}
__device__ __forceinline__ float h2f_bits(unsigned short s) {
    union { _Float16 h; unsigned short s; } u; u.s = s; return (float)u.h;
}
__device__ __forceinline__ unsigned packh2(float a, float b) {
    union { fp16x2 h; unsigned u; } u;
    u.h = __builtin_amdgcn_cvt_pkrtz(a, b);
    return u.u;
}

// deep-pipelined global->LDS staging: float4 x unroll-4
__device__ __forceinline__ void stage(float* dst, const float* __restrict__ src,
                                      int n, int tid) {
    int n4 = n >> 2;
    float4* d = (float4*)dst;
    const float4* s = (const float4*)src;
#pragma unroll 4
    for (int i = tid; i < n4; i += 256) d[i] = s[i];
    for (int i = (n4 << 2) + tid; i < n; i += 256) dst[i] = src[i];
}

// ---------------------------------------------------------------------------
// setup_all: 75 independent blocks x 256 threads.
// ---------------------------------------------------------------------------
__global__ __launch_bounds__(256) void setup_all(
    const float* __restrict__ W_input, const float* __restrict__ b_input,
    const float* __restrict__ W_h1,  const float* __restrict__ b_h1,
    const float* __restrict__ W_h2,  const float* __restrict__ b_h2,
    const float* __restrict__ W_h3,  const float* __restrict__ b_h3,
    const float* __restrict__ W_h4,  const float* __restrict__ b_h4,
    const float* __restrict__ W_h5,  const float* __restrict__ b_h5,
    const float* __restrict__ W_out, const float* __restrict__ b_out,
    const float* __restrict__ W_e1,  const float* __restrict__ b_e1,
    const float* __restrict__ W_e2,  const float* __restrict__ b_e2,
    const float* __restrict__ W_e3,  const float* __restrict__ b_e3,
    const float* __restrict__ W_f1,  const float* __restrict__ b_f1,
    const float* __restrict__ W_f2,  const float* __restrict__ b_f2,
    const float* __restrict__ W_f3,  const float* __restrict__ b_f3,
    const float* __restrict__ W_d1,  const float* __restrict__ b_d1,
    const float* __restrict__ W_d2,  const float* __restrict__ b_d2,
    const float* __restrict__ W_d3,  const float* __restrict__ b_d3,
    float* __restrict__ ws)
{
    const int tid = threadIdx.x;
    const int NT = 256;
    short* wimg = (short*)(ws + BIAS_TOT);

    if (blockIdx.x < 71) {
        // ---- raw-weight fragment packing (unchanged tables) ----
        const int soff[17] = {W_A0,W_A1,W_A2, W_H1A,W_H1B, W_H2A,W_H2B,W_H2C,
                              W_H4C0,W_H5C0, W_H4C0+4096,W_H5C0+4096,
                              W_H4C0+8192,W_H5C0+8192, W_H4C0+12288,W_H5C0+12288,
                              W_OUT};
        const int slay[17] = {0,0,0, 1,1, 2,2,2, 6,7, 6,7, 6,7, 6,7, 8};
        const int sNT[17]  = {4,4,4, 5,5, 5,5,5, 2,4, 2,4, 2,4, 2,4, 1};
        const int sKTS[17] = {1,1,1, 1,1, 1,1,1, 2,1, 2,1, 2,1, 2,1, 2};
        const int snb[17]  = {0,0,0, 0,0, 0,0,0, 0,0, 32,0, 64,0, 96,0, 0};
        const int skb[17]  = {0,32,64, 0,32, 0,32,64, 0,0, 0,32, 0,64, 0,96, 0};

        int seg = 0, local = blockIdx.x;
        while (seg < 16 && local >= sNT[seg] * sKTS[seg]) { local -= sNT[seg] * sKTS[seg]; seg++; }
        const int kts = sKTS[seg];
        const int kt = local % kts, nt = local / kts;
        const int lay = slay[seg];
        short* dst = wimg + soff[seg] + local * 512;

#pragma unroll
        for (int t = 0; t < 2; t++) {
            int idx = tid + t * 256;
            int j = idx & 7, lane = idx >> 3;
            int n = snb[seg] + nt * 16 + (lane & 15);
            int k = skb[seg] + kt * 32 + (lane >> 4) * 8 + j;
            float v = 0.0f;
            switch (lay) {
                case 0: if (n < 50  && k < 75)  v = W_input[n * 75 + k]; break;
                case 1: if (n < 75  && k < 50)  v = W_h1[n * 50 + k]; break;
                case 2: if (n < 75  && k < 75)  v = W_h2[n * 75 + k]; break;
                case 6: if (n < 125 && k < 50)  v = W_h4[n * 50 + k]; break;
                case 7: if (n < 50  && k < 125) v = W_h5[n * 125 + k]; break;
                case 8: if (n < 3   && k < 50)  v = W_out[n * 50 + k]; break;
            }
            dst[idx] = (short)f2h_bits(v);
        }
        return;
    }

    if (blockIdx.x == 74) {
        // ---- plain bias regions (NOT [BD,B4), written by block 73) ----
        for (int i = tid; i < BIAS_TOT; i += NT) {
            if (i >= BD && i < B4) continue;
            float v = 0.0f;
            if (i < B1)        { int o = i - BA;   if (o < 50)  v = b_input[o]; }
            else if (i < B2)   { int o = i - B1;   if (o < 75)  v = b_h1[o]; }
            else if (i < BEF)  { int o = i - B2;   if (o < 75)  v = b_h2[o]; }
            else if (i < BD)   { v = 0.0f; }          // BEF region: fused patches 224..226
            else if (i < B5)   { int o = i - B4;   if (o < 125) v = b_h4[o]; }
            else if (i < BOUT) { int o = i - B5;   if (o < 50)  v = b_h5[o]; }
            else               { int o = i - BOUT; if (o < 3)   v = b_out[o]; }
            ws[i] = v;
        }
        return;
    }

    // ---- collapse chains (blocks 71/72/73), operands staged in LDS ----
    __shared__ __align__(16) float A[17500];
    __shared__ float B[675];
    __shared__ float C[256];
    __shared__ float Dd[256];
    __shared__ float Es[256];
    __shared__ float S[232];

    if (blockIdx.x == 71) {
        // ================= E chain =================
        stage(A, W_e2, 16875, tid);
        for (int i = tid; i < 225; i += NT) { Es[i] = W_e3[i]; C[i] = b_e1[i]; }
        __syncthreads();
        for (int o = tid; o < 675; o += NT) {            // M1 = W_e3 @ W_e2
            int r = o / 225, c = o % 225;
            float s0 = 0.f, s1 = 0.f, s2 = 0.f;
#pragma unroll
            for (int t = 0; t < 75; t += 3) {
                s0 += Es[r * 75 + t]     * A[t * 225 + c];
                s1 += Es[r * 75 + t + 1] * A[(t + 1) * 225 + c];
                s2 += Es[r * 75 + t + 2] * A[(t + 2) * 225 + c];
            }
            B[o] = s0 + s1 + s2;
        }
        for (int o = tid; o < 75; o += NT) {             // ue = W_e2 @ b_e1 + b_e2
            float s0 = 0.f, s1 = 0.f, s2 = 0.f;
#pragma unroll
            for (int t = 0; t < 225; t += 3) {
                s0 += A[o * 225 + t]     * C[t];
                s1 += A[o * 225 + t + 1] * C[t + 1];
                s2 += A[o * 225 + t + 2] * C[t + 2];
            }
            Dd[o] = b_e2[o] + s0 + s1 + s2;
        }
        __syncthreads();
        stage(A, W_e1, 16875, tid);
        __syncthreads();
        for (int o = tid; o < 225; o += NT) {            // sE = M1 @ W_e1
            int r = o / 75, c = o % 75;
            float s0 = 0.f, s1 = 0.f, s2 = 0.f;
#pragma unroll
            for (int t = 0; t < 225; t += 3) {
                s0 += B[r * 225 + t]     * A[t * 75 + c];
                s1 += B[r * 225 + t + 1] * A[(t + 1) * 75 + c];
                s2 += B[r * 225 + t + 2] * A[(t + 2) * 75 + c];
            }
            S[o] = s0 + s1 + s2;
        }
        for (int o = tid; o < 3; o += NT) {              // be
            float s = b_e3[o];
            for (int t = 0; t < 75; t++) s += Es[o * 75 + t] * Dd[t];
            ws[STG_BE + o] = s;
        }
        __syncthreads();
        for (int i = tid; i < 3072; i += NT) {           // E frag images
            int j = i & 7, lane = (i >> 3) & 63, frag = i >> 9, pl = frag & 1, kt = frag >> 1;
            int n = lane & 15, k = kt * 32 + (lane >> 4) * 8 + j;
            float v = (n < 3 && k < 75) ? S[n * 75 + k] : 0.0f;
            float hi = h2f_bits(f2h_bits(v));
            wimg[W_EF + i] = (short)(pl ? f2h_bits(v - hi) : f2h_bits(v));
        }
    } else if (blockIdx.x == 72) {
        // ================= F chain =================
        stage(A,        W_f2, 7500, tid);
        stage(A + 7500, W_f1, 7500, tid);
        for (int i = tid; i < 150; i += NT) { Es[i] = W_f3[i]; C[i] = b_f1[i]; }
        __syncthreads();
        for (int o = tid; o < 450; o += NT) {            // MF = W_f3 @ W_f2
            int r = o / 150, c = o % 150;
            float s0 = 0.f, s1 = 0.f;
#pragma unroll
            for (int t = 0; t < 50; t += 2) {
                s0 += Es[r * 50 + t]     * A[t * 150 + c];
                s1 += Es[r * 50 + t + 1] * A[(t + 1) * 150 + c];
            }
            B[o] = s0 + s1;
        }
        for (int o = tid; o < 50; o += NT) {             // uf
            float s0 = 0.f, s1 = 0.f;
#pragma unroll
            for (int t = 0; t < 150; t += 2) {
                s0 += A[o * 150 + t]     * C[t];
                s1 += A[o * 150 + t + 1] * C[t + 1];
            }
            Dd[o] = b_f2[o] + s0 + s1;
        }
        __syncthreads();
        for (int o = tid; o < 150; o += NT) {            // sF = MF @ W_f1
            int r = o / 50, c = o % 50;
            float s0 = 0.f, s1 = 0.f;
#pragma unroll
            for (int t = 0; t < 150; t += 2) {
                s0 += B[r * 150 + t]     * A[7500 + t * 50 + c];
                s1 += B[r * 150 + t + 1] * A[7500 + (t + 1) * 50 + c];
            }
            S[o] = s0 + s1;
        }
        for (int o = tid; o < 3; o += NT) {              // bf
            float s = b_f3[o];
            for (int t = 0; t < 50; t++) s += Es[o * 50 + t] * Dd[t];
            ws[STG_BF + o] = s;
        }
        __syncthreads();
        for (int i = tid; i < 2048; i += NT) {           // F frag images
            int j = i & 7, lane = (i >> 3) & 63, frag = i >> 9, pl = frag & 1, kt = frag >> 1;
            int n = lane & 15, k = kt * 32 + (lane >> 4) * 8 + j;
            float v = (n < 3 && k < 50) ? S[n * 50 + k] : 0.0f;
            float hi = h2f_bits(f2h_bits(v));
            wimg[W_EF + 3072 + i] = (short)(pl ? f2h_bits(v - hi) : f2h_bits(v));
        }
    } else {
        // ================= D chain =================
        stage(A,         W_d2, 7500, tid);
        stage(A + 7500,  W_d3, 7500, tid);
        stage(A + 15000, W_h3, 2500, tid);
        for (int i = tid; i < 150; i += NT) Es[i] = W_d1[i];
        for (int i = tid; i < 50;  i += NT) C[i] = b_d1[i];
        __syncthreads();
        for (int o = tid; o < 450; o += NT) {            // A1 = W_d2 @ W_d1
            int r = o / 3, c = o % 3;
            float s0 = 0.f, s1 = 0.f;
#pragma unroll
            for (int t = 0; t < 50; t += 2) {
                s0 += A[r * 50 + t]     * Es[t * 3 + c];
                s1 += A[r * 50 + t + 1] * Es[(t + 1) * 3 + c];
            }
            B[o] = s0 + s1;
        }
        for (int o = tid; o < 150; o += NT) {            // v1
            float s0 = 0.f, s1 = 0.f;
#pragma unroll
            for (int t = 0; t < 50; t += 2) {
                s0 += A[o * 50 + t]     * C[t];
                s1 += A[o * 50 + t + 1] * C[t + 1];
            }
            Dd[o] = b_d2[o] + s0 + s1;
        }
        __syncthreads();
        for (int o = tid; o < 150; o += NT) {            // A2 = W_d3 @ A1 -> Es
            int r = o / 3, c = o % 3;
            float s0 = 0.f, s1 = 0.f;
#pragma unroll
            for (int t = 0; t < 150; t += 2) {
                s0 += A[7500 + r * 150 + t]     * B[t * 3 + c];
                s1 += A[7500 + r * 150 + t + 1] * B[(t + 1) * 3 + c];
            }
            Es[o] = s0 + s1;
        }
        for (int o = tid; o < 50; o += NT) {             // v2 -> C
            float s0 = 0.f, s1 = 0.f;
#pragma unroll
            for (int t = 0; t < 150; t += 2) {
                s0 += A[7500 + o * 150 + t]     * Dd[t];
                s1 += A[7500 + o * 150 + t + 1] * Dd[t + 1];
            }
            C[o] = b_d3[o] + s0 + s1;
        }
        __syncthreads();
        for (int o = tid; o < 150; o += NT) {            // sD = W_h3 @ A2
            int r = o / 3, c = o % 3;
            float s0 = 0.f, s1 = 0.f;
#pragma unroll
            for (int t = 0; t < 50; t += 2) {
                s0 += A[15000 + r * 50 + t]     * Es[t * 3 + c];
                s1 += A[15000 + r * 50 + t + 1] * Es[(t + 1) * 3 + c];
            }
            S[o] = s0 + s1;
        }
        for (int o = tid; o < 64; o += NT) {             // bd -> BD region (padded)
            float v = 0.0f;
            if (o < 50) {
                float s0 = 0.f, s1 = 0.f;
#pragma unroll
                for (int t = 0; t < 50; t += 2) {
                    s0 += A[15000 + o * 50 + t]     * C[t];
                    s1 += A[15000 + o * 50 + t + 1] * C[t + 1];
                }
                v = b_h3[o] + s0 + s1;
            }
            ws[BD + o] = v;
        }
        __syncthreads();
        for (int i = tid; i < 4096; i += NT) {           // D frag images
            int j = i & 7, lane = (i >> 3) & 63, frag = i >> 9, pl = frag & 1, nt = frag >> 1;
            int n = nt * 16 + (lane & 15), k = (lane >> 4) * 8 + j;
            float v = (n < 50 && k < 3) ? S[n * 3 + k] : 0.0f;
            float hi = h2f_bits(f2h_bits(v));
            wimg[W_D + i] = (short)(pl ? f2h_bits(v - hi) : f2h_bits(v));
        }
    }
}

// ---------------------------------------------------------------------------
// main kernel helpers
// ---------------------------------------------------------------------------
__device__ __forceinline__ void copyStage(short* dst, const short* src, int nsh, int tid) {
    uint4_* d = (uint4_*)dst;
    const uint4_* s = (const uint4_*)src;
    int n = nsh >> 3;
    for (int i = tid; i < n; i += 256) d[i] = s[i];
}

__device__ __forceinline__ half8 bfragH(const short* wb, int fragIdx, int lane) {
    return *(const half8*)(wb + fragIdx * 512 + lane * 8);
}

__device__ __forceinline__ half8 readAf(const unsigned int* acts, int row0, int pane, int lane) {
    int m = lane & 15, qd = lane >> 4;
    const unsigned int* p = &acts[(row0 + m) * AST + pane + (qd & 1) * 8];
    uint4_ a = *(const uint4_*)p;
    uint4_ b = *(const uint4_*)(p + 4);
    unsigned sel = (qd >> 1) ? 0x07060302u : 0x05040100u;
    union { unsigned u[4]; half8 v; } r;
    r.u[0] = __builtin_amdgcn_perm(a.y, a.x, sel);
    r.u[1] = __builtin_amdgcn_perm(a.w, a.z, sel);
    r.u[2] = __builtin_amdgcn_perm(b.y, b.x, sel);
    r.u[3] = __builtin_amdgcn_perm(b.w, b.z, sel);
    return r.v;
}

__device__ __forceinline__ void writeCf(unsigned int* acts, int row0q, int dcol,
                                        f32x4 va, f32x4 vb) {
    unsigned int* p = &acts[row0q * AST + dcol];
#pragma unroll
    for (int r = 0; r < 4; r++) p[r * AST] = packh2(va[r], vb[r]);
}

__device__ __forceinline__ void t2s(f32x4& a0, f32x4& a1, half8 x0, half8 x1, half8 b) {
    a0 = MFMAH(x0, b, a0);
    a1 = MFMAH(x1, b, a1);
}
__device__ __forceinline__ void t2p(f32x4& a0, f32x4& a1, half8 x0, half8 x1,
                                    half8 bh, half8 bl) {
    a0 = MFMAH(x0, bh, a0);
    a1 = MFMAH(x1, bh, a1);
    a0 = MFMAH(x0, bl, a0);
    a1 = MFMAH(x1, bl, a1);
}

// ---------------------------------------------------------------------------
// main fused kernel
// ---------------------------------------------------------------------------
__global__ __launch_bounds__(256, 3) void fused_mfma(
    const float* __restrict__ xin,
    const float* __restrict__ ws,
    float* __restrict__ out)
{
    __shared__ unsigned int acts[MTILE * AST];
    __shared__ short wbuf[2][5120];
    __shared__ float sbias[BIAS_TOT];

    const int tid = threadIdx.x;
    const int wv = tid >> 6;
    const int lane = tid & 63;
    const int qd = lane >> 4;
    const int mcol = lane & 15;
    const int rw = wv * 32;
    const short* wimg = (const short*)(ws + BIAS_TOT);
    const f32x4 zero4 = {0.f, 0.f, 0.f, 0.f};

    const int g0 = blockIdx.x * MTILE;
    const int bb = g0 / HW;
    const int p0 = g0 - bb * HW;
    const int yb = p0 / IW;
    const int xblk = p0 - yb * IW;
    const float* __restrict__ xb = xin + bb * 3 * HW;

    // patch (15 x 132 floats) + tap table alias the acts array (first real
    // acts write happens 3 barriers later).
    float* patch = (float*)acts;
    int*   stab  = (int*)(acts + 1984);

    // bias load; BEF = be + bf summed from setup slots
    for (int i = tid; i < BIAS_TOT; i += 256) {
        float v = ws[i];
        unsigned d = (unsigned)(i - BEF);
        if (d < 3u) v = ws[STG_BE + d] + ws[STG_BF + d];
        sbias[i] = v;
    }
    // stage reflect-padded patch: rows (c*5+r), cols i -> x = xblk-2+i
    for (int e = tid; e < 1980; e += 256) {
        int cr = e / 132;
        int i  = e - cr * 132;
        int c  = cr / 5, r = cr - c * 5;
        int ty = yb + r - 2; ty = ty < 0 ? -ty : ty; ty = (766 - ty) < ty ? 766 - ty : ty;
        int tx = xblk - 2 + i; tx = tx < 0 ? -tx : tx; tx = (766 - tx) < tx ? 766 - tx : tx;
        patch[cr * 132 + i] = xb[c * HW + ty * IW + tx];
    }
    // tap offset table: qq -> (c*5+rr)*132 + ss  (0 for padded taps)
    if (tid < 96) {
        int v = 0;
        if (tid < 75) {
            int c = tid / 25, rem = tid - 25 * c;
            int rr = rem / 5, ss = rem - 5 * rr;
            v = (c * 5 + rr) * 132 + ss;
        }
        stab[tid] = v;
    }
    copyStage(wbuf[0], wimg + W_A0, 2048, tid);
    __syncthreads();

    // build sw fragments from LDS patch
    half8 swf[3][2];
    {
        int st[3][8];
#pragma unroll
        for (int kt = 0; kt < 3; kt++)
#pragma unroll
            for (int j = 0; j < 8; j++)
                st[kt][j] = stab[kt * 32 + qd * 8 + j];
#pragma unroll
        for (int mt = 0; mt < 2; mt++) {
            const int xloc = wv * 32 + mt * 16 + mcol;
#pragma unroll
            for (int kt = 0; kt < 3; kt++) {
                union { unsigned u32[4]; half8 v; } u;
#pragma unroll
                for (int jj = 0; jj < 8; jj += 2) {
                    float v0 = patch[st[kt][jj]     + xloc];
                    float v1 = patch[st[kt][jj + 1] + xloc];
                    if (kt == 2) {
                        int qq0 = 64 + qd * 8 + jj;
                        v0 = (qq0     < 75) ? v0 : 0.0f;
                        v1 = (qq0 + 1 < 75) ? v1 : 0.0f;
                    }
                    u.u32[jj >> 1] = packh2(v0, v1);
                }
                swf[kt][mt] = u.v;
            }
        }
    }

    // ===== layer A =====
    f32x4 accA[4][2];
#pragma unroll
    for (int nt = 0; nt < 4; nt++) { accA[nt][0] = zero4; accA[nt][1] = zero4; }

    copyStage(wbuf[1], wimg + W_A1, 2048, tid);
#pragma unroll
    for (int nt = 0; nt < 4; nt++)
        t2s(accA[nt][0], accA[nt][1], swf[0][0], swf[0][1], bfragH(wbuf[0], nt, lane));
    __syncthreads();
    copyStage(wbuf[0], wimg + W_A2, 2048, tid);
#pragma unroll
    for (int nt = 0; nt < 4; nt++)
        t2s(accA[nt][0], accA[nt][1], swf[1][0], swf[1][1], bfragH(wbuf[1], nt, lane));
    __syncthreads();
    copyStage(wbuf[1], wimg + W_H1A, 2560, tid);
#pragma unroll
    for (int nt = 0; nt < 4; nt++)
        t2s(accA[nt][0], accA[nt][1], swf[2][0], swf[2][1], bfragH(wbuf[0], nt, lane));

    f32x4 x1C[4][2];
    half8 x1f[2][2];
#pragma unroll
    for (int nt = 0; nt < 4; nt++) {
        float bv = sbias[BA + nt * 16 + mcol];
#pragma unroll
        for (int mt = 0; mt < 2; mt++) {
            f32x4 v = accA[nt][mt];
            v[0] += bv; v[1] += bv; v[2] += bv; v[3] += bv;
            x1C[nt][mt] = v;
        }
    }
#pragma unroll
    for (int mt = 0; mt < 2; mt++) {
        writeCf(acts, rw + mt * 16 + qd * 4, mcol,      x1C[0][mt], x1C[1][mt]);
        writeCf(acts, rw + mt * 16 + qd * 4, 16 + mcol, x1C[2][mt], x1C[3][mt]);
    }
#pragma unroll
    for (int kt = 0; kt < 2; kt++)
#pragma unroll
        for (int mt = 0; mt < 2; mt++)
            x1f[kt][mt] = readAf(acts, rw + mt * 16, kt * 16, lane);
    __syncthreads();

    // ===== h1 =====
    f32x4 acc1[5][2];
#pragma unroll
    for (int nt = 0; nt < 5; nt++) { acc1[nt][0] = zero4; acc1[nt][1] = zero4; }

    copyStage(wbuf[0], wimg + W_H1B, 2560, tid);
#pragma unroll
    for (int nt = 0; nt < 5; nt++)
        t2s(acc1[nt][0], acc1[nt][1], x1f[0][0], x1f[0][1], bfragH(wbuf[1], nt, lane));
    __syncthreads();
    copyStage(wbuf[1], wimg + W_H2A, 2560, tid);
#pragma unroll
    for (int nt = 0; nt < 5; nt++)
        t2s(acc1[nt][0], acc1[nt][1], x1f[1][0], x1f[1][1], bfragH(wbuf[0], nt, lane));
#pragma unroll
    for (int mt = 0; mt < 2; mt++) {
        f32x4 w5[5];
#pragma unroll
        for (int nt = 0; nt < 5; nt++) {
            float bv = sbias[B1 + nt * 16 + mcol];
            f32x4 v = acc1[nt][mt];
            v[0] = lrelu(v[0] + bv); v[1] = lrelu(v[1] + bv);
            v[2] = lrelu(v[2] + bv); v[3] = lrelu(v[3] + bv);
            w5[nt] = v;
        }
        writeCf(acts, rw + mt * 16 + qd * 4, mcol,      w5[0], w5[1]);
        writeCf(acts, rw + mt * 16 + qd * 4, 16 + mcol, w5[2], w5[3]);
        writeCf(acts, rw + mt * 16 + qd * 4, 32 + mcol, w5[4], zero4);
    }
    __syncthreads();

    // ===== h2 =====
    f32x4 acc2[5][2];
#pragma unroll
    for (int nt = 0; nt < 5; nt++) { acc2[nt][0] = zero4; acc2[nt][1] = zero4; }

    copyStage(wbuf[0], wimg + W_H2B, 2560, tid);
    {
        half8 a0 = readAf(acts, rw, 0, lane), a1 = readAf(acts, rw + 16, 0, lane);
#pragma unroll
        for (int nt = 0; nt < 5; nt++)
            t2s(acc2[nt][0], acc2[nt][1], a0, a1, bfragH(wbuf[1], nt, lane));
    }
    __syncthreads();
    copyStage(wbuf[1], wimg + W_H2C, 2560, tid);
    {
        half8 a0 = readAf(acts, rw, 16, lane), a1 = readAf(acts, rw + 16, 16, lane);
#pragma unroll
        for (int nt = 0; nt < 5; nt++)
            t2s(acc2[nt][0], acc2[nt][1], a0, a1, bfragH(wbuf[0], nt, lane));
    }
    __syncthreads();
    copyStage(wbuf[0], wimg + W_EF, 5120, tid);
    {
        half8 a0 = readAf(acts, rw, 32, lane), a1 = readAf(acts, rw + 16, 32, lane);
#pragma unroll
        for (int nt = 0; nt < 5; nt++)
            t2s(acc2[nt][0], acc2[nt][1], a0, a1, bfragH(wbuf[1], nt, lane));
    }
#pragma unroll
    for (int mt = 0; mt < 2; mt++) {
        f32x4 w5[5];
#pragma unroll
        for (int nt = 0; nt < 5; nt++) {
            float bv = sbias[B2 + nt * 16 + mcol];
            f32x4 v = acc2[nt][mt];
            v[0] = tanh_fast(v[0] + bv); v[1] = tanh_fast(v[1] + bv);
            v[2] = tanh_fast(v[2] + bv); v[3] = tanh_fast(v[3] + bv);
            w5[nt] = v;
        }
        writeCf(acts, rw + mt * 16 + qd * 4, mcol,      w5[0], w5[1]);
        writeCf(acts, rw + mt * 16 + qd * 4, 16 + mcol, w5[2], w5[3]);
        writeCf(acts, rw + mt * 16 + qd * 4, 32 + mcol, w5[4], zero4);
    }
    __syncthreads();

    // ===== EF =====
    copyStage(wbuf[1], wimg + W_D, 4096, tid);
    f32x4 accEF[2];
    {
        float bv = sbias[BEF + mcol];
        accEF[0] = (f32x4){bv, bv, bv, bv};
        accEF[1] = accEF[0];
    }
#pragma unroll
    for (int kt = 0; kt < 3; kt++) {
        half8 a0 = readAf(acts, rw, kt * 16, lane), a1 = readAf(acts, rw + 16, kt * 16, lane);
        t2p(accEF[0], accEF[1], a0, a1,
            bfragH(wbuf[0], kt * 2, lane), bfragH(wbuf[0], kt * 2 + 1, lane));
    }
    {
        const short* Fp = wbuf[0] + 3072;
#pragma unroll
        for (int kt = 0; kt < 2; kt++)
            t2p(accEF[0], accEF[1], x1f[kt][0], x1f[kt][1],
                bfragH(Fp, kt * 2, lane), bfragH(Fp, kt * 2 + 1, lane));
    }
    half8 x4f[2];
#pragma unroll
    for (int mt = 0; mt < 2; mt++) {
        f32x4 v = accEF[mt];
        v[0] = lrelu(v[0]); v[1] = lrelu(v[1]); v[2] = lrelu(v[2]); v[3] = lrelu(v[3]);
        writeCf(acts, rw + mt * 16 + qd * 4, 32 + mcol, v, zero4);
    }
    x4f[0] = readAf(acts, rw, 32, lane);
    x4f[1] = readAf(acts, rw + 16, 32, lane);
    __syncthreads();

    // ===== D =====
    copyStage(wbuf[0], wimg + W_H4C0, 2048, tid);
    f32x4 accD[4][2];
#pragma unroll
    for (int nt = 0; nt < 4; nt++) {
        float bv = sbias[BD + nt * 16 + mcol];
        accD[nt][0] = (f32x4){bv, bv, bv, bv};
        accD[nt][1] = accD[nt][0];
    }
#pragma unroll
    for (int nt = 0; nt < 4; nt++)
        t2p(accD[nt][0], accD[nt][1], x4f[0], x4f[1],
            bfragH(wbuf[1], nt * 2, lane), bfragH(wbuf[1], nt * 2 + 1, lane));
#pragma unroll
    for (int mt = 0; mt < 2; mt++) {
        writeCf(acts, rw + mt * 16 + qd * 4, mcol,      accD[0][mt], accD[1][mt]);
        writeCf(acts, rw + mt * 16 + qd * 4, 16 + mcol, accD[2][mt], accD[3][mt]);
    }
    half8 xdf[2][2];
#pragma unroll
    for (int kt = 0; kt < 2; kt++)
#pragma unroll
        for (int mt = 0; mt < 2; mt++)
            xdf[kt][mt] = readAf(acts, rw + mt * 16, kt * 16, lane);

    f32x4 x6a[4][2];
#pragma unroll
    for (int nt = 0; nt < 4; nt++) {
        float bv = sbias[B5 + nt * 16 + mcol];
#pragma unroll
        for (int mt = 0; mt < 2; mt++) {
            f32x4 v;
            v[0] = bv - x1C[nt][mt][0]; v[1] = bv - x1C[nt][mt][1];
            v[2] = bv - x1C[nt][mt][2]; v[3] = bv - x1C[nt][mt][3];
            x6a[nt][mt] = v;
        }
    }
    __syncthreads();

    // ===== h4/h5 chunks =====
    for (int c = 0; c < 4; c++) {
        copyStage(wbuf[1], wimg + W_H5C0 + c * 4096, 2048, tid);
        f32x4 acc5[2][2];
#pragma unroll
        for (int nt2 = 0; nt2 < 2; nt2++) {
            float bv = sbias[B4 + c * 32 + nt2 * 16 + mcol];
            acc5[nt2][0] = (f32x4){bv, bv, bv, bv};
            acc5[nt2][1] = acc5[nt2][0];
        }
#pragma unroll
        for (int nt2 = 0; nt2 < 2; nt2++)
#pragma unroll
            for (int kt = 0; kt < 2; kt++)
                t2s(acc5[nt2][0], acc5[nt2][1], xdf[kt][0], xdf[kt][1],
                    bfragH(wbuf[0], nt2 * 2 + kt, lane));
#pragma unroll
        for (int mt = 0; mt < 2; mt++) {
            f32x4 v0 = acc5[0][mt], v1 = acc5[1][mt];
            v0[0] = tanh_fast(v0[0]); v0[1] = tanh_fast(v0[1]);
            v0[2] = tanh_fast(v0[2]); v0[3] = tanh_fast(v0[3]);
            v1[0] = tanh_fast(v1[0]); v1[1] = tanh_fast(v1[1]);
            v1[2] = tanh_fast(v1[2]); v1[3] = tanh_fast(v1[3]);
            writeCf(acts, rw + mt * 16 + qd * 4, 32 + mcol, v0, v1);
        }
        half8 chf[2];
        chf[0] = readAf(acts, rw, 32, lane);
        chf[1] = readAf(acts, rw + 16, 32, lane);
        __syncthreads();

        if (c < 3) copyStage(wbuf[0], wimg + W_H4C0 + (c + 1) * 4096, 2048, tid);
        else       copyStage(wbuf[0], wimg + W_OUT, 1024, tid);
#pragma unroll
        for (int nt = 0; nt < 4; nt++)
            t2s(x6a[nt][0], x6a[nt][1], chf[0], chf[1], bfragH(wbuf[1], nt, lane));
        __syncthreads();
    }

    // ===== out =====
#pragma unroll
    for (int mt = 0; mt < 2; mt++) {
        writeCf(acts, rw + mt * 16 + qd * 4, mcol,      x6a[0][mt], x6a[1][mt]);
        writeCf(acts, rw + mt * 16 + qd * 4, 16 + mcol, x6a[2][mt], x6a[3][mt]);
    }
    f32x4 accO[2];
    {
        float bv = sbias[BOUT + mcol];
        accO[0] = (f32x4){bv, bv, bv, bv};
        accO[1] = accO[0];
    }
#pragma unroll
    for (int kt = 0; kt < 2; kt++) {
        half8 a0 = readAf(acts, rw, kt * 16, lane), a1 = readAf(acts, rw + 16, kt * 16, lane);
        t2s(accO[0], accO[1], a0, a1, bfragH(wbuf[0], kt, lane));
    }
    if (mcol < 3) {
#pragma unroll
        for (int mt = 0; mt < 2; mt++) {
#pragma unroll
            for (int r = 0; r < 4; r++) {
                int p = p0 + wv * 32 + mt * 16 + qd * 4 + r;
                out[(bb * 3 + mcol) * HW + p] = lrelu(accO[mt][r]);
            }
        }
    }
}

extern "C" void kernel_launch(void* const* d_in, const int* in_sizes, int n_in,
                              void* d_out, int out_size, void* d_ws, size_t ws_size,
                              hipStream_t stream)
{
    const float* xin = (const float*)d_in[0];
    float* ws = (float*)d_ws;

    setup_all<<<75, 256, 0, stream>>>(
        (const float*)d_in[1],  (const float*)d_in[2],   // input
        (const float*)d_in[3],  (const float*)d_in[4],   // h1
        (const float*)d_in[5],  (const float*)d_in[6],   // h2
        (const float*)d_in[7],  (const float*)d_in[8],   // h3
        (const float*)d_in[9],  (const float*)d_in[10],  // h4
        (const float*)d_in[11], (const float*)d_in[12],  // h5
        (const float*)d_in[13], (const float*)d_in[14],  // out
        (const float*)d_in[15], (const float*)d_in[16],  // e1
        (const float*)d_in[17], (const float*)d_in[18],  // e2
        (const float*)d_in[19], (const float*)d_in[20],  // e3
        (const float*)d_in[21], (const float*)d_in[22],  // f1
        (const float*)d_in[23], (const float*)d_in[24],  // f2
        (const float*)d_in[25], (const float*)d_in[26],  // f3
        (const float*)d_in[27], (const float*)d_in[28],  // d1
        (const float*)d_in[29], (const float*)d_in[30],  // d2
        (const float*)d_in[31], (const float*)d_in[32],  // d3
        ws);

    fused_mfma<<<NBLK, 256, 0, stream>>>(xin, ws, (float*)d_out);
}

// Round 11
// 235.515 us; speedup vs baseline: 10.1644x; 1.0855x over previous
//
#include <hip/hip_runtime.h>

// ---------------------------------------------------------------------------
// Round 11: barrier-free main loop.
//  - B-fragments read DIRECTLY from global (L2-resident 91KB image, perfectly
//    coalesced 16B/lane) — wbuf LDS staging and ALL post-prologue barriers
//    removed (acts traffic is wave-private).
//  - LDS 49152 -> 28672 B => 5 blocks/CU. setup_all identical to R10.
// ---------------------------------------------------------------------------

#define IW 384
#define HW (384 * 384)           // 147456
#define NPIX (4 * HW)            // 589824
#define MTILE 128
#define NBLK (NPIX / MTILE)      // 4608
#define AST 52                   // acts row stride in dwords (48 data + 4 pad)

typedef _Float16 half8 __attribute__((ext_vector_type(8)));
typedef __fp16 fp16x2 __attribute__((ext_vector_type(2)));
typedef __attribute__((ext_vector_type(4))) float f32x4;
typedef __attribute__((ext_vector_type(4))) unsigned int uint4_;

#define MFMAH(A, B, C) __builtin_amdgcn_mfma_f32_16x16x32_f16((A), (B), (C), 0, 0, 0)

// bias table offsets (dwords in ws)
#define BA   0
#define B1   64
#define B2   144
#define BEF  224
#define BD   240
#define B4   304
#define B5   432
#define BOUT 496
#define BIAS_TOT 512

// weight image segment offsets (shorts, after bias table). frag = 512 shorts.
#define W_A0   0
#define W_A1   2048
#define W_A2   4096
#define W_H1A  6144
#define W_H1B  8704
#define W_H2A  11264
#define W_H2B  13824
#define W_H2C  16384
#define W_EF   18944    // E: 6 frags hi/lo (kt-major), F: 4 frags at +3072
#define W_D    24064    // 8 frags hi/lo (nt-major)
#define W_H4C0 28160    // chunk c: h4 at 28160+c*4096
#define W_H5C0 30208    //          h5 at 30208+c*4096
#define W_OUT  44544
#define W_TOT  45568

// be / bf slots (dword offsets, after images: 512 + 45568/2 = 23296)
#define STG_BE  23296   // 3
#define STG_BF  23300   // 3

__device__ __forceinline__ float lrelu(float v) { return v >= 0.0f ? v : 0.01f * v; }

__device__ __forceinline__ float tanh_fast(float v) {
    float e = __expf(2.0f * v);
    return 1.0f - 2.0f * __builtin_amdgcn_rcpf(e + 1.0f);
}

__device__ __forceinline__ unsigned short f2h_bits(float v) {
    union { _Float16 h; unsigned short s; } u; u.h = (_Float16)v; return u.s;
}
__device__ __forceinline__ float h2f_bits(unsigned short s) {
    union { _Float16 h; unsigned short s; } u; u.s = s; return (float)u.h;
}
__device__ __forceinline__ unsigned packh2(float a, float b) {
    union { fp16x2 h; unsigned u; } u;
    u.h = __builtin_amdgcn_cvt_pkrtz(a, b);
    return u.u;
}

// deep-pipelined global->LDS staging: float4 x unroll-4
__device__ __forceinline__ void stage(float* dst, const float* __restrict__ src,
                                      int n, int tid) {
    int n4 = n >> 2;
    float4* d = (float4*)dst;
    const float4* s = (const float4*)src;
#pragma unroll 4
    for (int i = tid; i < n4; i += 256) d[i] = s[i];
    for (int i = (n4 << 2) + tid; i < n; i += 256) dst[i] = src[i];
}

// ---------------------------------------------------------------------------
// setup_all: 75 independent blocks x 256 threads. (identical to R10)
// ---------------------------------------------------------------------------
__global__ __launch_bounds__(256) void setup_all(
    const float* __restrict__ W_input, const float* __restrict__ b_input,
    const float* __restrict__ W_h1,  const float* __restrict__ b_h1,
    const float* __restrict__ W_h2,  const float* __restrict__ b_h2,
    const float* __restrict__ W_h3,  const float* __restrict__ b_h3,
    const float* __restrict__ W_h4,  const float* __restrict__ b_h4,
    const float* __restrict__ W_h5,  const float* __restrict__ b_h5,
    const float* __restrict__ W_out, const float* __restrict__ b_out,
    const float* __restrict__ W_e1,  const float* __restrict__ b_e1,
    const float* __restrict__ W_e2,  const float* __restrict__ b_e2,
    const float* __restrict__ W_e3,  const float* __restrict__ b_e3,
    const float* __restrict__ W_f1,  const float* __restrict__ b_f1,
    const float* __restrict__ W_f2,  const float* __restrict__ b_f2,
    const float* __restrict__ W_f3,  const float* __restrict__ b_f3,
    const float* __restrict__ W_d1,  const float* __restrict__ b_d1,
    const float* __restrict__ W_d2,  const float* __restrict__ b_d2,
    const float* __restrict__ W_d3,  const float* __restrict__ b_d3,
    float* __restrict__ ws)
{
    const int tid = threadIdx.x;
    const int NT = 256;
    short* wimg = (short*)(ws + BIAS_TOT);

    if (blockIdx.x < 71) {
        const int soff[17] = {W_A0,W_A1,W_A2, W_H1A,W_H1B, W_H2A,W_H2B,W_H2C,
                              W_H4C0,W_H5C0, W_H4C0+4096,W_H5C0+4096,
                              W_H4C0+8192,W_H5C0+8192, W_H4C0+12288,W_H5C0+12288,
                              W_OUT};
        const int slay[17] = {0,0,0, 1,1, 2,2,2, 6,7, 6,7, 6,7, 6,7, 8};
        const int sNT[17]  = {4,4,4, 5,5, 5,5,5, 2,4, 2,4, 2,4, 2,4, 1};
        const int sKTS[17] = {1,1,1, 1,1, 1,1,1, 2,1, 2,1, 2,1, 2,1, 2};
        const int snb[17]  = {0,0,0, 0,0, 0,0,0, 0,0, 32,0, 64,0, 96,0, 0};
        const int skb[17]  = {0,32,64, 0,32, 0,32,64, 0,0, 0,32, 0,64, 0,96, 0};

        int seg = 0, local = blockIdx.x;
        while (seg < 16 && local >= sNT[seg] * sKTS[seg]) { local -= sNT[seg] * sKTS[seg]; seg++; }
        const int kts = sKTS[seg];
        const int kt = local % kts, nt = local / kts;
        const int lay = slay[seg];
        short* dst = wimg + soff[seg] + local * 512;

#pragma unroll
        for (int t = 0; t < 2; t++) {
            int idx = tid + t * 256;
            int j = idx & 7, lane = idx >> 3;
            int n = snb[seg] + nt * 16 + (lane & 15);
            int k = skb[seg] + kt * 32 + (lane >> 4) * 8 + j;
            float v = 0.0f;
            switch (lay) {
                case 0: if (n < 50  && k < 75)  v = W_input[n * 75 + k]; break;
                case 1: if (n < 75  && k < 50)  v = W_h1[n * 50 + k]; break;
                case 2: if (n < 75  && k < 75)  v = W_h2[n * 75 + k]; break;
                case 6: if (n < 125 && k < 50)  v = W_h4[n * 50 + k]; break;
                case 7: if (n < 50  && k < 125) v = W_h5[n * 125 + k]; break;
                case 8: if (n < 3   && k < 50)  v = W_out[n * 50 + k]; break;
            }
            dst[idx] = (short)f2h_bits(v);
        }
        return;
    }

    if (blockIdx.x == 74) {
        for (int i = tid; i < BIAS_TOT; i += NT) {
            if (i >= BD && i < B4) continue;
            float v = 0.0f;
            if (i < B1)        { int o = i - BA;   if (o < 50)  v = b_input[o]; }
            else if (i < B2)   { int o = i - B1;   if (o < 75)  v = b_h1[o]; }
            else if (i < BEF)  { int o = i - B2;   if (o < 75)  v = b_h2[o]; }
            else if (i < BD)   { v = 0.0f; }
            else if (i < B5)   { int o = i - B4;   if (o < 125) v = b_h4[o]; }
            else if (i < BOUT) { int o = i - B5;   if (o < 50)  v = b_h5[o]; }
            else               { int o = i - BOUT; if (o < 3)   v = b_out[o]; }
            ws[i] = v;
        }
        return;
    }

    __shared__ __align__(16) float A[17500];
    __shared__ float B[675];
    __shared__ float C[256];
    __shared__ float Dd[256];
    __shared__ float Es[256];
    __shared__ float S[232];

    if (blockIdx.x == 71) {
        // ================= E chain =================
        stage(A, W_e2, 16875, tid);
        for (int i = tid; i < 225; i += NT) { Es[i] = W_e3[i]; C[i] = b_e1[i]; }
        __syncthreads();
        for (int o = tid; o < 675; o += NT) {
            int r = o / 225, c = o % 225;
            float s0 = 0.f, s1 = 0.f, s2 = 0.f;
#pragma unroll
            for (int t = 0; t < 75; t += 3) {
                s0 += Es[r * 75 + t]     * A[t * 225 + c];
                s1 += Es[r * 75 + t + 1] * A[(t + 1) * 225 + c];
                s2 += Es[r * 75 + t + 2] * A[(t + 2) * 225 + c];
            }
            B[o] = s0 + s1 + s2;
        }
        for (int o = tid; o < 75; o += NT) {
            float s0 = 0.f, s1 = 0.f, s2 = 0.f;
#pragma unroll
            for (int t = 0; t < 225; t += 3) {
                s0 += A[o * 225 + t]     * C[t];
                s1 += A[o * 225 + t + 1] * C[t + 1];
                s2 += A[o * 225 + t + 2] * C[t + 2];
            }
            Dd[o] = b_e2[o] + s0 + s1 + s2;
        }
        __syncthreads();
        stage(A, W_e1, 16875, tid);
        __syncthreads();
        for (int o = tid; o < 225; o += NT) {
            int r = o / 75, c = o % 75;
            float s0 = 0.f, s1 = 0.f, s2 = 0.f;
#pragma unroll
            for (int t = 0; t < 225; t += 3) {
                s0 += B[r * 225 + t]     * A[t * 75 + c];
                s1 += B[r * 225 + t + 1] * A[(t + 1) * 75 + c];
                s2 += B[r * 225 + t + 2] * A[(t + 2) * 75 + c];
            }
            S[o] = s0 + s1 + s2;
        }
        for (int o = tid; o < 3; o += NT) {
            float s = b_e3[o];
            for (int t = 0; t < 75; t++) s += Es[o * 75 + t] * Dd[t];
            ws[STG_BE + o] = s;
        }
        __syncthreads();
        for (int i = tid; i < 3072; i += NT) {
            int j = i & 7, lane = (i >> 3) & 63, frag = i >> 9, pl = frag & 1, kt = frag >> 1;
            int n = lane & 15, k = kt * 32 + (lane >> 4) * 8 + j;
            float v = (n < 3 && k < 75) ? S[n * 75 + k] : 0.0f;
            float hi = h2f_bits(f2h_bits(v));
            wimg[W_EF + i] = (short)(pl ? f2h_bits(v - hi) : f2h_bits(v));
        }
    } else if (blockIdx.x == 72) {
        // ================= F chain =================
        stage(A,        W_f2, 7500, tid);
        stage(A + 7500, W_f1, 7500, tid);
        for (int i = tid; i < 150; i += NT) { Es[i] = W_f3[i]; C[i] = b_f1[i]; }
        __syncthreads();
        for (int o = tid; o < 450; o += NT) {
            int r = o / 150, c = o % 150;
            float s0 = 0.f, s1 = 0.f;
#pragma unroll
            for (int t = 0; t < 50; t += 2) {
                s0 += Es[r * 50 + t]     * A[t * 150 + c];
                s1 += Es[r * 50 + t + 1] * A[(t + 1) * 150 + c];
            }
            B[o] = s0 + s1;
        }
        for (int o = tid; o < 50; o += NT) {
            float s0 = 0.f, s1 = 0.f;
#pragma unroll
            for (int t = 0; t < 150; t += 2) {
                s0 += A[o * 150 + t]     * C[t];
                s1 += A[o * 150 + t + 1] * C[t + 1];
            }
            Dd[o] = b_f2[o] + s0 + s1;
        }
        __syncthreads();
        for (int o = tid; o < 150; o += NT) {
            int r = o / 50, c = o % 50;
            float s0 = 0.f, s1 = 0.f;
#pragma unroll
            for (int t = 0; t < 150; t += 2) {
                s0 += B[r * 150 + t]     * A[7500 + t * 50 + c];
                s1 += B[r * 150 + t + 1] * A[7500 + (t + 1) * 50 + c];
            }
            S[o] = s0 + s1;
        }
        for (int o = tid; o < 3; o += NT) {
            float s = b_f3[o];
            for (int t = 0; t < 50; t++) s += Es[o * 50 + t] * Dd[t];
            ws[STG_BF + o] = s;
        }
        __syncthreads();
        for (int i = tid; i < 2048; i += NT) {
            int j = i & 7, lane = (i >> 3) & 63, frag = i >> 9, pl = frag & 1, kt = frag >> 1;
            int n = lane & 15, k = kt * 32 + (lane >> 4) * 8 + j;
            float v = (n < 3 && k < 50) ? S[n * 50 + k] : 0.0f;
            float hi = h2f_bits(f2h_bits(v));
            wimg[W_EF + 3072 + i] = (short)(pl ? f2h_bits(v - hi) : f2h_bits(v));
        }
    } else {
        // ================= D chain =================
        stage(A,         W_d2, 7500, tid);
        stage(A + 7500,  W_d3, 7500, tid);
        stage(A + 15000, W_h3, 2500, tid);
        for (int i = tid; i < 150; i += NT) Es[i] = W_d1[i];
        for (int i = tid; i < 50;  i += NT) C[i] = b_d1[i];
        __syncthreads();
        for (int o = tid; o < 450; o += NT) {
            int r = o / 3, c = o % 3;
            float s0 = 0.f, s1 = 0.f;
#pragma unroll
            for (int t = 0; t < 50; t += 2) {
                s0 += A[r * 50 + t]     * Es[t * 3 + c];
                s1 += A[r * 50 + t + 1] * Es[(t + 1) * 3 + c];
            }
            B[o] = s0 + s1;
        }
        for (int o = tid; o < 150; o += NT) {
            float s0 = 0.f, s1 = 0.f;
#pragma unroll
            for (int t = 0; t < 50; t += 2) {
                s0 += A[o * 50 + t]     * C[t];
                s1 += A[o * 50 + t + 1] * C[t + 1];
            }
            Dd[o] = b_d2[o] + s0 + s1;
        }
        __syncthreads();
        for (int o = tid; o < 150; o += NT) {
            int r = o / 3, c = o % 3;
            float s0 = 0.f, s1 = 0.f;
#pragma unroll
            for (int t = 0; t < 150; t += 2) {
                s0 += A[7500 + r * 150 + t]     * B[t * 3 + c];
                s1 += A[7500 + r * 150 + t + 1] * B[(t + 1) * 3 + c];
            }
            Es[o] = s0 + s1;
        }
        for (int o = tid; o < 50; o += NT) {
            float s0 = 0.f, s1 = 0.f;
#pragma unroll
            for (int t = 0; t < 150; t += 2) {
                s0 += A[7500 + o * 150 + t]     * Dd[t];
                s1 += A[7500 + o * 150 + t + 1] * Dd[t + 1];
            }
            C[o] = b_d3[o] + s0 + s1;
        }
        __syncthreads();
        for (int o = tid; o < 150; o += NT) {
            int r = o / 3, c = o % 3;
            float s0 = 0.f, s1 = 0.f;
#pragma unroll
            for (int t = 0; t < 50; t += 2) {
                s0 += A[15000 + r * 50 + t]     * Es[t * 3 + c];
                s1 += A[15000 + r * 50 + t + 1] * Es[(t + 1) * 3 + c];
            }
            S[o] = s0 + s1;
        }
        for (int o = tid; o < 64; o += NT) {
            float v = 0.0f;
            if (o < 50) {
                float s0 = 0.f, s1 = 0.f;
#pragma unroll
                for (int t = 0; t < 50; t += 2) {
                    s0 += A[15000 + o * 50 + t]     * C[t];
                    s1 += A[15000 + o * 50 + t + 1] * C[t + 1];
                }
                v = b_h3[o] + s0 + s1;
            }
            ws[BD + o] = v;
        }
        __syncthreads();
        for (int i = tid; i < 4096; i += NT) {
            int j = i & 7, lane = (i >> 3) & 63, frag = i >> 9, pl = frag & 1, nt = frag >> 1;
            int n = nt * 16 + (lane & 15), k = (lane >> 4) * 8 + j;
            float v = (n < 50 && k < 3) ? S[n * 3 + k] : 0.0f;
            float hi = h2f_bits(f2h_bits(v));
            wimg[W_D + i] = (short)(pl ? f2h_bits(v - hi) : f2h_bits(v));
        }
    }
}

// ---------------------------------------------------------------------------
// main kernel helpers
// ---------------------------------------------------------------------------
// B-fragment straight from global (L2-hot, 16B/lane coalesced)
__device__ __forceinline__ half8 gfragH(const short* __restrict__ wl, int off) {
    return *(const half8*)(wl + off);
}

__device__ __forceinline__ half8 readAf(const unsigned int* acts, int row0, int pane, int lane) {
    int m = lane & 15, qd = lane >> 4;
    const unsigned int* p = &acts[(row0 + m) * AST + pane + (qd & 1) * 8];
    uint4_ a = *(const uint4_*)p;
    uint4_ b = *(const uint4_*)(p + 4);
    unsigned sel = (qd >> 1) ? 0x07060302u : 0x05040100u;
    union { unsigned u[4]; half8 v; } r;
    r.u[0] = __builtin_amdgcn_perm(a.y, a.x, sel);
    r.u[1] = __builtin_amdgcn_perm(a.w, a.z, sel);
    r.u[2] = __builtin_amdgcn_perm(b.y, b.x, sel);
    r.u[3] = __builtin_amdgcn_perm(b.w, b.z, sel);
    return r.v;
}

__device__ __forceinline__ void writeCf(unsigned int* acts, int row0q, int dcol,
                                        f32x4 va, f32x4 vb) {
    unsigned int* p = &acts[row0q * AST + dcol];
#pragma unroll
    for (int r = 0; r < 4; r++) p[r * AST] = packh2(va[r], vb[r]);
}

__device__ __forceinline__ void t2s(f32x4& a0, f32x4& a1, half8 x0, half8 x1, half8 b) {
    a0 = MFMAH(x0, b, a0);
    a1 = MFMAH(x1, b, a1);
}
__device__ __forceinline__ void t2p(f32x4& a0, f32x4& a1, half8 x0, half8 x1,
                                    half8 bh, half8 bl) {
    a0 = MFMAH(x0, bh, a0);
    a1 = MFMAH(x1, bh, a1);
    a0 = MFMAH(x0, bl, a0);
    a1 = MFMAH(x1, bl, a1);
}

// ---------------------------------------------------------------------------
// main fused kernel: barrier-free after prologue
// ---------------------------------------------------------------------------
__global__ __launch_bounds__(256, 4) void fused_mfma(
    const float* __restrict__ xin,
    const float* __restrict__ ws,
    float* __restrict__ out)
{
    __shared__ unsigned int acts[MTILE * AST];   // 26624 B
    __shared__ float sbias[BIAS_TOT];            // 2048 B

    const int tid = threadIdx.x;
    const int wv = tid >> 6;
    const int lane = tid & 63;
    const int qd = lane >> 4;
    const int mcol = lane & 15;
    const int rw = wv * 32;
    // per-lane base into the weight image: lane's 8 shorts of every frag
    const short* __restrict__ wl = (const short*)(ws + BIAS_TOT) + lane * 8;
    const f32x4 zero4 = {0.f, 0.f, 0.f, 0.f};

    const int g0 = blockIdx.x * MTILE;
    const int bb = g0 / HW;
    const int p0 = g0 - bb * HW;
    const int yb = p0 / IW;
    const int xblk = p0 - yb * IW;
    const float* __restrict__ xb = xin + bb * 3 * HW;

    float* patch = (float*)acts;
    int*   stab  = (int*)(acts + 1984);

    for (int i = tid; i < BIAS_TOT; i += 256) {
        float v = ws[i];
        unsigned d = (unsigned)(i - BEF);
        if (d < 3u) v = ws[STG_BE + d] + ws[STG_BF + d];
        sbias[i] = v;
    }
    for (int e = tid; e < 1980; e += 256) {
        int cr = e / 132;
        int i  = e - cr * 132;
        int c  = cr / 5, r = cr - c * 5;
        int ty = yb + r - 2; ty = ty < 0 ? -ty : ty; ty = (766 - ty) < ty ? 766 - ty : ty;
        int tx = xblk - 2 + i; tx = tx < 0 ? -tx : tx; tx = (766 - tx) < tx ? 766 - tx : tx;
        patch[cr * 132 + i] = xb[c * HW + ty * IW + tx];
    }
    if (tid < 96) {
        int v = 0;
        if (tid < 75) {
            int c = tid / 25, rem = tid - 25 * c;
            int rr = rem / 5, ss = rem - 5 * rr;
            v = (c * 5 + rr) * 132 + ss;
        }
        stab[tid] = v;
    }
    __syncthreads();

    // build sw fragments from LDS patch
    half8 swf[3][2];
    {
        int st[3][8];
#pragma unroll
        for (int kt = 0; kt < 3; kt++)
#pragma unroll
            for (int j = 0; j < 8; j++)
                st[kt][j] = stab[kt * 32 + qd * 8 + j];
#pragma unroll
        for (int mt = 0; mt < 2; mt++) {
            const int xloc = wv * 32 + mt * 16 + mcol;
#pragma unroll
            for (int kt = 0; kt < 3; kt++) {
                union { unsigned u32[4]; half8 v; } u;
#pragma unroll
                for (int jj = 0; jj < 8; jj += 2) {
                    float v0 = patch[st[kt][jj]     + xloc];
                    float v1 = patch[st[kt][jj + 1] + xloc];
                    if (kt == 2) {
                        int qq0 = 64 + qd * 8 + jj;
                        v0 = (qq0     < 75) ? v0 : 0.0f;
                        v1 = (qq0 + 1 < 75) ? v1 : 0.0f;
                    }
                    u.u32[jj >> 1] = packh2(v0, v1);
                }
                swf[kt][mt] = u.v;
            }
        }
    }
    __syncthreads();     // protect patch before acts writes; last barrier.

    // ===== layer A =====
    f32x4 accA[4][2];
#pragma unroll
    for (int nt = 0; nt < 4; nt++) { accA[nt][0] = zero4; accA[nt][1] = zero4; }
#pragma unroll
    for (int nt = 0; nt < 4; nt++)
        t2s(accA[nt][0], accA[nt][1], swf[0][0], swf[0][1], gfragH(wl, W_A0 + nt * 512));
#pragma unroll
    for (int nt = 0; nt < 4; nt++)
        t2s(accA[nt][0], accA[nt][1], swf[1][0], swf[1][1], gfragH(wl, W_A1 + nt * 512));
#pragma unroll
    for (int nt = 0; nt < 4; nt++)
        t2s(accA[nt][0], accA[nt][1], swf[2][0], swf[2][1], gfragH(wl, W_A2 + nt * 512));

    f32x4 x1C[4][2];
    half8 x1f[2][2];
#pragma unroll
    for (int nt = 0; nt < 4; nt++) {
        float bv = sbias[BA + nt * 16 + mcol];
#pragma unroll
        for (int mt = 0; mt < 2; mt++) {
            f32x4 v = accA[nt][mt];
            v[0] += bv; v[1] += bv; v[2] += bv; v[3] += bv;
            x1C[nt][mt] = v;
        }
    }
#pragma unroll
    for (int mt = 0; mt < 2; mt++) {
        writeCf(acts, rw + mt * 16 + qd * 4, mcol,      x1C[0][mt], x1C[1][mt]);
        writeCf(acts, rw + mt * 16 + qd * 4, 16 + mcol, x1C[2][mt], x1C[3][mt]);
    }
#pragma unroll
    for (int kt = 0; kt < 2; kt++)
#pragma unroll
        for (int mt = 0; mt < 2; mt++)
            x1f[kt][mt] = readAf(acts, rw + mt * 16, kt * 16, lane);

    // ===== h1 =====
    f32x4 acc1[5][2];
#pragma unroll
    for (int nt = 0; nt < 5; nt++) { acc1[nt][0] = zero4; acc1[nt][1] = zero4; }
#pragma unroll
    for (int nt = 0; nt < 5; nt++)
        t2s(acc1[nt][0], acc1[nt][1], x1f[0][0], x1f[0][1], gfragH(wl, W_H1A + nt * 512));
#pragma unroll
    for (int nt = 0; nt < 5; nt++)
        t2s(acc1[nt][0], acc1[nt][1], x1f[1][0], x1f[1][1], gfragH(wl, W_H1B + nt * 512));
#pragma unroll
    for (int mt = 0; mt < 2; mt++) {
        f32x4 w5[5];
#pragma unroll
        for (int nt = 0; nt < 5; nt++) {
            float bv = sbias[B1 + nt * 16 + mcol];
            f32x4 v = acc1[nt][mt];
            v[0] = lrelu(v[0] + bv); v[1] = lrelu(v[1] + bv);
            v[2] = lrelu(v[2] + bv); v[3] = lrelu(v[3] + bv);
            w5[nt] = v;
        }
        writeCf(acts, rw + mt * 16 + qd * 4, mcol,      w5[0], w5[1]);
        writeCf(acts, rw + mt * 16 + qd * 4, 16 + mcol, w5[2], w5[3]);
        writeCf(acts, rw + mt * 16 + qd * 4, 32 + mcol, w5[4], zero4);
    }

    // ===== h2 =====
    f32x4 acc2[5][2];
#pragma unroll
    for (int nt = 0; nt < 5; nt++) { acc2[nt][0] = zero4; acc2[nt][1] = zero4; }
    {
        half8 a0 = readAf(acts, rw, 0, lane), a1 = readAf(acts, rw + 16, 0, lane);
#pragma unroll
        for (int nt = 0; nt < 5; nt++)
            t2s(acc2[nt][0], acc2[nt][1], a0, a1, gfragH(wl, W_H2A + nt * 512));
    }
    {
        half8 a0 = readAf(acts, rw, 16, lane), a1 = readAf(acts, rw + 16, 16, lane);
#pragma unroll
        for (int nt = 0; nt < 5; nt++)
            t2s(acc2[nt][0], acc2[nt][1], a0, a1, gfragH(wl, W_H2B + nt * 512));
    }
    {
        half8 a0 = readAf(acts, rw, 32, lane), a1 = readAf(acts, rw + 16, 32, lane);
#pragma unroll
        for (int nt = 0; nt < 5; nt++)
            t2s(acc2[nt][0], acc2[nt][1], a0, a1, gfragH(wl, W_H2C + nt * 512));
    }
#pragma unroll
    for (int mt = 0; mt < 2; mt++) {
        f32x4 w5[5];
#pragma unroll
        for (int nt = 0; nt < 5; nt++) {
            float bv = sbias[B2 + nt * 16 + mcol];
            f32x4 v = acc2[nt][mt];
            v[0] = tanh_fast(v[0] + bv); v[1] = tanh_fast(v[1] + bv);
            v[2] = tanh_fast(v[2] + bv); v[3] = tanh_fast(v[3] + bv);
            w5[nt] = v;
        }
        writeCf(acts, rw + mt * 16 + qd * 4, mcol,      w5[0], w5[1]);
        writeCf(acts, rw + mt * 16 + qd * 4, 16 + mcol, w5[2], w5[3]);
        writeCf(acts, rw + mt * 16 + qd * 4, 32 + mcol, w5[4], zero4);
    }

    // ===== EF =====
    f32x4 accEF[2];
    {
        float bv = sbias[BEF + mcol];
        accEF[0] = (f32x4){bv, bv, bv, bv};
        accEF[1] = accEF[0];
    }
#pragma unroll
    for (int kt = 0; kt < 3; kt++) {
        half8 a0 = readAf(acts, rw, kt * 16, lane), a1 = readAf(acts, rw + 16, kt * 16, lane);
        t2p(accEF[0], accEF[1], a0, a1,
            gfragH(wl, W_EF + kt * 1024), gfragH(wl, W_EF + kt * 1024 + 512));
    }
#pragma unroll
    for (int kt = 0; kt < 2; kt++)
        t2p(accEF[0], accEF[1], x1f[kt][0], x1f[kt][1],
            gfragH(wl, W_EF + 3072 + kt * 1024), gfragH(wl, W_EF + 3072 + kt * 1024 + 512));
    half8 x4f[2];
#pragma unroll
    for (int mt = 0; mt < 2; mt++) {
        f32x4 v = accEF[mt];
        v[0] = lrelu(v[0]); v[1] = lrelu(v[1]); v[2] = lrelu(v[2]); v[3] = lrelu(v[3]);
        writeCf(acts, rw + mt * 16 + qd * 4, 32 + mcol, v, zero4);
    }
    x4f[0] = readAf(acts, rw, 32, lane);
    x4f[1] = readAf(acts, rw + 16, 32, lane);

    // ===== D =====
    f32x4 accD[4][2];
#pragma unroll
    for (int nt = 0; nt < 4; nt++) {
        float bv = sbias[BD + nt * 16 + mcol];
        accD[nt][0] = (f32x4){bv, bv, bv, bv};
        accD[nt][1] = accD[nt][0];
    }
#pragma unroll
    for (int nt = 0; nt < 4; nt++)
        t2p(accD[nt][0], accD[nt][1], x4f[0], x4f[1],
            gfragH(wl, W_D + nt * 1024), gfragH(wl, W_D + nt * 1024 + 512));
#pragma unroll
    for (int mt = 0; mt < 2; mt++) {
        writeCf(acts, rw + mt * 16 + qd * 4, mcol,      accD[0][mt], accD[1][mt]);
        writeCf(acts, rw + mt * 16 + qd * 4, 16 + mcol, accD[2][mt], accD[3][mt]);
    }
    half8 xdf[2][2];
#pragma unroll
    for (int kt = 0; kt < 2; kt++)
#pragma unroll
        for (int mt = 0; mt < 2; mt++)
            xdf[kt][mt] = readAf(acts, rw + mt * 16, kt * 16, lane);

    f32x4 x6a[4][2];
#pragma unroll
    for (int nt = 0; nt < 4; nt++) {
        float bv = sbias[B5 + nt * 16 + mcol];
#pragma unroll
        for (int mt = 0; mt < 2; mt++) {
            f32x4 v;
            v[0] = bv - x1C[nt][mt][0]; v[1] = bv - x1C[nt][mt][1];
            v[2] = bv - x1C[nt][mt][2]; v[3] = bv - x1C[nt][mt][3];
            x6a[nt][mt] = v;
        }
    }

    // ===== h4/h5 chunks =====
#pragma unroll 1
    for (int c = 0; c < 4; c++) {
        f32x4 acc5[2][2];
#pragma unroll
        for (int nt2 = 0; nt2 < 2; nt2++) {
            float bv = sbias[B4 + c * 32 + nt2 * 16 + mcol];
            acc5[nt2][0] = (f32x4){bv, bv, bv, bv};
            acc5[nt2][1] = acc5[nt2][0];
        }
#pragma unroll
        for (int nt2 = 0; nt2 < 2; nt2++)
#pragma unroll
            for (int kt = 0; kt < 2; kt++)
                t2s(acc5[nt2][0], acc5[nt2][1], xdf[kt][0], xdf[kt][1],
                    gfragH(wl, W_H4C0 + c * 4096 + (nt2 * 2 + kt) * 512));
#pragma unroll
        for (int mt = 0; mt < 2; mt++) {
            f32x4 v0 = acc5[0][mt], v1 = acc5[1][mt];
            v0[0] = tanh_fast(v0[0]); v0[1] = tanh_fast(v0[1]);
            v0[2] = tanh_fast(v0[2]); v0[3] = tanh_fast(v0[3]);
            v1[0] = tanh_fast(v1[0]); v1[1] = tanh_fast(v1[1]);
            v1[2] = tanh_fast(v1[2]); v1[3] = tanh_fast(v1[3]);
            writeCf(acts, rw + mt * 16 + qd * 4, 32 + mcol, v0, v1);
        }
        half8 chf[2];
        chf[0] = readAf(acts, rw, 32, lane);
        chf[1] = readAf(acts, rw + 16, 32, lane);
#pragma unroll
        for (int nt = 0; nt < 4; nt++)
            t2s(x6a[nt][0], x6a[nt][1], chf[0], chf[1],
                gfragH(wl, W_H5C0 + c * 4096 + nt * 512));
    }

    // ===== out =====
#pragma unroll
    for (int mt = 0; mt < 2; mt++) {
        writeCf(acts, rw + mt * 16 + qd * 4, mcol,      x6a[0][mt], x6a[1][mt]);
        writeCf(acts, rw + mt * 16 + qd * 4, 16 + mcol, x6a[2][mt], x6a[3][mt]);
    }
    f32x4 accO[2];
    {
        float bv = sbias[BOUT + mcol];
        accO[0] = (f32x4){bv, bv, bv, bv};
        accO[1] = accO[0];
    }
#pragma unroll
    for (int kt = 0; kt < 2; kt++) {
        half8 a0 = readAf(acts, rw, kt * 16, lane), a1 = readAf(acts, rw + 16, kt * 16, lane);
        t2s(accO[0], accO[1], a0, a1, gfragH(wl, W_OUT + kt * 512));
    }
    if (mcol < 3) {
#pragma unroll
        for (int mt = 0; mt < 2; mt++) {
#pragma unroll
            for (int r = 0; r < 4; r++) {
                int p = p0 + wv * 32 + mt * 16 + qd * 4 + r;
                out[(bb * 3 + mcol) * HW + p] = lrelu(accO[mt][r]);
            }
        }
    }
}

extern "C" void kernel_launch(void* const* d_in, const int* in_sizes, int n_in,
                              void* d_out, int out_size, void* d_ws, size_t ws_size,
                              hipStream_t stream)
{
    const float* xin = (const float*)d_in[0];
    float* ws = (float*)d_ws;

    setup_all<<<75, 256, 0, stream>>>(
        (const float*)d_in[1],  (const float*)d_in[2],   // input
        (const float*)d_in[3],  (const float*)d_in[4],   // h1
        (const float*)d_in[5],  (const float*)d_in[6],   // h2
        (const float*)d_in[7],  (const float*)d_in[8],   // h3
        (const float*)d_in[9],  (const float*)d_in[10],  // h4
        (const float*)d_in[11], (const float*)d_in[12],  // h5
        (const float*)d_in[13], (const float*)d_in[14],  // out
        (const float*)d_in[15], (const float*)d_in[16],  // e1
        (const float*)d_in[17], (const float*)d_in[18],  // e2
        (const float*)d_in[19], (const float*)d_in[20],  // e3
        (const float*)d_in[21], (const float*)d_in[22],  // f1
        (const float*)d_in[23], (const float*)d_in[24],  // f2
        (const float*)d_in[25], (const float*)d_in[26],  // f3
        (const float*)d_in[27], (const float*)d_in[28],  // d1
        (const float*)d_in[29], (const float*)d_in[30],  // d2
        (const float*)d_in[31], (const float*)d_in[32],  // d3
        ws);

    fused_mfma<<<NBLK, 256, 0, stream>>>(xin, ws, (float*)d_out);
}

// Round 12
// 231.317 us; speedup vs baseline: 10.3488x; 1.0181x over previous
//
#include <hip/hip_runtime.h>

// ---------------------------------------------------------------------------
// Round 12 = Round 11 with __launch_bounds__(256, 3) on fused_mfma.
// R11's (256,4) capped VGPR at 64 and introduced 3.3 MB of scratch spill
// (WRITE_SIZE 6912 -> 10200 KB). VGPR>64 quantizes to the same 4 waves/SIMD
// residency (LDS 28.7KB allows 4 blocks/CU), so relaxing the bound removes
// spills at no occupancy cost. Everything else identical to R11.
// ---------------------------------------------------------------------------

#define IW 384
#define HW (384 * 384)           // 147456
#define NPIX (4 * HW)            // 589824
#define MTILE 128
#define NBLK (NPIX / MTILE)      // 4608
#define AST 52                   // acts row stride in dwords (48 data + 4 pad)

typedef _Float16 half8 __attribute__((ext_vector_type(8)));
typedef __fp16 fp16x2 __attribute__((ext_vector_type(2)));
typedef __attribute__((ext_vector_type(4))) float f32x4;
typedef __attribute__((ext_vector_type(4))) unsigned int uint4_;

#define MFMAH(A, B, C) __builtin_amdgcn_mfma_f32_16x16x32_f16((A), (B), (C), 0, 0, 0)

// bias table offsets (dwords in ws)
#define BA   0
#define B1   64
#define B2   144
#define BEF  224
#define BD   240
#define B4   304
#define B5   432
#define BOUT 496
#define BIAS_TOT 512

// weight image segment offsets (shorts, after bias table). frag = 512 shorts.
#define W_A0   0
#define W_A1   2048
#define W_A2   4096
#define W_H1A  6144
#define W_H1B  8704
#define W_H2A  11264
#define W_H2B  13824
#define W_H2C  16384
#define W_EF   18944    // E: 6 frags hi/lo (kt-major), F: 4 frags at +3072
#define W_D    24064    // 8 frags hi/lo (nt-major)
#define W_H4C0 28160    // chunk c: h4 at 28160+c*4096
#define W_H5C0 30208    //          h5 at 30208+c*4096
#define W_OUT  44544
#define W_TOT  45568

// be / bf slots (dword offsets, after images: 512 + 45568/2 = 23296)
#define STG_BE  23296   // 3
#define STG_BF  23300   // 3

__device__ __forceinline__ float lrelu(float v) { return v >= 0.0f ? v : 0.01f * v; }

__device__ __forceinline__ float tanh_fast(float v) {
    float e = __expf(2.0f * v);
    return 1.0f - 2.0f * __builtin_amdgcn_rcpf(e + 1.0f);
}

__device__ __forceinline__ unsigned short f2h_bits(float v) {
    union { _Float16 h; unsigned short s; } u; u.h = (_Float16)v; return u.s;
}
__device__ __forceinline__ float h2f_bits(unsigned short s) {
    union { _Float16 h; unsigned short s; } u; u.s = s; return (float)u.h;
}
__device__ __forceinline__ unsigned packh2(float a, float b) {
    union { fp16x2 h; unsigned u; } u;
    u.h = __builtin_amdgcn_cvt_pkrtz(a, b);
    return u.u;
}

// deep-pipelined global->LDS staging: float4 x unroll-4
__device__ __forceinline__ void stage(float* dst, const float* __restrict__ src,
                                      int n, int tid) {
    int n4 = n >> 2;
    float4* d = (float4*)dst;
    const float4* s = (const float4*)src;
#pragma unroll 4
    for (int i = tid; i < n4; i += 256) d[i] = s[i];
    for (int i = (n4 << 2) + tid; i < n; i += 256) dst[i] = src[i];
}

// ---------------------------------------------------------------------------
// setup_all: 75 independent blocks x 256 threads. (identical to R10/R11)
// ---------------------------------------------------------------------------
__global__ __launch_bounds__(256) void setup_all(
    const float* __restrict__ W_input, const float* __restrict__ b_input,
    const float* __restrict__ W_h1,  const float* __restrict__ b_h1,
    const float* __restrict__ W_h2,  const float* __restrict__ b_h2,
    const float* __restrict__ W_h3,  const float* __restrict__ b_h3,
    const float* __restrict__ W_h4,  const float* __restrict__ b_h4,
    const float* __restrict__ W_h5,  const float* __restrict__ b_h5,
    const float* __restrict__ W_out, const float* __restrict__ b_out,
    const float* __restrict__ W_e1,  const float* __restrict__ b_e1,
    const float* __restrict__ W_e2,  const float* __restrict__ b_e2,
    const float* __restrict__ W_e3,  const float* __restrict__ b_e3,
    const float* __restrict__ W_f1,  const float* __restrict__ b_f1,
    const float* __restrict__ W_f2,  const float* __restrict__ b_f2,
    const float* __restrict__ W_f3,  const float* __restrict__ b_f3,
    const float* __restrict__ W_d1,  const float* __restrict__ b_d1,
    const float* __restrict__ W_d2,  const float* __restrict__ b_d2,
    const float* __restrict__ W_d3,  const float* __restrict__ b_d3,
    float* __restrict__ ws)
{
    const int tid = threadIdx.x;
    const int NT = 256;
    short* wimg = (short*)(ws + BIAS_TOT);

    if (blockIdx.x < 71) {
        const int soff[17] = {W_A0,W_A1,W_A2, W_H1A,W_H1B, W_H2A,W_H2B,W_H2C,
                              W_H4C0,W_H5C0, W_H4C0+4096,W_H5C0+4096,
                              W_H4C0+8192,W_H5C0+8192, W_H4C0+12288,W_H5C0+12288,
                              W_OUT};
        const int slay[17] = {0,0,0, 1,1, 2,2,2, 6,7, 6,7, 6,7, 6,7, 8};
        const int sNT[17]  = {4,4,4, 5,5, 5,5,5, 2,4, 2,4, 2,4, 2,4, 1};
        const int sKTS[17] = {1,1,1, 1,1, 1,1,1, 2,1, 2,1, 2,1, 2,1, 2};
        const int snb[17]  = {0,0,0, 0,0, 0,0,0, 0,0, 32,0, 64,0, 96,0, 0};
        const int skb[17]  = {0,32,64, 0,32, 0,32,64, 0,0, 0,32, 0,64, 0,96, 0};

        int seg = 0, local = blockIdx.x;
        while (seg < 16 && local >= sNT[seg] * sKTS[seg]) { local -= sNT[seg] * sKTS[seg]; seg++; }
        const int kts = sKTS[seg];
        const int kt = local % kts, nt = local / kts;
        const int lay = slay[seg];
        short* dst = wimg + soff[seg] + local * 512;

#pragma unroll
        for (int t = 0; t < 2; t++) {
            int idx = tid + t * 256;
            int j = idx & 7, lane = idx >> 3;
            int n = snb[seg] + nt * 16 + (lane & 15);
            int k = skb[seg] + kt * 32 + (lane >> 4) * 8 + j;
            float v = 0.0f;
            switch (lay) {
                case 0: if (n < 50  && k < 75)  v = W_input[n * 75 + k]; break;
                case 1: if (n < 75  && k < 50)  v = W_h1[n * 50 + k]; break;
                case 2: if (n < 75  && k < 75)  v = W_h2[n * 75 + k]; break;
                case 6: if (n < 125 && k < 50)  v = W_h4[n * 50 + k]; break;
                case 7: if (n < 50  && k < 125) v = W_h5[n * 125 + k]; break;
                case 8: if (n < 3   && k < 50)  v = W_out[n * 50 + k]; break;
            }
            dst[idx] = (short)f2h_bits(v);
        }
        return;
    }

    if (blockIdx.x == 74) {
        for (int i = tid; i < BIAS_TOT; i += NT) {
            if (i >= BD && i < B4) continue;
            float v = 0.0f;
            if (i < B1)        { int o = i - BA;   if (o < 50)  v = b_input[o]; }
            else if (i < B2)   { int o = i - B1;   if (o < 75)  v = b_h1[o]; }
            else if (i < BEF)  { int o = i - B2;   if (o < 75)  v = b_h2[o]; }
            else if (i < BD)   { v = 0.0f; }
            else if (i < B5)   { int o = i - B4;   if (o < 125) v = b_h4[o]; }
            else if (i < BOUT) { int o = i - B5;   if (o < 50)  v = b_h5[o]; }
            else               { int o = i - BOUT; if (o < 3)   v = b_out[o]; }
            ws[i] = v;
        }
        return;
    }

    __shared__ __align__(16) float A[17500];
    __shared__ float B[675];
    __shared__ float C[256];
    __shared__ float Dd[256];
    __shared__ float Es[256];
    __shared__ float S[232];

    if (blockIdx.x == 71) {
        // ================= E chain =================
        stage(A, W_e2, 16875, tid);
        for (int i = tid; i < 225; i += NT) { Es[i] = W_e3[i]; C[i] = b_e1[i]; }
        __syncthreads();
        for (int o = tid; o < 675; o += NT) {
            int r = o / 225, c = o % 225;
            float s0 = 0.f, s1 = 0.f, s2 = 0.f;
#pragma unroll
            for (int t = 0; t < 75; t += 3) {
                s0 += Es[r * 75 + t]     * A[t * 225 + c];
                s1 += Es[r * 75 + t + 1] * A[(t + 1) * 225 + c];
                s2 += Es[r * 75 + t + 2] * A[(t + 2) * 225 + c];
            }
            B[o] = s0 + s1 + s2;
        }
        for (int o = tid; o < 75; o += NT) {
            float s0 = 0.f, s1 = 0.f, s2 = 0.f;
#pragma unroll
            for (int t = 0; t < 225; t += 3) {
                s0 += A[o * 225 + t]     * C[t];
                s1 += A[o * 225 + t + 1] * C[t + 1];
                s2 += A[o * 225 + t + 2] * C[t + 2];
            }
            Dd[o] = b_e2[o] + s0 + s1 + s2;
        }
        __syncthreads();
        stage(A, W_e1, 16875, tid);
        __syncthreads();
        for (int o = tid; o < 225; o += NT) {
            int r = o / 75, c = o % 75;
            float s0 = 0.f, s1 = 0.f, s2 = 0.f;
#pragma unroll
            for (int t = 0; t < 225; t += 3) {
                s0 += B[r * 225 + t]     * A[t * 75 + c];
                s1 += B[r * 225 + t + 1] * A[(t + 1) * 75 + c];
                s2 += B[r * 225 + t + 2] * A[(t + 2) * 75 + c];
            }
            S[o] = s0 + s1 + s2;
        }
        for (int o = tid; o < 3; o += NT) {
            float s = b_e3[o];
            for (int t = 0; t < 75; t++) s += Es[o * 75 + t] * Dd[t];
            ws[STG_BE + o] = s;
        }
        __syncthreads();
        for (int i = tid; i < 3072; i += NT) {
            int j = i & 7, lane = (i >> 3) & 63, frag = i >> 9, pl = frag & 1, kt = frag >> 1;
            int n = lane & 15, k = kt * 32 + (lane >> 4) * 8 + j;
            float v = (n < 3 && k < 75) ? S[n * 75 + k] : 0.0f;
            float hi = h2f_bits(f2h_bits(v));
            wimg[W_EF + i] = (short)(pl ? f2h_bits(v - hi) : f2h_bits(v));
        }
    } else if (blockIdx.x == 72) {
        // ================= F chain =================
        stage(A,        W_f2, 7500, tid);
        stage(A + 7500, W_f1, 7500, tid);
        for (int i = tid; i < 150; i += NT) { Es[i] = W_f3[i]; C[i] = b_f1[i]; }
        __syncthreads();
        for (int o = tid; o < 450; o += NT) {
            int r = o / 150, c = o % 150;
            float s0 = 0.f, s1 = 0.f;
#pragma unroll
            for (int t = 0; t < 50; t += 2) {
                s0 += Es[r * 50 + t]     * A[t * 150 + c];
                s1 += Es[r * 50 + t + 1] * A[(t + 1) * 150 + c];
            }
            B[o] = s0 + s1;
        }
        for (int o = tid; o < 50; o += NT) {
            float s0 = 0.f, s1 = 0.f;
#pragma unroll
            for (int t = 0; t < 150; t += 2) {
                s0 += A[o * 150 + t]     * C[t];
                s1 += A[o * 150 + t + 1] * C[t + 1];
            }
            Dd[o] = b_f2[o] + s0 + s1;
        }
        __syncthreads();
        for (int o = tid; o < 150; o += NT) {
            int r = o / 50, c = o % 50;
            float s0 = 0.f, s1 = 0.f;
#pragma unroll
            for (int t = 0; t < 150; t += 2) {
                s0 += B[r * 150 + t]     * A[7500 + t * 50 + c];
                s1 += B[r * 150 + t + 1] * A[7500 + (t + 1) * 50 + c];
            }
            S[o] = s0 + s1;
        }
        for (int o = tid; o < 3; o += NT) {
            float s = b_f3[o];
            for (int t = 0; t < 50; t++) s += Es[o * 50 + t] * Dd[t];
            ws[STG_BF + o] = s;
        }
        __syncthreads();
        for (int i = tid; i < 2048; i += NT) {
            int j = i & 7, lane = (i >> 3) & 63, frag = i >> 9, pl = frag & 1, kt = frag >> 1;
            int n = lane & 15, k = kt * 32 + (lane >> 4) * 8 + j;
            float v = (n < 3 && k < 50) ? S[n * 50 + k] : 0.0f;
            float hi = h2f_bits(f2h_bits(v));
            wimg[W_EF + 3072 + i] = (short)(pl ? f2h_bits(v - hi) : f2h_bits(v));
        }
    } else {
        // ================= D chain =================
        stage(A,         W_d2, 7500, tid);
        stage(A + 7500,  W_d3, 7500, tid);
        stage(A + 15000, W_h3, 2500, tid);
        for (int i = tid; i < 150; i += NT) Es[i] = W_d1[i];
        for (int i = tid; i < 50;  i += NT) C[i] = b_d1[i];
        __syncthreads();
        for (int o = tid; o < 450; o += NT) {
            int r = o / 3, c = o % 3;
            float s0 = 0.f, s1 = 0.f;
#pragma unroll
            for (int t = 0; t < 50; t += 2) {
                s0 += A[r * 50 + t]     * Es[t * 3 + c];
                s1 += A[r * 50 + t + 1] * Es[(t + 1) * 3 + c];
            }
            B[o] = s0 + s1;
        }
        for (int o = tid; o < 150; o += NT) {
            float s0 = 0.f, s1 = 0.f;
#pragma unroll
            for (int t = 0; t < 50; t += 2) {
                s0 += A[o * 50 + t]     * C[t];
                s1 += A[o * 50 + t + 1] * C[t + 1];
            }
            Dd[o] = b_d2[o] + s0 + s1;
        }
        __syncthreads();
        for (int o = tid; o < 150; o += NT) {
            int r = o / 3, c = o % 3;
            float s0 = 0.f, s1 = 0.f;
#pragma unroll
            for (int t = 0; t < 150; t += 2) {
                s0 += A[7500 + r * 150 + t]     * B[t * 3 + c];
                s1 += A[7500 + r * 150 + t + 1] * B[(t + 1) * 3 + c];
            }
            Es[o] = s0 + s1;
        }
        for (int o = tid; o < 50; o += NT) {
            float s0 = 0.f, s1 = 0.f;
#pragma unroll
            for (int t = 0; t < 150; t += 2) {
                s0 += A[7500 + o * 150 + t]     * Dd[t];
                s1 += A[7500 + o * 150 + t + 1] * Dd[t + 1];
            }
            C[o] = b_d3[o] + s0 + s1;
        }
        __syncthreads();
        for (int o = tid; o < 150; o += NT) {
            int r = o / 3, c = o % 3;
            float s0 = 0.f, s1 = 0.f;
#pragma unroll
            for (int t = 0; t < 50; t += 2) {
                s0 += A[15000 + r * 50 + t]     * Es[t * 3 + c];
                s1 += A[15000 + r * 50 + t + 1] * Es[(t + 1) * 3 + c];
            }
            S[o] = s0 + s1;
        }
        for (int o = tid; o < 64; o += NT) {
            float v = 0.0f;
            if (o < 50) {
                float s0 = 0.f, s1 = 0.f;
#pragma unroll
                for (int t = 0; t < 50; t += 2) {
                    s0 += A[15000 + o * 50 + t]     * C[t];
                    s1 += A[15000 + o * 50 + t + 1] * C[t + 1];
                }
                v = b_h3[o] + s0 + s1;
            }
            ws[BD + o] = v;
        }
        __syncthreads();
        for (int i = tid; i < 4096; i += NT) {
            int j = i & 7, lane = (i >> 3) & 63, frag = i >> 9, pl = frag & 1, nt = frag >> 1;
            int n = nt * 16 + (lane & 15), k = (lane >> 4) * 8 + j;
            float v = (n < 50 && k < 3) ? S[n * 3 + k] : 0.0f;
            float hi = h2f_bits(f2h_bits(v));
            wimg[W_D + i] = (short)(pl ? f2h_bits(v - hi) : f2h_bits(v));
        }
    }
}

// ---------------------------------------------------------------------------
// main kernel helpers
// ---------------------------------------------------------------------------
// B-fragment straight from global (L2-hot, 16B/lane coalesced)
__device__ __forceinline__ half8 gfragH(const short* __restrict__ wl, int off) {
    return *(const half8*)(wl + off);
}

__device__ __forceinline__ half8 readAf(const unsigned int* acts, int row0, int pane, int lane) {
    int m = lane & 15, qd = lane >> 4;
    const unsigned int* p = &acts[(row0 + m) * AST + pane + (qd & 1) * 8];
    uint4_ a = *(const uint4_*)p;
    uint4_ b = *(const uint4_*)(p + 4);
    unsigned sel = (qd >> 1) ? 0x07060302u : 0x05040100u;
    union { unsigned u[4]; half8 v; } r;
    r.u[0] = __builtin_amdgcn_perm(a.y, a.x, sel);
    r.u[1] = __builtin_amdgcn_perm(a.w, a.z, sel);
    r.u[2] = __builtin_amdgcn_perm(b.y, b.x, sel);
    r.u[3] = __builtin_amdgcn_perm(b.w, b.z, sel);
    return r.v;
}

__device__ __forceinline__ void writeCf(unsigned int* acts, int row0q, int dcol,
                                        f32x4 va, f32x4 vb) {
    unsigned int* p = &acts[row0q * AST + dcol];
#pragma unroll
    for (int r = 0; r < 4; r++) p[r * AST] = packh2(va[r], vb[r]);
}

__device__ __forceinline__ void t2s(f32x4& a0, f32x4& a1, half8 x0, half8 x1, half8 b) {
    a0 = MFMAH(x0, b, a0);
    a1 = MFMAH(x1, b, a1);
}
__device__ __forceinline__ void t2p(f32x4& a0, f32x4& a1, half8 x0, half8 x1,
                                    half8 bh, half8 bl) {
    a0 = MFMAH(x0, bh, a0);
    a1 = MFMAH(x1, bh, a1);
    a0 = MFMAH(x0, bl, a0);
    a1 = MFMAH(x1, bl, a1);
}

// ---------------------------------------------------------------------------
// main fused kernel: barrier-free after prologue
// ---------------------------------------------------------------------------
__global__ __launch_bounds__(256, 3) void fused_mfma(
    const float* __restrict__ xin,
    const float* __restrict__ ws,
    float* __restrict__ out)
{
    __shared__ unsigned int acts[MTILE * AST];   // 26624 B
    __shared__ float sbias[BIAS_TOT];            // 2048 B

    const int tid = threadIdx.x;
    const int wv = tid >> 6;
    const int lane = tid & 63;
    const int qd = lane >> 4;
    const int mcol = lane & 15;
    const int rw = wv * 32;
    const short* __restrict__ wl = (const short*)(ws + BIAS_TOT) + lane * 8;
    const f32x4 zero4 = {0.f, 0.f, 0.f, 0.f};

    const int g0 = blockIdx.x * MTILE;
    const int bb = g0 / HW;
    const int p0 = g0 - bb * HW;
    const int yb = p0 / IW;
    const int xblk = p0 - yb * IW;
    const float* __restrict__ xb = xin + bb * 3 * HW;

    float* patch = (float*)acts;
    int*   stab  = (int*)(acts + 1984);

    for (int i = tid; i < BIAS_TOT; i += 256) {
        float v = ws[i];
        unsigned d = (unsigned)(i - BEF);
        if (d < 3u) v = ws[STG_BE + d] + ws[STG_BF + d];
        sbias[i] = v;
    }
    for (int e = tid; e < 1980; e += 256) {
        int cr = e / 132;
        int i  = e - cr * 132;
        int c  = cr / 5, r = cr - c * 5;
        int ty = yb + r - 2; ty = ty < 0 ? -ty : ty; ty = (766 - ty) < ty ? 766 - ty : ty;
        int tx = xblk - 2 + i; tx = tx < 0 ? -tx : tx; tx = (766 - tx) < tx ? 766 - tx : tx;
        patch[cr * 132 + i] = xb[c * HW + ty * IW + tx];
    }
    if (tid < 96) {
        int v = 0;
        if (tid < 75) {
            int c = tid / 25, rem = tid - 25 * c;
            int rr = rem / 5, ss = rem - 5 * rr;
            v = (c * 5 + rr) * 132 + ss;
        }
        stab[tid] = v;
    }
    __syncthreads();

    // build sw fragments from LDS patch
    half8 swf[3][2];
    {
        int st[3][8];
#pragma unroll
        for (int kt = 0; kt < 3; kt++)
#pragma unroll
            for (int j = 0; j < 8; j++)
                st[kt][j] = stab[kt * 32 + qd * 8 + j];
#pragma unroll
        for (int mt = 0; mt < 2; mt++) {
            const int xloc = wv * 32 + mt * 16 + mcol;
#pragma unroll
            for (int kt = 0; kt < 3; kt++) {
                union { unsigned u32[4]; half8 v; } u;
#pragma unroll
                for (int jj = 0; jj < 8; jj += 2) {
                    float v0 = patch[st[kt][jj]     + xloc];
                    float v1 = patch[st[kt][jj + 1] + xloc];
                    if (kt == 2) {
                        int qq0 = 64 + qd * 8 + jj;
                        v0 = (qq0     < 75) ? v0 : 0.0f;
                        v1 = (qq0 + 1 < 75) ? v1 : 0.0f;
                    }
                    u.u32[jj >> 1] = packh2(v0, v1);
                }
                swf[kt][mt] = u.v;
            }
        }
    }
    __syncthreads();     // protect patch before acts writes; last barrier.

    // ===== layer A =====
    f32x4 accA[4][2];
#pragma unroll
    for (int nt = 0; nt < 4; nt++) { accA[nt][0] = zero4; accA[nt][1] = zero4; }
#pragma unroll
    for (int nt = 0; nt < 4; nt++)
        t2s(accA[nt][0], accA[nt][1], swf[0][0], swf[0][1], gfragH(wl, W_A0 + nt * 512));
#pragma unroll
    for (int nt = 0; nt < 4; nt++)
        t2s(accA[nt][0], accA[nt][1], swf[1][0], swf[1][1], gfragH(wl, W_A1 + nt * 512));
#pragma unroll
    for (int nt = 0; nt < 4; nt++)
        t2s(accA[nt][0], accA[nt][1], swf[2][0], swf[2][1], gfragH(wl, W_A2 + nt * 512));

    f32x4 x1C[4][2];
    half8 x1f[2][2];
#pragma unroll
    for (int nt = 0; nt < 4; nt++) {
        float bv = sbias[BA + nt * 16 + mcol];
#pragma unroll
        for (int mt = 0; mt < 2; mt++) {
            f32x4 v = accA[nt][mt];
            v[0] += bv; v[1] += bv; v[2] += bv; v[3] += bv;
            x1C[nt][mt] = v;
        }
    }
#pragma unroll
    for (int mt = 0; mt < 2; mt++) {
        writeCf(acts, rw + mt * 16 + qd * 4, mcol,      x1C[0][mt], x1C[1][mt]);
        writeCf(acts, rw + mt * 16 + qd * 4, 16 + mcol, x1C[2][mt], x1C[3][mt]);
    }
#pragma unroll
    for (int kt = 0; kt < 2; kt++)
#pragma unroll
        for (int mt = 0; mt < 2; mt++)
            x1f[kt][mt] = readAf(acts, rw + mt * 16, kt * 16, lane);

    // ===== h1 =====
    f32x4 acc1[5][2];
#pragma unroll
    for (int nt = 0; nt < 5; nt++) { acc1[nt][0] = zero4; acc1[nt][1] = zero4; }
#pragma unroll
    for (int nt = 0; nt < 5; nt++)
        t2s(acc1[nt][0], acc1[nt][1], x1f[0][0], x1f[0][1], gfragH(wl, W_H1A + nt * 512));
#pragma unroll
    for (int nt = 0; nt < 5; nt++)
        t2s(acc1[nt][0], acc1[nt][1], x1f[1][0], x1f[1][1], gfragH(wl, W_H1B + nt * 512));
#pragma unroll
    for (int mt = 0; mt < 2; mt++) {
        f32x4 w5[5];
#pragma unroll
        for (int nt = 0; nt < 5; nt++) {
            float bv = sbias[B1 + nt * 16 + mcol];
            f32x4 v = acc1[nt][mt];
            v[0] = lrelu(v[0] + bv); v[1] = lrelu(v[1] + bv);
            v[2] = lrelu(v[2] + bv); v[3] = lrelu(v[3] + bv);
            w5[nt] = v;
        }
        writeCf(acts, rw + mt * 16 + qd * 4, mcol,      w5[0], w5[1]);
        writeCf(acts, rw + mt * 16 + qd * 4, 16 + mcol, w5[2], w5[3]);
        writeCf(acts, rw + mt * 16 + qd * 4, 32 + mcol, w5[4], zero4);
    }

    // ===== h2 =====
    f32x4 acc2[5][2];
#pragma unroll
    for (int nt = 0; nt < 5; nt++) { acc2[nt][0] = zero4; acc2[nt][1] = zero4; }
    {
        half8 a0 = readAf(acts, rw, 0, lane), a1 = readAf(acts, rw + 16, 0, lane);
#pragma unroll
        for (int nt = 0; nt < 5; nt++)
            t2s(acc2[nt][0], acc2[nt][1], a0, a1, gfragH(wl, W_H2A + nt * 512));
    }
    {
        half8 a0 = readAf(acts, rw, 16, lane), a1 = readAf(acts, rw + 16, 16, lane);
#pragma unroll
        for (int nt = 0; nt < 5; nt++)
            t2s(acc2[nt][0], acc2[nt][1], a0, a1, gfragH(wl, W_H2B + nt * 512));
    }
    {
        half8 a0 = readAf(acts, rw, 32, lane), a1 = readAf(acts, rw + 16, 32, lane);
#pragma unroll
        for (int nt = 0; nt < 5; nt++)
            t2s(acc2[nt][0], acc2[nt][1], a0, a1, gfragH(wl, W_H2C + nt * 512));
    }
#pragma unroll
    for (int mt = 0; mt < 2; mt++) {
        f32x4 w5[5];
#pragma unroll
        for (int nt = 0; nt < 5; nt++) {
            float bv = sbias[B2 + nt * 16 + mcol];
            f32x4 v = acc2[nt][mt];
            v[0] = tanh_fast(v[0] + bv); v[1] = tanh_fast(v[1] + bv);
            v[2] = tanh_fast(v[2] + bv); v[3] = tanh_fast(v[3] + bv);
            w5[nt] = v;
        }
        writeCf(acts, rw + mt * 16 + qd * 4, mcol,      w5[0], w5[1]);
        writeCf(acts, rw + mt * 16 + qd * 4, 16 + mcol, w5[2], w5[3]);
        writeCf(acts, rw + mt * 16 + qd * 4, 32 + mcol, w5[4], zero4);
    }

    // ===== EF =====
    f32x4 accEF[2];
    {
        float bv = sbias[BEF + mcol];
        accEF[0] = (f32x4){bv, bv, bv, bv};
        accEF[1] = accEF[0];
    }
#pragma unroll
    for (int kt = 0; kt < 3; kt++) {
        half8 a0 = readAf(acts, rw, kt * 16, lane), a1 = readAf(acts, rw + 16, kt * 16, lane);
        t2p(accEF[0], accEF[1], a0, a1,
            gfragH(wl, W_EF + kt * 1024), gfragH(wl, W_EF + kt * 1024 + 512));
    }
#pragma unroll
    for (int kt = 0; kt < 2; kt++)
        t2p(accEF[0], accEF[1], x1f[kt][0], x1f[kt][1],
            gfragH(wl, W_EF + 3072 + kt * 1024), gfragH(wl, W_EF + 3072 + kt * 1024 + 512));
    half8 x4f[2];
#pragma unroll
    for (int mt = 0; mt < 2; mt++) {
        f32x4 v = accEF[mt];
        v[0] = lrelu(v[0]); v[1] = lrelu(v[1]); v[2] = lrelu(v[2]); v[3] = lrelu(v[3]);
        writeCf(acts, rw + mt * 16 + qd * 4, 32 + mcol, v, zero4);
    }
    x4f[0] = readAf(acts, rw, 32, lane);
    x4f[1] = readAf(acts, rw + 16, 32, lane);

    // ===== D =====
    f32x4 accD[4][2];
#pragma unroll
    for (int nt = 0; nt < 4; nt++) {
        float bv = sbias[BD + nt * 16 + mcol];
        accD[nt][0] = (f32x4){bv, bv, bv, bv};
        accD[nt][1] = accD[nt][0];
    }
#pragma unroll
    for (int nt = 0; nt < 4; nt++)
        t2p(accD[nt][0], accD[nt][1], x4f[0], x4f[1],
            gfragH(wl, W_D + nt * 1024), gfragH(wl, W_D + nt * 1024 + 512));
#pragma unroll
    for (int mt = 0; mt < 2; mt++) {
        writeCf(acts, rw + mt * 16 + qd * 4, mcol,      accD[0][mt], accD[1][mt]);
        writeCf(acts, rw + mt * 16 + qd * 4, 16 + mcol, accD[2][mt], accD[3][mt]);
    }
    half8 xdf[2][2];
#pragma unroll
    for (int kt = 0; kt < 2; kt++)
#pragma unroll
        for (int mt = 0; mt < 2; mt++)
            xdf[kt][mt] = readAf(acts, rw + mt * 16, kt * 16, lane);

    f32x4 x6a[4][2];
#pragma unroll
    for (int nt = 0; nt < 4; nt++) {
        float bv = sbias[B5 + nt * 16 + mcol];
#pragma unroll
        for (int mt = 0; mt < 2; mt++) {
            f32x4 v;
            v[0] = bv - x1C[nt][mt][0]; v[1] = bv - x1C[nt][mt][1];
            v[2] = bv - x1C[nt][mt][2]; v[3] = bv - x1C[nt][mt][3];
            x6a[nt][mt] = v;
        }
    }

    // ===== h4/h5 chunks =====
#pragma unroll 1
    for (int c = 0; c < 4; c++) {
        f32x4 acc5[2][2];
#pragma unroll
        for (int nt2 = 0; nt2 < 2; nt2++) {
            float bv = sbias[B4 + c * 32 + nt2 * 16 + mcol];
            acc5[nt2][0] = (f32x4){bv, bv, bv, bv};
            acc5[nt2][1] = acc5[nt2][0];
        }
#pragma unroll
        for (int nt2 = 0; nt2 < 2; nt2++)
#pragma unroll
            for (int kt = 0; kt < 2; kt++)
                t2s(acc5[nt2][0], acc5[nt2][1], xdf[kt][0], xdf[kt][1],
                    gfragH(wl, W_H4C0 + c * 4096 + (nt2 * 2 + kt) * 512));
#pragma unroll
        for (int mt = 0; mt < 2; mt++) {
            f32x4 v0 = acc5[0][mt], v1 = acc5[1][mt];
            v0[0] = tanh_fast(v0[0]); v0[1] = tanh_fast(v0[1]);
            v0[2] = tanh_fast(v0[2]); v0[3] = tanh_fast(v0[3]);
            v1[0] = tanh_fast(v1[0]); v1[1] = tanh_fast(v1[1]);
            v1[2] = tanh_fast(v1[2]); v1[3] = tanh_fast(v1[3]);
            writeCf(acts, rw + mt * 16 + qd * 4, 32 + mcol, v0, v1);
        }
        half8 chf[2];
        chf[0] = readAf(acts, rw, 32, lane);
        chf[1] = readAf(acts, rw + 16, 32, lane);
#pragma unroll
        for (int nt = 0; nt < 4; nt++)
            t2s(x6a[nt][0], x6a[nt][1], chf[0], chf[1],
                gfragH(wl, W_H5C0 + c * 4096 + nt * 512));
    }

    // ===== out =====
#pragma unroll
    for (int mt = 0; mt < 2; mt++) {
        writeCf(acts, rw + mt * 16 + qd * 4, mcol,      x6a[0][mt], x6a[1][mt]);
        writeCf(acts, rw + mt * 16 + qd * 4, 16 + mcol, x6a[2][mt], x6a[3][mt]);
    }
    f32x4 accO[2];
    {
        float bv = sbias[BOUT + mcol];
        accO[0] = (f32x4){bv, bv, bv, bv};
        accO[1] = accO[0];
    }
#pragma unroll
    for (int kt = 0; kt < 2; kt++) {
        half8 a0 = readAf(acts, rw, kt * 16, lane), a1 = readAf(acts, rw + 16, kt * 16, lane);
        t2s(accO[0], accO[1], a0, a1, gfragH(wl, W_OUT + kt * 512));
    }
    if (mcol < 3) {
#pragma unroll
        for (int mt = 0; mt < 2; mt++) {
#pragma unroll
            for (int r = 0; r < 4; r++) {
                int p = p0 + wv * 32 + mt * 16 + qd * 4 + r;
                out[(bb * 3 + mcol) * HW + p] = lrelu(accO[mt][r]);
            }
        }
    }
}

extern "C" void kernel_launch(void* const* d_in, const int* in_sizes, int n_in,
                              void* d_out, int out_size, void* d_ws, size_t ws_size,
                              hipStream_t stream)
{
    const float* xin = (const float*)d_in[0];
    float* ws = (float*)d_ws;

    setup_all<<<75, 256, 0, stream>>>(
        (const float*)d_in[1],  (const float*)d_in[2],   // input
        (const float*)d_in[3],  (const float*)d_in[4],   // h1
        (const float*)d_in[5],  (const float*)d_in[6],   // h2
        (const float*)d_in[7],  (const float*)d_in[8],   // h3
        (const float*)d_in[9],  (const float*)d_in[10],  // h4
        (const float*)d_in[11], (const float*)d_in[12],  // h5
        (const float*)d_in[13], (const float*)d_in[14],  // out
        (const float*)d_in[15], (const float*)d_in[16],  // e1
        (const float*)d_in[17], (const float*)d_in[18],  // e2
        (const float*)d_in[19], (const float*)d_in[20],  // e3
        (const float*)d_in[21], (const float*)d_in[22],  // f1
        (const float*)d_in[23], (const float*)d_in[24],  // f2
        (const float*)d_in[25], (const float*)d_in[26],  // f3
        (const float*)d_in[27], (const float*)d_in[28],  // d1
        (const float*)d_in[29], (const float*)d_in[30],  // d2
        (const float*)d_in[31], (const float*)d_in[32],  // d3
        ws);

    fused_mfma<<<NBLK, 256, 0, stream>>>(xin, ws, (float*)d_out);
}